// Round 1
// baseline (1241.469 us; speedup 1.0000x reference)
//
#include <hip/hip_runtime.h>

#define BN_ 256
#define T_  128
#define F_  16
#define H_  64
#define EG_ 16
#define Eg_ 8

__device__ __forceinline__ float elu_(float x) { return x > 0.f ? x : __expf(x) - 1.f; }

// ---------------- temporal conv (per-feature-instance weights), optional fused LN ----------------
// in/out: [BN, T, F, H].  W: [3, F, H, Hout].  bias: [F, H].
// Block: fixed (bn, f), t-tile of 64. 256 threads; each thread 4 rows x 4 h'.
template<int DIL, bool DO_LN>
__global__ __launch_bounds__(256) void tconv_kernel(const float* __restrict__ in,
                                                    const float* __restrict__ W,
                                                    const float* __restrict__ bias,
                                                    const float* __restrict__ gamma,
                                                    const float* __restrict__ beta,
                                                    float* __restrict__ out)
{
    __shared__ float sW[3 * 64 * 64];   // [k][h][h']
    __shared__ float sIn[72 * 68];      // t0-4 .. t0+67, pad stride 68
    __shared__ float sB[64];

    const int bid  = blockIdx.x;
    const int tile = bid & 1;
    const int f    = (bid >> 1) & 15;
    const int bn   = bid >> 5;
    const int t0   = tile * 64;
    const int tid  = threadIdx.x;

    // stage W[k][f][:][:]  (3*64*64 floats = 3072 float4)
    for (int idx = tid; idx < 3 * 1024; idx += 256) {
        int k = idx >> 10, rem = idx & 1023;
        float4 v = reinterpret_cast<const float4*>(W + (size_t)(k * 16 + f) * 4096)[rem];
        reinterpret_cast<float4*>(sW + k * 4096)[rem] = v;
    }
    if (tid < 64) sB[tid] = bias[f * 64 + tid];
    // stage input rows [t0-4, t0+68)
    for (int idx = tid; idx < 72 * 64; idx += 256) {
        int r = idx >> 6, h = idx & 63;
        int t = t0 + r - 4;
        float v = 0.f;
        if (t >= 0 && t < T_) v = in[(((size_t)bn * T_ + t) * F_ + f) * H_ + h];
        sIn[r * 68 + h] = v;
    }
    __syncthreads();

    const int l  = tid & 63;
    const int hb = (l & 15) * 4;          // h' base
    const int rb = (tid >> 6) * 16 + (l >> 4) * 4;  // local row base

    float acc[4][4];
#pragma unroll
    for (int i = 0; i < 4; i++)
#pragma unroll
        for (int j = 0; j < 4; j++) acc[i][j] = sB[hb + j];

#pragma unroll
    for (int k = 0; k < 3; k++) {
        const int off = 4 + (k - 1) * DIL;
        for (int h = 0; h < 64; h++) {
            float4 wv = *reinterpret_cast<const float4*>(sW + (k * 64 + h) * 64 + hb);
#pragma unroll
            for (int i = 0; i < 4; i++) {
                float x = sIn[(rb + i + off) * 68 + h];
                acc[i][0] = fmaf(x, wv.x, acc[i][0]);
                acc[i][1] = fmaf(x, wv.y, acc[i][1]);
                acc[i][2] = fmaf(x, wv.z, acc[i][2]);
                acc[i][3] = fmaf(x, wv.w, acc[i][3]);
            }
        }
    }

#pragma unroll
    for (int i = 0; i < 4; i++) {
#pragma unroll
        for (int j = 0; j < 4; j++) acc[i][j] = elu_(acc[i][j]);
        if (DO_LN) {
            float s = 0.f, q = 0.f;
#pragma unroll
            for (int j = 0; j < 4; j++) { s += acc[i][j]; q += acc[i][j] * acc[i][j]; }
#pragma unroll
            for (int m = 1; m < 16; m <<= 1) { s += __shfl_xor(s, m, 64); q += __shfl_xor(q, m, 64); }
            float mean = s * (1.f / 64.f);
            float var  = q * (1.f / 64.f) - mean * mean;
            float rstd = rsqrtf(var + 1e-5f);
#pragma unroll
            for (int j = 0; j < 4; j++)
                acc[i][j] = (acc[i][j] - mean) * rstd * gamma[hb + j] + beta[hb + j];
        }
        int t = t0 + rb + i;
        float4 o = {acc[i][0], acc[i][1], acc[i][2], acc[i][3]};
        *reinterpret_cast<float4*>(out + (((size_t)bn * T_ + t) * F_ + f) * H_ + hb) = o;
    }
}

// ---------------- dense: elu(concat(x, e) @ W + b) ----------------
// x: [R, 64], e: [R, NE], W: [64+NE, 64]. Block: 64 rows; thread 4x4.
template<int NE>
__global__ __launch_bounds__(256) void dense_kernel(const float* __restrict__ x,
                                                    const float* __restrict__ e,
                                                    const float* __restrict__ W,
                                                    const float* __restrict__ bias,
                                                    float* __restrict__ out)
{
    __shared__ float sW[(64 + NE) * 64];
    __shared__ float sX[64 * 68];
    __shared__ float sE[64 * NE];
    __shared__ float sB[64];

    const int row0 = blockIdx.x * 64;
    const int tid  = threadIdx.x;

    for (int idx = tid; idx < (64 + NE) * 16; idx += 256)
        reinterpret_cast<float4*>(sW)[idx] = reinterpret_cast<const float4*>(W)[idx];
    if (tid < 64) sB[tid] = bias[tid];
    for (int idx = tid; idx < 64 * 16; idx += 256) {
        int r = idx >> 4, c4 = idx & 15;
        float4 v = reinterpret_cast<const float4*>(x + (size_t)(row0 + r) * 64)[c4];
        *reinterpret_cast<float4*>(sX + r * 68 + c4 * 4) = v;
    }
    for (int idx = tid; idx < 64 * NE / 4; idx += 256)
        reinterpret_cast<float4*>(sE)[idx] = reinterpret_cast<const float4*>(e + (size_t)row0 * NE)[idx];
    __syncthreads();

    const int l  = tid & 63;
    const int hb = (l & 15) * 4;
    const int rb = (tid >> 6) * 16 + (l >> 4) * 4;

    float acc[4][4];
#pragma unroll
    for (int i = 0; i < 4; i++)
#pragma unroll
        for (int j = 0; j < 4; j++) acc[i][j] = sB[hb + j];

    for (int h = 0; h < 64; h++) {
        float4 wv = *reinterpret_cast<const float4*>(sW + h * 64 + hb);
#pragma unroll
        for (int i = 0; i < 4; i++) {
            float xv = sX[(rb + i) * 68 + h];
            acc[i][0] = fmaf(xv, wv.x, acc[i][0]);
            acc[i][1] = fmaf(xv, wv.y, acc[i][1]);
            acc[i][2] = fmaf(xv, wv.z, acc[i][2]);
            acc[i][3] = fmaf(xv, wv.w, acc[i][3]);
        }
    }
#pragma unroll
    for (int h = 0; h < NE; h++) {
        float4 wv = *reinterpret_cast<const float4*>(sW + (64 + h) * 64 + hb);
#pragma unroll
        for (int i = 0; i < 4; i++) {
            float xv = sE[(rb + i) * NE + h];
            acc[i][0] = fmaf(xv, wv.x, acc[i][0]);
            acc[i][1] = fmaf(xv, wv.y, acc[i][1]);
            acc[i][2] = fmaf(xv, wv.z, acc[i][2]);
            acc[i][3] = fmaf(xv, wv.w, acc[i][3]);
        }
    }
#pragma unroll
    for (int i = 0; i < 4; i++) {
        float4 o = {elu_(acc[i][0]), elu_(acc[i][1]), elu_(acc[i][2]), elu_(acc[i][3])};
        *reinterpret_cast<float4*>(out + (size_t)(row0 + rb + i) * 64 + hb) = o;
    }
}

// ---------------- node mix: out[b,m,t,f,:] = LN( sum_n adj[m,n] c[b,n,t,f,:] ) ----------------
__global__ __launch_bounds__(256) void nodemix_kernel(const float* __restrict__ c,
                                                      const float* __restrict__ adj,
                                                      const float* __restrict__ gamma,
                                                      const float* __restrict__ beta,
                                                      float* __restrict__ out)
{
    __shared__ float sc[64 * 68];   // [n][h]
    __shared__ float sA[64 * 68];   // [n][m] (transposed adj)

    const int bid = blockIdx.x;
    const int f = bid & 15, t = (bid >> 4) & 127, b = bid >> 11;
    const int tid = threadIdx.x;

    for (int idx = tid; idx < 1024; idx += 256) {
        int n = idx >> 4, c4 = idx & 15;
        float4 v = reinterpret_cast<const float4*>(c + ((((size_t)b * 64 + n) * T_ + t) * F_ + f) * H_)[c4];
        *reinterpret_cast<float4*>(sc + n * 68 + c4 * 4) = v;
    }
    for (int idx = tid; idx < 4096; idx += 256) {
        int n = idx & 63, m = idx >> 6;
        sA[n * 68 + m] = adj[m * 64 + n];
    }
    __syncthreads();

    const int h = tid & 63, mq = tid >> 6;
    float acc[16];
#pragma unroll
    for (int j = 0; j < 16; j++) acc[j] = 0.f;

    for (int n = 0; n < 64; n++) {
        float xv = sc[n * 68 + h];
        const float4* ap = reinterpret_cast<const float4*>(sA + n * 68 + mq * 16);
        float4 a0 = ap[0], a1 = ap[1], a2 = ap[2], a3 = ap[3];
        acc[0]  = fmaf(a0.x, xv, acc[0]);  acc[1]  = fmaf(a0.y, xv, acc[1]);
        acc[2]  = fmaf(a0.z, xv, acc[2]);  acc[3]  = fmaf(a0.w, xv, acc[3]);
        acc[4]  = fmaf(a1.x, xv, acc[4]);  acc[5]  = fmaf(a1.y, xv, acc[5]);
        acc[6]  = fmaf(a1.z, xv, acc[6]);  acc[7]  = fmaf(a1.w, xv, acc[7]);
        acc[8]  = fmaf(a2.x, xv, acc[8]);  acc[9]  = fmaf(a2.y, xv, acc[9]);
        acc[10] = fmaf(a2.z, xv, acc[10]); acc[11] = fmaf(a2.w, xv, acc[11]);
        acc[12] = fmaf(a3.x, xv, acc[12]); acc[13] = fmaf(a3.y, xv, acc[13]);
        acc[14] = fmaf(a3.z, xv, acc[14]); acc[15] = fmaf(a3.w, xv, acc[15]);
    }

    float g = gamma[h], be = beta[h];
#pragma unroll
    for (int j = 0; j < 16; j++) {
        float v = acc[j];
        float s = v, q = v * v;
#pragma unroll
        for (int msk = 1; msk < 64; msk <<= 1) { s += __shfl_xor(s, msk, 64); q += __shfl_xor(q, msk, 64); }
        float mean = s * (1.f / 64.f);
        float var  = q * (1.f / 64.f) - mean * mean;
        float rstd = rsqrtf(var + 1e-5f);
        int m = mq * 16 + j;
        out[((((size_t)b * 64 + m) * T_ + t) * F_ + f) * H_ + h] = (v - mean) * rstd * g + be;
    }
}

// ---------------- feature mix + LN + residual ----------------
__global__ __launch_bounds__(256) void featmix_kernel(const float* __restrict__ e,
                                                      const float* __restrict__ adjg,
                                                      const float* __restrict__ gamma,
                                                      const float* __restrict__ beta,
                                                      const float* __restrict__ res,
                                                      float* __restrict__ out)
{
    __shared__ float se[16 * 68];   // [f][h]
    __shared__ float sA[16 * 16];   // [f][g]

    const int bid = blockIdx.x;
    const int t = bid & 127, bn = bid >> 7;
    const int tid = threadIdx.x;

    {
        int f = tid >> 4, c4 = tid & 15;
        float4 v = reinterpret_cast<const float4*>(e + (((size_t)bn * T_ + t) * F_ + f) * H_)[c4];
        *reinterpret_cast<float4*>(se + f * 68 + c4 * 4) = v;
        int ff = tid & 15, g = tid >> 4;
        sA[ff * 16 + g] = adjg[g * 16 + ff];
    }
    __syncthreads();

    const int h = tid & 63, w = tid >> 6;
    float acc[4] = {0.f, 0.f, 0.f, 0.f};
    for (int f2 = 0; f2 < 16; f2++) {
        float xv = se[f2 * 68 + h];
        float4 a = *reinterpret_cast<const float4*>(sA + f2 * 16 + w * 4);
        acc[0] = fmaf(a.x, xv, acc[0]);
        acc[1] = fmaf(a.y, xv, acc[1]);
        acc[2] = fmaf(a.z, xv, acc[2]);
        acc[3] = fmaf(a.w, xv, acc[3]);
    }
    float g_ = gamma[h], be = beta[h];
#pragma unroll
    for (int j = 0; j < 4; j++) {
        float v = acc[j];
        float s = v, q = v * v;
#pragma unroll
        for (int msk = 1; msk < 64; msk <<= 1) { s += __shfl_xor(s, msk, 64); q += __shfl_xor(q, msk, 64); }
        float mean = s * (1.f / 64.f);
        float var  = q * (1.f / 64.f) - mean * mean;
        float rstd = rsqrtf(var + 1e-5f);
        int gq = w * 4 + j;
        size_t o = (((size_t)bn * T_ + t) * F_ + gq) * H_ + h;
        out[o] = (v - mean) * rstd * g_ + be + res[o];
    }
}

extern "C" void kernel_launch(void* const* d_in, const int* in_sizes, int n_in,
                              void* d_out, int out_size, void* d_ws, size_t ws_size,
                              hipStream_t stream)
{
    const float* h_in    = (const float*)d_in[0];
    const float* embs_G  = (const float*)d_in[2];
    const float* embs_g  = (const float*)d_in[3];
    const float* adj_G   = (const float*)d_in[4];
    const float* adj_g   = (const float*)d_in[5];
    const float* Wt0 = (const float*)d_in[6];  const float* bt0 = (const float*)d_in[7];
    const float* Wt1 = (const float*)d_in[8];  const float* bt1 = (const float*)d_in[9];
    const float* Wt2 = (const float*)d_in[10]; const float* bt2 = (const float*)d_in[11];
    const float* gamma_t = (const float*)d_in[12]; const float* beta_t = (const float*)d_in[13];
    const float* W_G = (const float*)d_in[14]; const float* b_G = (const float*)d_in[15];
    const float* gamma_G = (const float*)d_in[16]; const float* beta_G = (const float*)d_in[17];
    const float* W_g = (const float*)d_in[18]; const float* b_g = (const float*)d_in[19];
    const float* gamma_g = (const float*)d_in[20]; const float* beta_g = (const float*)d_in[21];

    float* out  = (float*)d_out;
    float* buf0 = (float*)d_ws;
    float* buf1 = buf0 + (size_t)BN_ * T_ * F_ * H_;

    // 3 dilated temporal convs (last fuses LayerNorm_t)
    tconv_kernel<1, false><<<8192, 256, 0, stream>>>(h_in, Wt0, bt0, nullptr, nullptr, buf0);
    tconv_kernel<2, false><<<8192, 256, 0, stream>>>(buf0, Wt1, bt1, nullptr, nullptr, buf1);
    tconv_kernel<4, true ><<<8192, 256, 0, stream>>>(buf1, Wt2, bt2, gamma_t, beta_t, buf0);
    // outer graph conv: dense(concat h,embs_G) -> node mix + LN
    dense_kernel<16><<<8192, 256, 0, stream>>>(buf0, embs_G, W_G, b_G, buf1);
    nodemix_kernel<<<8192, 256, 0, stream>>>(buf1, adj_G, gamma_G, beta_G, buf0);
    // inner graph conv: dense(concat h,embs_g) -> feature mix + LN + residual
    dense_kernel<8><<<8192, 256, 0, stream>>>(buf0, embs_g, W_g, b_g, buf1);
    featmix_kernel<<<32768, 256, 0, stream>>>(buf1, adj_g, gamma_g, beta_g, h_in, out);
}

// Round 2
// 652.074 us; speedup vs baseline: 1.9039x; 1.9039x over previous
//
#include <hip/hip_runtime.h>

#define BN_ 256
#define T_  128
#define F_  16
#define H_  64

using bf16x8 = __attribute__((ext_vector_type(8))) __bf16;
using f32x4  = __attribute__((ext_vector_type(4))) float;

__device__ __forceinline__ float elu_(float x) { return x > 0.f ? x : __expf(x) - 1.f; }
__device__ __forceinline__ unsigned short f2b(float x) {
    unsigned u = __float_as_uint(x);
    u += 0x7FFF + ((u >> 16) & 1);
    return (unsigned short)(u >> 16);
}

// ---------------- temporal conv via MFMA ----------------
// in/out: [BN, T, F, *].  W: [3, F, H, Hout] fp32.  One block per (bn, f); 4 waves.
// Wave w computes rows [w*32, w*32+32) x 64 cols. K = 3 taps x 64 h.
template<int DIL, bool DO_LN, typename TIN, typename TOUT>
__global__ __launch_bounds__(256) void tconv_mfma(const TIN* __restrict__ in,
                                                  const float* __restrict__ W,
                                                  const float* __restrict__ bias,
                                                  const float* __restrict__ gamma,
                                                  const float* __restrict__ beta,
                                                  TOUT* __restrict__ out)
{
    __shared__ __align__(16) unsigned short sA[136 * 72];  // rows t0-4..t0+131, pad stride 72 (16B-aligned, 2-way max)
    __shared__ __align__(16) unsigned short sW[64 * 200];  // [g][tap*64+h] transposed, pad stride 200
    __shared__ float sB[64];

    const int f   = blockIdx.x & 15;
    const int bn  = blockIdx.x >> 4;
    const int tid = threadIdx.x;

    if (tid < 64) sB[tid] = bias[f * 64 + tid];

    // stage W transposed -> [g][k] so B-fragments are contiguous 8-bf16 reads
    for (int idx = tid; idx < 3 * 4096; idx += 256) {
        int tap = idx >> 12, rem = idx & 4095;
        int h = rem >> 6, g = rem & 63;
        sW[g * 200 + tap * 64 + h] = f2b(W[(size_t)(tap * 16 + f) * 4096 + rem]);
    }
    // stage input rows [-4, 132) with zero pad
    for (int idx = tid; idx < 136 * 16; idx += 256) {
        int r = idx >> 4, h4 = (idx & 15) * 4;
        int t = r - 4;
        unsigned short v0 = 0, v1 = 0, v2 = 0, v3 = 0;
        if (t >= 0 && t < T_) {
            const size_t base = (((size_t)bn * T_ + t) * F_ + f) * H_ + h4;
            if constexpr (sizeof(TIN) == 4) {
                float4 v = *reinterpret_cast<const float4*>(in + base);
                v0 = f2b(v.x); v1 = f2b(v.y); v2 = f2b(v.z); v3 = f2b(v.w);
            } else {
                ushort4 v = *reinterpret_cast<const ushort4*>(in + base);
                v0 = v.x; v1 = v.y; v2 = v.z; v3 = v.w;
            }
        }
        sA[r * 72 + h4 + 0] = v0; sA[r * 72 + h4 + 1] = v1;
        sA[r * 72 + h4 + 2] = v2; sA[r * 72 + h4 + 3] = v3;
    }
    __syncthreads();

    const int lane = tid & 63;
    const int w    = tid >> 6;
    const int r16  = lane & 15;
    const int q    = lane >> 4;

    f32x4 acc[2][4];
#pragma unroll
    for (int i = 0; i < 2; i++)
#pragma unroll
        for (int j = 0; j < 4; j++) acc[i][j] = {0.f, 0.f, 0.f, 0.f};

#pragma unroll
    for (int tap = 0; tap < 3; ++tap) {
        const int row0 = w * 32 + r16 + 4 + (tap - 1) * DIL;
#pragma unroll
        for (int ks = 0; ks < 2; ++ks) {
            const int ko = ks * 32 + q * 8;
            bf16x8 a0 = *reinterpret_cast<const bf16x8*>(&sA[row0 * 72 + ko]);
            bf16x8 a1 = *reinterpret_cast<const bf16x8*>(&sA[(row0 + 16) * 72 + ko]);
            const int kb = tap * 64 + ko;
            bf16x8 b0 = *reinterpret_cast<const bf16x8*>(&sW[(r16     ) * 200 + kb]);
            bf16x8 b1 = *reinterpret_cast<const bf16x8*>(&sW[(r16 + 16) * 200 + kb]);
            bf16x8 b2 = *reinterpret_cast<const bf16x8*>(&sW[(r16 + 32) * 200 + kb]);
            bf16x8 b3 = *reinterpret_cast<const bf16x8*>(&sW[(r16 + 48) * 200 + kb]);
            acc[0][0] = __builtin_amdgcn_mfma_f32_16x16x32_bf16(a0, b0, acc[0][0], 0, 0, 0);
            acc[0][1] = __builtin_amdgcn_mfma_f32_16x16x32_bf16(a0, b1, acc[0][1], 0, 0, 0);
            acc[0][2] = __builtin_amdgcn_mfma_f32_16x16x32_bf16(a0, b2, acc[0][2], 0, 0, 0);
            acc[0][3] = __builtin_amdgcn_mfma_f32_16x16x32_bf16(a0, b3, acc[0][3], 0, 0, 0);
            acc[1][0] = __builtin_amdgcn_mfma_f32_16x16x32_bf16(a1, b0, acc[1][0], 0, 0, 0);
            acc[1][1] = __builtin_amdgcn_mfma_f32_16x16x32_bf16(a1, b1, acc[1][1], 0, 0, 0);
            acc[1][2] = __builtin_amdgcn_mfma_f32_16x16x32_bf16(a1, b2, acc[1][2], 0, 0, 0);
            acc[1][3] = __builtin_amdgcn_mfma_f32_16x16x32_bf16(a1, b3, acc[1][3], 0, 0, 0);
        }
    }

    float gv[4], bv[4];
    if (DO_LN) {
#pragma unroll
        for (int ct = 0; ct < 4; ++ct) { gv[ct] = gamma[ct * 16 + r16]; bv[ct] = beta[ct * 16 + r16]; }
    }
#pragma unroll
    for (int rt = 0; rt < 2; ++rt) {
#pragma unroll
        for (int rg = 0; rg < 4; ++rg) {
            float v[4];
#pragma unroll
            for (int ct = 0; ct < 4; ++ct) v[ct] = elu_(acc[rt][ct][rg] + sB[ct * 16 + r16]);
            if (DO_LN) {
                float s  = v[0] + v[1] + v[2] + v[3];
                float qq = v[0]*v[0] + v[1]*v[1] + v[2]*v[2] + v[3]*v[3];
#pragma unroll
                for (int m = 1; m < 16; m <<= 1) { s += __shfl_xor(s, m, 64); qq += __shfl_xor(qq, m, 64); }
                float mean = s * (1.f / 64.f);
                float var  = qq * (1.f / 64.f) - mean * mean;
                float rstd = rsqrtf(var + 1e-5f);
#pragma unroll
                for (int ct = 0; ct < 4; ++ct) v[ct] = (v[ct] - mean) * rstd * gv[ct] + bv[ct];
            }
            const int t = w * 32 + rt * 16 + q * 4 + rg;
            const size_t ob = (((size_t)bn * T_ + t) * F_ + f) * H_ + r16;
#pragma unroll
            for (int ct = 0; ct < 4; ++ct) {
                if constexpr (sizeof(TOUT) == 2) out[ob + ct * 16] = f2b(v[ct]);
                else                             out[ob + ct * 16] = v[ct];
            }
        }
    }
}

// ---------------- dense: elu(concat(x, e) @ W + b) ----------------
template<int NE>
__global__ __launch_bounds__(256) void dense_kernel(const float* __restrict__ x,
                                                    const float* __restrict__ e,
                                                    const float* __restrict__ W,
                                                    const float* __restrict__ bias,
                                                    float* __restrict__ out)
{
    __shared__ float sW[(64 + NE) * 64];
    __shared__ float sX[64 * 68];
    __shared__ float sE[64 * NE];
    __shared__ float sB[64];

    const int row0 = blockIdx.x * 64;
    const int tid  = threadIdx.x;

    for (int idx = tid; idx < (64 + NE) * 16; idx += 256)
        reinterpret_cast<float4*>(sW)[idx] = reinterpret_cast<const float4*>(W)[idx];
    if (tid < 64) sB[tid] = bias[tid];
    for (int idx = tid; idx < 64 * 16; idx += 256) {
        int r = idx >> 4, c4 = idx & 15;
        float4 v = reinterpret_cast<const float4*>(x + (size_t)(row0 + r) * 64)[c4];
        *reinterpret_cast<float4*>(sX + r * 68 + c4 * 4) = v;
    }
    for (int idx = tid; idx < 64 * NE / 4; idx += 256)
        reinterpret_cast<float4*>(sE)[idx] = reinterpret_cast<const float4*>(e + (size_t)row0 * NE)[idx];
    __syncthreads();

    const int l  = tid & 63;
    const int hb = (l & 15) * 4;
    const int rb = (tid >> 6) * 16 + (l >> 4) * 4;

    float acc[4][4];
#pragma unroll
    for (int i = 0; i < 4; i++)
#pragma unroll
        for (int j = 0; j < 4; j++) acc[i][j] = sB[hb + j];

    for (int h = 0; h < 64; h++) {
        float4 wv = *reinterpret_cast<const float4*>(sW + h * 64 + hb);
#pragma unroll
        for (int i = 0; i < 4; i++) {
            float xv = sX[(rb + i) * 68 + h];
            acc[i][0] = fmaf(xv, wv.x, acc[i][0]);
            acc[i][1] = fmaf(xv, wv.y, acc[i][1]);
            acc[i][2] = fmaf(xv, wv.z, acc[i][2]);
            acc[i][3] = fmaf(xv, wv.w, acc[i][3]);
        }
    }
#pragma unroll
    for (int h = 0; h < NE; h++) {
        float4 wv = *reinterpret_cast<const float4*>(sW + (64 + h) * 64 + hb);
#pragma unroll
        for (int i = 0; i < 4; i++) {
            float xv = sE[(rb + i) * NE + h];
            acc[i][0] = fmaf(xv, wv.x, acc[i][0]);
            acc[i][1] = fmaf(xv, wv.y, acc[i][1]);
            acc[i][2] = fmaf(xv, wv.z, acc[i][2]);
            acc[i][3] = fmaf(xv, wv.w, acc[i][3]);
        }
    }
#pragma unroll
    for (int i = 0; i < 4; i++) {
        float4 o = {elu_(acc[i][0]), elu_(acc[i][1]), elu_(acc[i][2]), elu_(acc[i][3])};
        *reinterpret_cast<float4*>(out + (size_t)(row0 + rb + i) * 64 + hb) = o;
    }
}

// ---------------- node mix + LN ----------------
__global__ __launch_bounds__(256) void nodemix_kernel(const float* __restrict__ c,
                                                      const float* __restrict__ adj,
                                                      const float* __restrict__ gamma,
                                                      const float* __restrict__ beta,
                                                      float* __restrict__ out)
{
    __shared__ float sc[64 * 68];
    __shared__ float sA[64 * 68];

    const int bid = blockIdx.x;
    const int f = bid & 15, t = (bid >> 4) & 127, b = bid >> 11;
    const int tid = threadIdx.x;

    for (int idx = tid; idx < 1024; idx += 256) {
        int n = idx >> 4, c4 = idx & 15;
        float4 v = reinterpret_cast<const float4*>(c + ((((size_t)b * 64 + n) * T_ + t) * F_ + f) * H_)[c4];
        *reinterpret_cast<float4*>(sc + n * 68 + c4 * 4) = v;
    }
    for (int idx = tid; idx < 4096; idx += 256) {
        int n = idx & 63, m = idx >> 6;
        sA[n * 68 + m] = adj[m * 64 + n];
    }
    __syncthreads();

    const int h = tid & 63, mq = tid >> 6;
    float acc[16];
#pragma unroll
    for (int j = 0; j < 16; j++) acc[j] = 0.f;

    for (int n = 0; n < 64; n++) {
        float xv = sc[n * 68 + h];
        const float4* ap = reinterpret_cast<const float4*>(sA + n * 68 + mq * 16);
        float4 a0 = ap[0], a1 = ap[1], a2 = ap[2], a3 = ap[3];
        acc[0]  = fmaf(a0.x, xv, acc[0]);  acc[1]  = fmaf(a0.y, xv, acc[1]);
        acc[2]  = fmaf(a0.z, xv, acc[2]);  acc[3]  = fmaf(a0.w, xv, acc[3]);
        acc[4]  = fmaf(a1.x, xv, acc[4]);  acc[5]  = fmaf(a1.y, xv, acc[5]);
        acc[6]  = fmaf(a1.z, xv, acc[6]);  acc[7]  = fmaf(a1.w, xv, acc[7]);
        acc[8]  = fmaf(a2.x, xv, acc[8]);  acc[9]  = fmaf(a2.y, xv, acc[9]);
        acc[10] = fmaf(a2.z, xv, acc[10]); acc[11] = fmaf(a2.w, xv, acc[11]);
        acc[12] = fmaf(a3.x, xv, acc[12]); acc[13] = fmaf(a3.y, xv, acc[13]);
        acc[14] = fmaf(a3.z, xv, acc[14]); acc[15] = fmaf(a3.w, xv, acc[15]);
    }

    float g = gamma[h], be = beta[h];
#pragma unroll
    for (int j = 0; j < 16; j++) {
        float v = acc[j];
        float s = v, qv = v * v;
#pragma unroll
        for (int msk = 1; msk < 64; msk <<= 1) { s += __shfl_xor(s, msk, 64); qv += __shfl_xor(qv, msk, 64); }
        float mean = s * (1.f / 64.f);
        float var  = qv * (1.f / 64.f) - mean * mean;
        float rstd = rsqrtf(var + 1e-5f);
        int m = mq * 16 + j;
        out[((((size_t)b * 64 + m) * T_ + t) * F_ + f) * H_ + h] = (v - mean) * rstd * g + be;
    }
}

// ---------------- feature mix + LN + residual ----------------
__global__ __launch_bounds__(256) void featmix_kernel(const float* __restrict__ e,
                                                      const float* __restrict__ adjg,
                                                      const float* __restrict__ gamma,
                                                      const float* __restrict__ beta,
                                                      const float* __restrict__ res,
                                                      float* __restrict__ out)
{
    __shared__ float se[16 * 68];
    __shared__ float sA[16 * 16];

    const int bid = blockIdx.x;
    const int t = bid & 127, bn = bid >> 7;
    const int tid = threadIdx.x;

    {
        int f = tid >> 4, c4 = tid & 15;
        float4 v = reinterpret_cast<const float4*>(e + (((size_t)bn * T_ + t) * F_ + f) * H_)[c4];
        *reinterpret_cast<float4*>(se + f * 68 + c4 * 4) = v;
        int ff = tid & 15, g = tid >> 4;
        sA[ff * 16 + g] = adjg[g * 16 + ff];
    }
    __syncthreads();

    const int h = tid & 63, w = tid >> 6;
    float acc[4] = {0.f, 0.f, 0.f, 0.f};
    for (int f2 = 0; f2 < 16; f2++) {
        float xv = se[f2 * 68 + h];
        float4 a = *reinterpret_cast<const float4*>(sA + f2 * 16 + w * 4);
        acc[0] = fmaf(a.x, xv, acc[0]);
        acc[1] = fmaf(a.y, xv, acc[1]);
        acc[2] = fmaf(a.z, xv, acc[2]);
        acc[3] = fmaf(a.w, xv, acc[3]);
    }
    float g_ = gamma[h], be = beta[h];
#pragma unroll
    for (int j = 0; j < 4; j++) {
        float v = acc[j];
        float s = v, qv = v * v;
#pragma unroll
        for (int msk = 1; msk < 64; msk <<= 1) { s += __shfl_xor(s, msk, 64); qv += __shfl_xor(qv, msk, 64); }
        float mean = s * (1.f / 64.f);
        float var  = qv * (1.f / 64.f) - mean * mean;
        float rstd = rsqrtf(var + 1e-5f);
        int gq = w * 4 + j;
        size_t o = (((size_t)bn * T_ + t) * F_ + gq) * H_ + h;
        out[o] = (v - mean) * rstd * g_ + be + res[o];
    }
}

extern "C" void kernel_launch(void* const* d_in, const int* in_sizes, int n_in,
                              void* d_out, int out_size, void* d_ws, size_t ws_size,
                              hipStream_t stream)
{
    const float* h_in    = (const float*)d_in[0];
    const float* embs_G  = (const float*)d_in[2];
    const float* embs_g  = (const float*)d_in[3];
    const float* adj_G   = (const float*)d_in[4];
    const float* adj_g   = (const float*)d_in[5];
    const float* Wt0 = (const float*)d_in[6];  const float* bt0 = (const float*)d_in[7];
    const float* Wt1 = (const float*)d_in[8];  const float* bt1 = (const float*)d_in[9];
    const float* Wt2 = (const float*)d_in[10]; const float* bt2 = (const float*)d_in[11];
    const float* gamma_t = (const float*)d_in[12]; const float* beta_t = (const float*)d_in[13];
    const float* W_G = (const float*)d_in[14]; const float* b_G = (const float*)d_in[15];
    const float* gamma_G = (const float*)d_in[16]; const float* beta_G = (const float*)d_in[17];
    const float* W_g = (const float*)d_in[18]; const float* b_g = (const float*)d_in[19];
    const float* gamma_g = (const float*)d_in[20]; const float* beta_g = (const float*)d_in[21];

    float* out = (float*)d_out;
    char*  ws  = (char*)d_ws;
    // layout: [0,64MB) bf16 conv0-out | [64,128MB) bf16 conv1-out | [128,256MB) fp32 region1
    // after convs, [0,128MB) is reused as fp32 region0
    unsigned short* c0 = (unsigned short*)ws;
    unsigned short* c1 = (unsigned short*)(ws + ((size_t)64 << 20));
    float* reg0 = (float*)ws;
    float* reg1 = (float*)(ws + ((size_t)128 << 20));

    tconv_mfma<1, false, float,          unsigned short><<<4096, 256, 0, stream>>>(h_in, Wt0, bt0, nullptr, nullptr, c0);
    tconv_mfma<2, false, unsigned short, unsigned short><<<4096, 256, 0, stream>>>(c0,   Wt1, bt1, nullptr, nullptr, c1);
    tconv_mfma<4, true,  unsigned short, float         ><<<4096, 256, 0, stream>>>(c1,   Wt2, bt2, gamma_t, beta_t, reg1);

    dense_kernel<16><<<8192, 256, 0, stream>>>(reg1, embs_G, W_G, b_G, reg0);
    nodemix_kernel<<<8192, 256, 0, stream>>>(reg0, adj_G, gamma_G, beta_G, reg1);
    dense_kernel<8><<<8192, 256, 0, stream>>>(reg1, embs_g, W_g, b_g, reg0);
    featmix_kernel<<<32768, 256, 0, stream>>>(reg0, adj_g, gamma_g, beta_g, h_in, out);
}

// Round 6
// 549.810 us; speedup vs baseline: 2.2580x; 1.1860x over previous
//
#include <hip/hip_runtime.h>

#define BN_ 256
#define T_  128
#define F_  16
#define H_  64

using f16x8   = __attribute__((ext_vector_type(8))) _Float16;
using f32x4   = __attribute__((ext_vector_type(4))) float;
using ushort8 = __attribute__((ext_vector_type(8))) unsigned short;

__device__ __forceinline__ float elu_(float x) { return x > 0.f ? x : __expf(x) - 1.f; }
__device__ __forceinline__ unsigned short f2h(float x) {
    union { _Float16 h; unsigned short u; } v; v.h = (_Float16)x; return v.u;
}
__device__ __forceinline__ float h2f(unsigned short u) {
    union { unsigned short u; _Float16 h; } v; v.u = u; return (float)v.h;
}

// ---------------- temporal conv via MFMA, optional fused LN (round-2-verified structure) ----------------
template<int DIL, bool DO_LN, typename TIN, typename TOUT>
__global__ __launch_bounds__(256) void tconv_mfma(const TIN* __restrict__ in,
                                                  const float* __restrict__ W,
                                                  const float* __restrict__ bias,
                                                  const float* __restrict__ gamma,
                                                  const float* __restrict__ beta,
                                                  TOUT* __restrict__ out)
{
    __shared__ __align__(16) unsigned short sA[136 * 72];
    __shared__ __align__(16) unsigned short sW[64 * 200];
    __shared__ float sB[64];

    const int f   = blockIdx.x & 15;
    const int bn  = blockIdx.x >> 4;
    const int tid = threadIdx.x;

    if (tid < 64) sB[tid] = bias[f * 64 + tid];
    for (int idx = tid; idx < 3 * 4096; idx += 256) {
        int tap = idx >> 12, rem = idx & 4095;
        int h = rem >> 6, g = rem & 63;
        sW[g * 200 + tap * 64 + h] = f2h(W[(size_t)(tap * 16 + f) * 4096 + rem]);
    }
    for (int idx = tid; idx < 136 * 16; idx += 256) {
        int r = idx >> 4, h4 = (idx & 15) * 4;
        int t = r - 4;
        unsigned short v0 = 0, v1 = 0, v2 = 0, v3 = 0;
        if (t >= 0 && t < T_) {
            const size_t base = (((size_t)bn * T_ + t) * F_ + f) * H_ + h4;
            if constexpr (sizeof(TIN) == 4) {
                float4 v = *reinterpret_cast<const float4*>(in + base);
                v0 = f2h(v.x); v1 = f2h(v.y); v2 = f2h(v.z); v3 = f2h(v.w);
            } else {
                ushort4 v = *reinterpret_cast<const ushort4*>(in + base);
                v0 = v.x; v1 = v.y; v2 = v.z; v3 = v.w;
            }
        }
        sA[r * 72 + h4 + 0] = v0; sA[r * 72 + h4 + 1] = v1;
        sA[r * 72 + h4 + 2] = v2; sA[r * 72 + h4 + 3] = v3;
    }
    __syncthreads();

    const int lane = tid & 63, w = tid >> 6;
    const int r16 = lane & 15, q = lane >> 4;

    f32x4 acc[2][4];
#pragma unroll
    for (int i = 0; i < 2; i++)
#pragma unroll
        for (int j = 0; j < 4; j++) acc[i][j] = {0.f, 0.f, 0.f, 0.f};

#pragma unroll
    for (int tap = 0; tap < 3; ++tap) {
        const int row0 = w * 32 + r16 + 4 + (tap - 1) * DIL;
#pragma unroll
        for (int ks = 0; ks < 2; ++ks) {
            const int ko = ks * 32 + q * 8;
            f16x8 a0 = *reinterpret_cast<const f16x8*>(&sA[row0 * 72 + ko]);
            f16x8 a1 = *reinterpret_cast<const f16x8*>(&sA[(row0 + 16) * 72 + ko]);
            const int kb = tap * 64 + ko;
            f16x8 b0 = *reinterpret_cast<const f16x8*>(&sW[(r16     ) * 200 + kb]);
            f16x8 b1 = *reinterpret_cast<const f16x8*>(&sW[(r16 + 16) * 200 + kb]);
            f16x8 b2 = *reinterpret_cast<const f16x8*>(&sW[(r16 + 32) * 200 + kb]);
            f16x8 b3 = *reinterpret_cast<const f16x8*>(&sW[(r16 + 48) * 200 + kb]);
            acc[0][0] = __builtin_amdgcn_mfma_f32_16x16x32_f16(a0, b0, acc[0][0], 0, 0, 0);
            acc[0][1] = __builtin_amdgcn_mfma_f32_16x16x32_f16(a0, b1, acc[0][1], 0, 0, 0);
            acc[0][2] = __builtin_amdgcn_mfma_f32_16x16x32_f16(a0, b2, acc[0][2], 0, 0, 0);
            acc[0][3] = __builtin_amdgcn_mfma_f32_16x16x32_f16(a0, b3, acc[0][3], 0, 0, 0);
            acc[1][0] = __builtin_amdgcn_mfma_f32_16x16x32_f16(a1, b0, acc[1][0], 0, 0, 0);
            acc[1][1] = __builtin_amdgcn_mfma_f32_16x16x32_f16(a1, b1, acc[1][1], 0, 0, 0);
            acc[1][2] = __builtin_amdgcn_mfma_f32_16x16x32_f16(a1, b2, acc[1][2], 0, 0, 0);
            acc[1][3] = __builtin_amdgcn_mfma_f32_16x16x32_f16(a1, b3, acc[1][3], 0, 0, 0);
        }
    }

    float gv[4], bv[4];
    if (DO_LN) {
#pragma unroll
        for (int ct = 0; ct < 4; ++ct) { gv[ct] = gamma[ct * 16 + r16]; bv[ct] = beta[ct * 16 + r16]; }
    }
#pragma unroll
    for (int rt = 0; rt < 2; ++rt)
#pragma unroll
        for (int rg = 0; rg < 4; ++rg) {
            float v[4];
#pragma unroll
            for (int ct = 0; ct < 4; ++ct) v[ct] = elu_(acc[rt][ct][rg] + sB[ct * 16 + r16]);
            if (DO_LN) {
                float s  = v[0] + v[1] + v[2] + v[3];
                float qq = v[0]*v[0] + v[1]*v[1] + v[2]*v[2] + v[3]*v[3];
#pragma unroll
                for (int m = 1; m < 16; m <<= 1) { s += __shfl_xor(s, m, 64); qq += __shfl_xor(qq, m, 64); }
                float mean = s * (1.f / 64.f);
                float var  = qq * (1.f / 64.f) - mean * mean;
                float rstd = rsqrtf(var + 1e-5f);
#pragma unroll
                for (int ct = 0; ct < 4; ++ct) v[ct] = (v[ct] - mean) * rstd * gv[ct] + bv[ct];
            }
            const int t = w * 32 + rt * 16 + q * 4 + rg;
            const size_t ob = (((size_t)bn * T_ + t) * F_ + f) * H_ + r16;
#pragma unroll
            for (int ct = 0; ct < 4; ++ct) {
                if constexpr (sizeof(TOUT) == 2) out[ob + ct * 16] = f2h(v[ct]);
                else                             out[ob + ct * 16] = v[ct];
            }
        }
}

// ---------------- dense: elu(concat(x, e) @ W + b) — round-2 VERBATIM (f32) ----------------
template<int NE>
__global__ __launch_bounds__(256) void dense_kernel(const float* __restrict__ x,
                                                    const float* __restrict__ e,
                                                    const float* __restrict__ W,
                                                    const float* __restrict__ bias,
                                                    float* __restrict__ out)
{
    __shared__ float sW[(64 + NE) * 64];
    __shared__ float sX[64 * 68];
    __shared__ float sE[64 * NE];
    __shared__ float sB[64];

    const int row0 = blockIdx.x * 64;
    const int tid  = threadIdx.x;

    for (int idx = tid; idx < (64 + NE) * 16; idx += 256)
        reinterpret_cast<float4*>(sW)[idx] = reinterpret_cast<const float4*>(W)[idx];
    if (tid < 64) sB[tid] = bias[tid];
    for (int idx = tid; idx < 64 * 16; idx += 256) {
        int r = idx >> 4, c4 = idx & 15;
        float4 v = reinterpret_cast<const float4*>(x + (size_t)(row0 + r) * 64)[c4];
        *reinterpret_cast<float4*>(sX + r * 68 + c4 * 4) = v;
    }
    for (int idx = tid; idx < 64 * NE / 4; idx += 256)
        reinterpret_cast<float4*>(sE)[idx] = reinterpret_cast<const float4*>(e + (size_t)row0 * NE)[idx];
    __syncthreads();

    const int l  = tid & 63;
    const int hb = (l & 15) * 4;
    const int rb = (tid >> 6) * 16 + (l >> 4) * 4;

    float acc[4][4];
#pragma unroll
    for (int i = 0; i < 4; i++)
#pragma unroll
        for (int j = 0; j < 4; j++) acc[i][j] = sB[hb + j];

    for (int h = 0; h < 64; h++) {
        float4 wv = *reinterpret_cast<const float4*>(sW + h * 64 + hb);
#pragma unroll
        for (int i = 0; i < 4; i++) {
            float xv = sX[(rb + i) * 68 + h];
            acc[i][0] = fmaf(xv, wv.x, acc[i][0]);
            acc[i][1] = fmaf(xv, wv.y, acc[i][1]);
            acc[i][2] = fmaf(xv, wv.z, acc[i][2]);
            acc[i][3] = fmaf(xv, wv.w, acc[i][3]);
        }
    }
#pragma unroll
    for (int h = 0; h < NE; h++) {
        float4 wv = *reinterpret_cast<const float4*>(sW + (64 + h) * 64 + hb);
#pragma unroll
        for (int i = 0; i < 4; i++) {
            float xv = sE[(rb + i) * NE + h];
            acc[i][0] = fmaf(xv, wv.x, acc[i][0]);
            acc[i][1] = fmaf(xv, wv.y, acc[i][1]);
            acc[i][2] = fmaf(xv, wv.z, acc[i][2]);
            acc[i][3] = fmaf(xv, wv.w, acc[i][3]);
        }
    }
#pragma unroll
    for (int i = 0; i < 4; i++) {
        float4 o = {elu_(acc[i][0]), elu_(acc[i][1]), elu_(acc[i][2]), elu_(acc[i][3])};
        *reinterpret_cast<float4*>(out + (size_t)(row0 + rb + i) * 64 + hb) = o;
    }
}

// ---------------- node mix via MFMA + LN_G — TEST SUBJECT (f32 in/out adapters) ----------------
__global__ __launch_bounds__(256) void nodemix_mfma(const float* __restrict__ d1,
                                                    const float* __restrict__ adjG,
                                                    const float* __restrict__ gamma,
                                                    const float* __restrict__ beta,
                                                    float* __restrict__ nmo)
{
    __shared__ __align__(16) unsigned short sAdj[64 * 72];  // [m][n]
    __shared__ __align__(16) unsigned short sXT[64 * 88];   // [h][n]

    const int f = blockIdx.x & 15, t = (blockIdx.x >> 4) & 127, b = blockIdx.x >> 11;
    const int tid = threadIdx.x, lane = tid & 63, w = tid >> 6;

    for (int idx = tid; idx < 4096; idx += 256) {
        int m = idx >> 6, n = idx & 63;
        sAdj[m * 72 + n] = f2h(adjG[idx]);
    }
    {
        const int n = lane;
        const size_t base = (((size_t)(b * 64 + n) * T_ + t) * F_ + f) * H_;
#pragma unroll
        for (int p = 0; p < 2; ++p) {
            int c = w + p * 4;
            float4 v0 = *reinterpret_cast<const float4*>(&d1[base + c * 8]);
            float4 v1 = *reinterpret_cast<const float4*>(&d1[base + c * 8 + 4]);
            sXT[(c * 8 + 0) * 88 + n] = f2h(v0.x);
            sXT[(c * 8 + 1) * 88 + n] = f2h(v0.y);
            sXT[(c * 8 + 2) * 88 + n] = f2h(v0.z);
            sXT[(c * 8 + 3) * 88 + n] = f2h(v0.w);
            sXT[(c * 8 + 4) * 88 + n] = f2h(v1.x);
            sXT[(c * 8 + 5) * 88 + n] = f2h(v1.y);
            sXT[(c * 8 + 6) * 88 + n] = f2h(v1.z);
            sXT[(c * 8 + 7) * 88 + n] = f2h(v1.w);
        }
    }
    __syncthreads();

    const int r16 = lane & 15, q = lane >> 4;
    f32x4 acc[4];
#pragma unroll
    for (int j = 0; j < 4; j++) acc[j] = {0.f, 0.f, 0.f, 0.f};

#pragma unroll
    for (int ks = 0; ks < 2; ++ks) {
        f16x8 af = *reinterpret_cast<const f16x8*>(&sAdj[(w * 16 + r16) * 72 + ks * 32 + q * 8]);
#pragma unroll
        for (int ht = 0; ht < 4; ++ht) {
            f16x8 bfv = *reinterpret_cast<const f16x8*>(&sXT[(ht * 16 + r16) * 88 + ks * 32 + q * 8]);
            acc[ht] = __builtin_amdgcn_mfma_f32_16x16x32_f16(af, bfv, acc[ht], 0, 0, 0);
        }
    }

    float gm[4], bt[4];
#pragma unroll
    for (int ht = 0; ht < 4; ++ht) { gm[ht] = gamma[ht * 16 + r16]; bt[ht] = beta[ht * 16 + r16]; }
#pragma unroll
    for (int reg = 0; reg < 4; ++reg) {
        const int m = w * 16 + q * 4 + reg;
        float v[4];
#pragma unroll
        for (int ht = 0; ht < 4; ++ht) v[ht] = acc[ht][reg];
        float s  = v[0] + v[1] + v[2] + v[3];
        float qq = v[0]*v[0] + v[1]*v[1] + v[2]*v[2] + v[3]*v[3];
#pragma unroll
        for (int msk = 1; msk < 16; msk <<= 1) { s += __shfl_xor(s, msk, 64); qq += __shfl_xor(qq, msk, 64); }
        float mean = s * (1.f / 64.f);
        float var  = qq * (1.f / 64.f) - mean * mean;
        float rstd = rsqrtf(var + 1e-5f);
        const size_t ob = (((size_t)(b * 64 + m) * T_ + t) * F_ + f) * H_ + r16;
#pragma unroll
        for (int ht = 0; ht < 4; ++ht)
            nmo[ob + ht * 16] = (v[ht] - mean) * rstd * gm[ht] + bt[ht];
    }
}

// ---------------- feature mix + LN + residual — round-2 VERBATIM (f32) ----------------
__global__ __launch_bounds__(256) void featmix_kernel(const float* __restrict__ e,
                                                      const float* __restrict__ adjg,
                                                      const float* __restrict__ gamma,
                                                      const float* __restrict__ beta,
                                                      const float* __restrict__ res,
                                                      float* __restrict__ out)
{
    __shared__ float se[16 * 68];
    __shared__ float sA[16 * 16];

    const int bid = blockIdx.x;
    const int t = bid & 127, bn = bid >> 7;
    const int tid = threadIdx.x;

    {
        int f = tid >> 4, c4 = tid & 15;
        float4 v = reinterpret_cast<const float4*>(e + (((size_t)bn * T_ + t) * F_ + f) * H_)[c4];
        *reinterpret_cast<float4*>(se + f * 68 + c4 * 4) = v;
        int ff = tid & 15, g = tid >> 4;
        sA[ff * 16 + g] = adjg[g * 16 + ff];
    }
    __syncthreads();

    const int h = tid & 63, w = tid >> 6;
    float acc[4] = {0.f, 0.f, 0.f, 0.f};
    for (int f2 = 0; f2 < 16; f2++) {
        float xv = se[f2 * 68 + h];
        float4 a = *reinterpret_cast<const float4*>(sA + f2 * 16 + w * 4);
        acc[0] = fmaf(a.x, xv, acc[0]);
        acc[1] = fmaf(a.y, xv, acc[1]);
        acc[2] = fmaf(a.z, xv, acc[2]);
        acc[3] = fmaf(a.w, xv, acc[3]);
    }
    float g_ = gamma[h], be = beta[h];
#pragma unroll
    for (int j = 0; j < 4; j++) {
        float v = acc[j];
        float s = v, qv = v * v;
#pragma unroll
        for (int msk = 1; msk < 64; msk <<= 1) { s += __shfl_xor(s, msk, 64); qv += __shfl_xor(qv, msk, 64); }
        float mean = s * (1.f / 64.f);
        float var  = qv * (1.f / 64.f) - mean * mean;
        float rstd = rsqrtf(var + 1e-5f);
        int gq = w * 4 + j;
        size_t o = (((size_t)bn * T_ + t) * F_ + gq) * H_ + h;
        out[o] = (v - mean) * rstd * g_ + be + res[o];
    }
}

extern "C" void kernel_launch(void* const* d_in, const int* in_sizes, int n_in,
                              void* d_out, int out_size, void* d_ws, size_t ws_size,
                              hipStream_t stream)
{
    const float* h_in    = (const float*)d_in[0];
    const float* embs_G  = (const float*)d_in[2];
    const float* embs_g  = (const float*)d_in[3];
    const float* adj_G   = (const float*)d_in[4];
    const float* adj_g   = (const float*)d_in[5];
    const float* Wt0 = (const float*)d_in[6];  const float* bt0 = (const float*)d_in[7];
    const float* Wt1 = (const float*)d_in[8];  const float* bt1 = (const float*)d_in[9];
    const float* Wt2 = (const float*)d_in[10]; const float* bt2 = (const float*)d_in[11];
    const float* gamma_t = (const float*)d_in[12]; const float* beta_t = (const float*)d_in[13];
    const float* W_G = (const float*)d_in[14]; const float* b_G = (const float*)d_in[15];
    const float* gamma_G = (const float*)d_in[16]; const float* beta_G = (const float*)d_in[17];
    const float* W_g = (const float*)d_in[18]; const float* b_g = (const float*)d_in[19];
    const float* gamma_g = (const float*)d_in[20]; const float* beta_g = (const float*)d_in[21];

    float* out = (float*)d_out;
    char*  ws  = (char*)d_ws;
    // round-2 layout: fp16 c0 @0 (64MB), fp16 c1 @64MB (64MB), f32 reg1 @128MB (128MB), f32 reg0 @0 (128MB)
    unsigned short* c0 = (unsigned short*)ws;
    unsigned short* c1 = (unsigned short*)(ws + ((size_t)64 << 20));
    float* reg0 = (float*)ws;
    float* reg1 = (float*)(ws + ((size_t)128 << 20));

    tconv_mfma<1, false, float,          unsigned short><<<4096, 256, 0, stream>>>(h_in, Wt0, bt0, nullptr, nullptr, c0);
    tconv_mfma<2, false, unsigned short, unsigned short><<<4096, 256, 0, stream>>>(c0,   Wt1, bt1, nullptr, nullptr, c1);
    tconv_mfma<4, true,  unsigned short, float         ><<<4096, 256, 0, stream>>>(c1,   Wt2, bt2, gamma_t, beta_t, reg1);

    dense_kernel<16><<<8192, 256, 0, stream>>>(reg1, embs_G, W_G, b_G, reg0);
    nodemix_mfma<<<8192, 256, 0, stream>>>(reg0, adj_G, gamma_G, beta_G, reg1);
    dense_kernel<8><<<8192, 256, 0, stream>>>(reg1, embs_g, W_g, b_g, reg0);
    featmix_kernel<<<32768, 256, 0, stream>>>(reg0, adj_g, gamma_g, beta_g, h_in, out);
}

// Round 7
// 537.395 us; speedup vs baseline: 2.3102x; 1.0231x over previous
//
#include <hip/hip_runtime.h>

#define BN_ 256
#define T_  128
#define F_  16
#define H_  64

using f16x8   = __attribute__((ext_vector_type(8))) _Float16;
using f32x4   = __attribute__((ext_vector_type(4))) float;
using ushort8 = __attribute__((ext_vector_type(8))) unsigned short;

__device__ __forceinline__ float elu_(float x) { return x > 0.f ? x : __expf(x) - 1.f; }
__device__ __forceinline__ unsigned short f2h(float x) {
    union { _Float16 h; unsigned short u; } v; v.h = (_Float16)x; return v.u;
}
__device__ __forceinline__ float h2f(unsigned short u) {
    union { unsigned short u; _Float16 h; } v; v.u = u; return (float)v.h;
}

// ---------------- temporal conv via MFMA, optional fused LN (verified) ----------------
template<int DIL, bool DO_LN, typename TIN, typename TOUT>
__global__ __launch_bounds__(256) void tconv_mfma(const TIN* __restrict__ in,
                                                  const float* __restrict__ W,
                                                  const float* __restrict__ bias,
                                                  const float* __restrict__ gamma,
                                                  const float* __restrict__ beta,
                                                  TOUT* __restrict__ out)
{
    __shared__ __align__(16) unsigned short sA[136 * 72];
    __shared__ __align__(16) unsigned short sW[64 * 200];
    __shared__ float sB[64];

    const int f   = blockIdx.x & 15;
    const int bn  = blockIdx.x >> 4;
    const int tid = threadIdx.x;

    if (tid < 64) sB[tid] = bias[f * 64 + tid];
    for (int idx = tid; idx < 3 * 4096; idx += 256) {
        int tap = idx >> 12, rem = idx & 4095;
        int h = rem >> 6, g = rem & 63;
        sW[g * 200 + tap * 64 + h] = f2h(W[(size_t)(tap * 16 + f) * 4096 + rem]);
    }
    for (int idx = tid; idx < 136 * 16; idx += 256) {
        int r = idx >> 4, h4 = (idx & 15) * 4;
        int t = r - 4;
        unsigned short v0 = 0, v1 = 0, v2 = 0, v3 = 0;
        if (t >= 0 && t < T_) {
            const size_t base = (((size_t)bn * T_ + t) * F_ + f) * H_ + h4;
            if constexpr (sizeof(TIN) == 4) {
                float4 v = *reinterpret_cast<const float4*>(in + base);
                v0 = f2h(v.x); v1 = f2h(v.y); v2 = f2h(v.z); v3 = f2h(v.w);
            } else {
                ushort4 v = *reinterpret_cast<const ushort4*>(in + base);
                v0 = v.x; v1 = v.y; v2 = v.z; v3 = v.w;
            }
        }
        sA[r * 72 + h4 + 0] = v0; sA[r * 72 + h4 + 1] = v1;
        sA[r * 72 + h4 + 2] = v2; sA[r * 72 + h4 + 3] = v3;
    }
    __syncthreads();

    const int lane = tid & 63, w = tid >> 6;
    const int r16 = lane & 15, q = lane >> 4;

    f32x4 acc[2][4];
#pragma unroll
    for (int i = 0; i < 2; i++)
#pragma unroll
        for (int j = 0; j < 4; j++) acc[i][j] = {0.f, 0.f, 0.f, 0.f};

#pragma unroll
    for (int tap = 0; tap < 3; ++tap) {
        const int row0 = w * 32 + r16 + 4 + (tap - 1) * DIL;
#pragma unroll
        for (int ks = 0; ks < 2; ++ks) {
            const int ko = ks * 32 + q * 8;
            f16x8 a0 = *reinterpret_cast<const f16x8*>(&sA[row0 * 72 + ko]);
            f16x8 a1 = *reinterpret_cast<const f16x8*>(&sA[(row0 + 16) * 72 + ko]);
            const int kb = tap * 64 + ko;
            f16x8 b0 = *reinterpret_cast<const f16x8*>(&sW[(r16     ) * 200 + kb]);
            f16x8 b1 = *reinterpret_cast<const f16x8*>(&sW[(r16 + 16) * 200 + kb]);
            f16x8 b2 = *reinterpret_cast<const f16x8*>(&sW[(r16 + 32) * 200 + kb]);
            f16x8 b3 = *reinterpret_cast<const f16x8*>(&sW[(r16 + 48) * 200 + kb]);
            acc[0][0] = __builtin_amdgcn_mfma_f32_16x16x32_f16(a0, b0, acc[0][0], 0, 0, 0);
            acc[0][1] = __builtin_amdgcn_mfma_f32_16x16x32_f16(a0, b1, acc[0][1], 0, 0, 0);
            acc[0][2] = __builtin_amdgcn_mfma_f32_16x16x32_f16(a0, b2, acc[0][2], 0, 0, 0);
            acc[0][3] = __builtin_amdgcn_mfma_f32_16x16x32_f16(a0, b3, acc[0][3], 0, 0, 0);
            acc[1][0] = __builtin_amdgcn_mfma_f32_16x16x32_f16(a1, b0, acc[1][0], 0, 0, 0);
            acc[1][1] = __builtin_amdgcn_mfma_f32_16x16x32_f16(a1, b1, acc[1][1], 0, 0, 0);
            acc[1][2] = __builtin_amdgcn_mfma_f32_16x16x32_f16(a1, b2, acc[1][2], 0, 0, 0);
            acc[1][3] = __builtin_amdgcn_mfma_f32_16x16x32_f16(a1, b3, acc[1][3], 0, 0, 0);
        }
    }

    float gv[4], bv[4];
    if (DO_LN) {
#pragma unroll
        for (int ct = 0; ct < 4; ++ct) { gv[ct] = gamma[ct * 16 + r16]; bv[ct] = beta[ct * 16 + r16]; }
    }
#pragma unroll
    for (int rt = 0; rt < 2; ++rt)
#pragma unroll
        for (int rg = 0; rg < 4; ++rg) {
            float v[4];
#pragma unroll
            for (int ct = 0; ct < 4; ++ct) v[ct] = elu_(acc[rt][ct][rg] + sB[ct * 16 + r16]);
            if (DO_LN) {
                float s  = v[0] + v[1] + v[2] + v[3];
                float qq = v[0]*v[0] + v[1]*v[1] + v[2]*v[2] + v[3]*v[3];
#pragma unroll
                for (int m = 1; m < 16; m <<= 1) { s += __shfl_xor(s, m, 64); qq += __shfl_xor(qq, m, 64); }
                float mean = s * (1.f / 64.f);
                float var  = qq * (1.f / 64.f) - mean * mean;
                float rstd = rsqrtf(var + 1e-5f);
#pragma unroll
                for (int ct = 0; ct < 4; ++ct) v[ct] = (v[ct] - mean) * rstd * gv[ct] + bv[ct];
            }
            const int t = w * 32 + rt * 16 + q * 4 + rg;
            const size_t ob = (((size_t)bn * T_ + t) * F_ + f) * H_ + r16;
#pragma unroll
            for (int ct = 0; ct < 4; ++ct) {
                if constexpr (sizeof(TOUT) == 2) out[ob + ct * 16] = f2h(v[ct]);
                else                             out[ob + ct * 16] = v[ct];
            }
        }
}

// ---------------- dense via MFMA: elu(concat(x, e) @ W + b) — NEW, f32 in/out ----------------
// x: [R,64] f32, e: [R,NE] f32, W: [64+NE,64] f32. Block: 128 rows, 4 waves.
template<int NE>
__global__ __launch_bounds__(256) void dense_mfma(const float* __restrict__ x,
                                                  const float* __restrict__ e,
                                                  const float* __restrict__ W,
                                                  const float* __restrict__ bias,
                                                  float* __restrict__ out)
{
    __shared__ __align__(16) unsigned short sA[128 * 104];  // [r][k], k=0..95 (64 x | NE emb | zero)
    __shared__ __align__(16) unsigned short sW[64 * 104];   // [g][k] transposed
    __shared__ float sB[64];

    const int row0 = blockIdx.x * 128;
    const int tid  = threadIdx.x;

    if (tid < 64) sB[tid] = bias[tid];
    // x -> cols 0..63
    for (int idx = tid; idx < 2048; idx += 256) {
        int r = idx >> 4, c4 = (idx & 15) * 4;
        float4 v = *reinterpret_cast<const float4*>(x + (size_t)(row0 + r) * 64 + c4);
        sA[r * 104 + c4 + 0] = f2h(v.x);
        sA[r * 104 + c4 + 1] = f2h(v.y);
        sA[r * 104 + c4 + 2] = f2h(v.z);
        sA[r * 104 + c4 + 3] = f2h(v.w);
    }
    // emb / zero -> cols 64..95 (single writer loop, no races)
    for (int idx = tid; idx < 4096; idx += 256) {
        int r = idx >> 5, c = idx & 31;
        unsigned short v = 0;
        if (c < NE) v = f2h(e[(size_t)(row0 + r) * NE + c]);
        sA[r * 104 + 64 + c] = v;
    }
    // W rows 0..63 transposed
    for (int idx = tid; idx < 4096; idx += 256) {
        int g = idx & 63, k = idx >> 6;
        sW[g * 104 + k] = f2h(W[k * 64 + g]);
    }
    // W rows 64..95 (emb rows or zero)
    for (int idx = tid; idx < 2048; idx += 256) {
        int g = idx >> 5, c = idx & 31;
        unsigned short v = 0;
        if (c < NE) v = f2h(W[(64 + c) * 64 + g]);
        sW[g * 104 + 64 + c] = v;
    }
    __syncthreads();

    const int lane = tid & 63, w = tid >> 6;
    const int r16 = lane & 15, q = lane >> 4;

    f32x4 dacc[2][4];
#pragma unroll
    for (int i = 0; i < 2; i++)
#pragma unroll
        for (int j = 0; j < 4; j++) dacc[i][j] = {0.f, 0.f, 0.f, 0.f};

#pragma unroll
    for (int ks = 0; ks < 3; ++ks) {
        const int ko = ks * 32 + q * 8;
        f16x8 a0 = *reinterpret_cast<const f16x8*>(&sA[(w * 32 + r16) * 104 + ko]);
        f16x8 a1 = *reinterpret_cast<const f16x8*>(&sA[(w * 32 + 16 + r16) * 104 + ko]);
#pragma unroll
        for (int nt = 0; nt < 4; ++nt) {
            f16x8 bb = *reinterpret_cast<const f16x8*>(&sW[(nt * 16 + r16) * 104 + ko]);
            dacc[0][nt] = __builtin_amdgcn_mfma_f32_16x16x32_f16(a0, bb, dacc[0][nt], 0, 0, 0);
            dacc[1][nt] = __builtin_amdgcn_mfma_f32_16x16x32_f16(a1, bb, dacc[1][nt], 0, 0, 0);
        }
    }

    float bg[4];
#pragma unroll
    for (int nt = 0; nt < 4; ++nt) bg[nt] = sB[nt * 16 + r16];
#pragma unroll
    for (int rt = 0; rt < 2; ++rt)
#pragma unroll
        for (int rg = 0; rg < 4; ++rg) {
            const int r = w * 32 + rt * 16 + q * 4 + rg;
            const size_t ob = (size_t)(row0 + r) * 64 + r16;
#pragma unroll
            for (int nt = 0; nt < 4; ++nt)
                out[ob + nt * 16] = elu_(dacc[rt][nt][rg] + bg[nt]);
        }
}

// ---------------- node mix via MFMA + LN_G (verified round 6) ----------------
__global__ __launch_bounds__(256) void nodemix_mfma(const float* __restrict__ d1,
                                                    const float* __restrict__ adjG,
                                                    const float* __restrict__ gamma,
                                                    const float* __restrict__ beta,
                                                    float* __restrict__ nmo)
{
    __shared__ __align__(16) unsigned short sAdj[64 * 72];  // [m][n]
    __shared__ __align__(16) unsigned short sXT[64 * 88];   // [h][n]

    const int f = blockIdx.x & 15, t = (blockIdx.x >> 4) & 127, b = blockIdx.x >> 11;
    const int tid = threadIdx.x, lane = tid & 63, w = tid >> 6;

    for (int idx = tid; idx < 4096; idx += 256) {
        int m = idx >> 6, n = idx & 63;
        sAdj[m * 72 + n] = f2h(adjG[idx]);
    }
    {
        const int n = lane;
        const size_t base = (((size_t)(b * 64 + n) * T_ + t) * F_ + f) * H_;
#pragma unroll
        for (int p = 0; p < 2; ++p) {
            int c = w + p * 4;
            float4 v0 = *reinterpret_cast<const float4*>(&d1[base + c * 8]);
            float4 v1 = *reinterpret_cast<const float4*>(&d1[base + c * 8 + 4]);
            sXT[(c * 8 + 0) * 88 + n] = f2h(v0.x);
            sXT[(c * 8 + 1) * 88 + n] = f2h(v0.y);
            sXT[(c * 8 + 2) * 88 + n] = f2h(v0.z);
            sXT[(c * 8 + 3) * 88 + n] = f2h(v0.w);
            sXT[(c * 8 + 4) * 88 + n] = f2h(v1.x);
            sXT[(c * 8 + 5) * 88 + n] = f2h(v1.y);
            sXT[(c * 8 + 6) * 88 + n] = f2h(v1.z);
            sXT[(c * 8 + 7) * 88 + n] = f2h(v1.w);
        }
    }
    __syncthreads();

    const int r16 = lane & 15, q = lane >> 4;
    f32x4 acc[4];
#pragma unroll
    for (int j = 0; j < 4; j++) acc[j] = {0.f, 0.f, 0.f, 0.f};

#pragma unroll
    for (int ks = 0; ks < 2; ++ks) {
        f16x8 af = *reinterpret_cast<const f16x8*>(&sAdj[(w * 16 + r16) * 72 + ks * 32 + q * 8]);
#pragma unroll
        for (int ht = 0; ht < 4; ++ht) {
            f16x8 bfv = *reinterpret_cast<const f16x8*>(&sXT[(ht * 16 + r16) * 88 + ks * 32 + q * 8]);
            acc[ht] = __builtin_amdgcn_mfma_f32_16x16x32_f16(af, bfv, acc[ht], 0, 0, 0);
        }
    }

    float gm[4], bt[4];
#pragma unroll
    for (int ht = 0; ht < 4; ++ht) { gm[ht] = gamma[ht * 16 + r16]; bt[ht] = beta[ht * 16 + r16]; }
#pragma unroll
    for (int reg = 0; reg < 4; ++reg) {
        const int m = w * 16 + q * 4 + reg;
        float v[4];
#pragma unroll
        for (int ht = 0; ht < 4; ++ht) v[ht] = acc[ht][reg];
        float s  = v[0] + v[1] + v[2] + v[3];
        float qq = v[0]*v[0] + v[1]*v[1] + v[2]*v[2] + v[3]*v[3];
#pragma unroll
        for (int msk = 1; msk < 16; msk <<= 1) { s += __shfl_xor(s, msk, 64); qq += __shfl_xor(qq, msk, 64); }
        float mean = s * (1.f / 64.f);
        float var  = qq * (1.f / 64.f) - mean * mean;
        float rstd = rsqrtf(var + 1e-5f);
        const size_t ob = (((size_t)(b * 64 + m) * T_ + t) * F_ + f) * H_ + r16;
#pragma unroll
        for (int ht = 0; ht < 4; ++ht)
            nmo[ob + ht * 16] = (v[ht] - mean) * rstd * gm[ht] + bt[ht];
    }
}

// ---------------- feature mix + LN + residual — round-2 VERBATIM (f32) ----------------
__global__ __launch_bounds__(256) void featmix_kernel(const float* __restrict__ e,
                                                      const float* __restrict__ adjg,
                                                      const float* __restrict__ gamma,
                                                      const float* __restrict__ beta,
                                                      const float* __restrict__ res,
                                                      float* __restrict__ out)
{
    __shared__ float se[16 * 68];
    __shared__ float sA[16 * 16];

    const int bid = blockIdx.x;
    const int t = bid & 127, bn = bid >> 7;
    const int tid = threadIdx.x;

    {
        int f = tid >> 4, c4 = tid & 15;
        float4 v = reinterpret_cast<const float4*>(e + (((size_t)bn * T_ + t) * F_ + f) * H_)[c4];
        *reinterpret_cast<float4*>(se + f * 68 + c4 * 4) = v;
        int ff = tid & 15, g = tid >> 4;
        sA[ff * 16 + g] = adjg[g * 16 + ff];
    }
    __syncthreads();

    const int h = tid & 63, w = tid >> 6;
    float acc[4] = {0.f, 0.f, 0.f, 0.f};
    for (int f2 = 0; f2 < 16; f2++) {
        float xv = se[f2 * 68 + h];
        float4 a = *reinterpret_cast<const float4*>(sA + f2 * 16 + w * 4);
        acc[0] = fmaf(a.x, xv, acc[0]);
        acc[1] = fmaf(a.y, xv, acc[1]);
        acc[2] = fmaf(a.z, xv, acc[2]);
        acc[3] = fmaf(a.w, xv, acc[3]);
    }
    float g_ = gamma[h], be = beta[h];
#pragma unroll
    for (int j = 0; j < 4; j++) {
        float v = acc[j];
        float s = v, qv = v * v;
#pragma unroll
        for (int msk = 1; msk < 64; msk <<= 1) { s += __shfl_xor(s, msk, 64); qv += __shfl_xor(qv, msk, 64); }
        float mean = s * (1.f / 64.f);
        float var  = qv * (1.f / 64.f) - mean * mean;
        float rstd = rsqrtf(var + 1e-5f);
        int gq = w * 4 + j;
        size_t o = (((size_t)bn * T_ + t) * F_ + gq) * H_ + h;
        out[o] = (v - mean) * rstd * g_ + be + res[o];
    }
}

extern "C" void kernel_launch(void* const* d_in, const int* in_sizes, int n_in,
                              void* d_out, int out_size, void* d_ws, size_t ws_size,
                              hipStream_t stream)
{
    const float* h_in    = (const float*)d_in[0];
    const float* embs_G  = (const float*)d_in[2];
    const float* embs_g  = (const float*)d_in[3];
    const float* adj_G   = (const float*)d_in[4];
    const float* adj_g   = (const float*)d_in[5];
    const float* Wt0 = (const float*)d_in[6];  const float* bt0 = (const float*)d_in[7];
    const float* Wt1 = (const float*)d_in[8];  const float* bt1 = (const float*)d_in[9];
    const float* Wt2 = (const float*)d_in[10]; const float* bt2 = (const float*)d_in[11];
    const float* gamma_t = (const float*)d_in[12]; const float* beta_t = (const float*)d_in[13];
    const float* W_G = (const float*)d_in[14]; const float* b_G = (const float*)d_in[15];
    const float* gamma_G = (const float*)d_in[16]; const float* beta_G = (const float*)d_in[17];
    const float* W_g = (const float*)d_in[18]; const float* b_g = (const float*)d_in[19];
    const float* gamma_g = (const float*)d_in[20]; const float* beta_g = (const float*)d_in[21];

    float* out = (float*)d_out;
    char*  ws  = (char*)d_ws;
    // layout: fp16 c0 @0 (64MB), fp16 c1 @64MB (64MB), f32 reg1 @128MB (128MB), f32 reg0 @0 (128MB)
    unsigned short* c0 = (unsigned short*)ws;
    unsigned short* c1 = (unsigned short*)(ws + ((size_t)64 << 20));
    float* reg0 = (float*)ws;
    float* reg1 = (float*)(ws + ((size_t)128 << 20));

    tconv_mfma<1, false, float,          unsigned short><<<4096, 256, 0, stream>>>(h_in, Wt0, bt0, nullptr, nullptr, c0);
    tconv_mfma<2, false, unsigned short, unsigned short><<<4096, 256, 0, stream>>>(c0,   Wt1, bt1, nullptr, nullptr, c1);
    tconv_mfma<4, true,  unsigned short, float         ><<<4096, 256, 0, stream>>>(c1,   Wt2, bt2, gamma_t, beta_t, reg1);

    dense_mfma<16><<<4096, 256, 0, stream>>>(reg1, embs_G, W_G, b_G, reg0);
    nodemix_mfma<<<8192, 256, 0, stream>>>(reg0, adj_G, gamma_G, beta_G, reg1);
    dense_mfma<8><<<4096, 256, 0, stream>>>(reg1, embs_g, W_g, b_g, reg0);
    featmix_kernel<<<32768, 256, 0, stream>>>(reg0, adj_g, gamma_g, beta_g, h_in, out);
}

// Round 8
// 423.422 us; speedup vs baseline: 2.9320x; 1.2692x over previous
//
#include <hip/hip_runtime.h>

#define BN_ 256
#define T_  128
#define F_  16
#define H_  64

using f16x8   = __attribute__((ext_vector_type(8))) _Float16;
using f32x4   = __attribute__((ext_vector_type(4))) float;
using ushort8 = __attribute__((ext_vector_type(8))) unsigned short;

__device__ __forceinline__ float elu_(float x) { return x > 0.f ? x : __expf(x) - 1.f; }
__device__ __forceinline__ unsigned short f2h(float x) {
    union { _Float16 h; unsigned short u; } v; v.h = (_Float16)x; return v.u;
}
__device__ __forceinline__ float h2f(unsigned short u) {
    union { unsigned short u; _Float16 h; } v; v.u = u; return (float)v.h;
}

// ---------------- temporal conv via MFMA, optional fused LN (verified) ----------------
template<int DIL, bool DO_LN, typename TIN, typename TOUT>
__global__ __launch_bounds__(256) void tconv_mfma(const TIN* __restrict__ in,
                                                  const float* __restrict__ W,
                                                  const float* __restrict__ bias,
                                                  const float* __restrict__ gamma,
                                                  const float* __restrict__ beta,
                                                  TOUT* __restrict__ out)
{
    __shared__ __align__(16) unsigned short sA[136 * 72];
    __shared__ __align__(16) unsigned short sW[64 * 200];
    __shared__ float sB[64];

    const int f   = blockIdx.x & 15;
    const int bn  = blockIdx.x >> 4;
    const int tid = threadIdx.x;

    if (tid < 64) sB[tid] = bias[f * 64 + tid];
    for (int idx = tid; idx < 3 * 4096; idx += 256) {
        int tap = idx >> 12, rem = idx & 4095;
        int h = rem >> 6, g = rem & 63;
        sW[g * 200 + tap * 64 + h] = f2h(W[(size_t)(tap * 16 + f) * 4096 + rem]);
    }
    for (int idx = tid; idx < 136 * 16; idx += 256) {
        int r = idx >> 4, h4 = (idx & 15) * 4;
        int t = r - 4;
        unsigned short v0 = 0, v1 = 0, v2 = 0, v3 = 0;
        if (t >= 0 && t < T_) {
            const size_t base = (((size_t)bn * T_ + t) * F_ + f) * H_ + h4;
            if constexpr (sizeof(TIN) == 4) {
                float4 v = *reinterpret_cast<const float4*>(in + base);
                v0 = f2h(v.x); v1 = f2h(v.y); v2 = f2h(v.z); v3 = f2h(v.w);
            } else {
                ushort4 v = *reinterpret_cast<const ushort4*>(in + base);
                v0 = v.x; v1 = v.y; v2 = v.z; v3 = v.w;
            }
        }
        sA[r * 72 + h4 + 0] = v0; sA[r * 72 + h4 + 1] = v1;
        sA[r * 72 + h4 + 2] = v2; sA[r * 72 + h4 + 3] = v3;
    }
    __syncthreads();

    const int lane = tid & 63, w = tid >> 6;
    const int r16 = lane & 15, q = lane >> 4;

    f32x4 acc[2][4];
#pragma unroll
    for (int i = 0; i < 2; i++)
#pragma unroll
        for (int j = 0; j < 4; j++) acc[i][j] = {0.f, 0.f, 0.f, 0.f};

#pragma unroll
    for (int tap = 0; tap < 3; ++tap) {
        const int row0 = w * 32 + r16 + 4 + (tap - 1) * DIL;
#pragma unroll
        for (int ks = 0; ks < 2; ++ks) {
            const int ko = ks * 32 + q * 8;
            f16x8 a0 = *reinterpret_cast<const f16x8*>(&sA[row0 * 72 + ko]);
            f16x8 a1 = *reinterpret_cast<const f16x8*>(&sA[(row0 + 16) * 72 + ko]);
            const int kb = tap * 64 + ko;
            f16x8 b0 = *reinterpret_cast<const f16x8*>(&sW[(r16     ) * 200 + kb]);
            f16x8 b1 = *reinterpret_cast<const f16x8*>(&sW[(r16 + 16) * 200 + kb]);
            f16x8 b2 = *reinterpret_cast<const f16x8*>(&sW[(r16 + 32) * 200 + kb]);
            f16x8 b3 = *reinterpret_cast<const f16x8*>(&sW[(r16 + 48) * 200 + kb]);
            acc[0][0] = __builtin_amdgcn_mfma_f32_16x16x32_f16(a0, b0, acc[0][0], 0, 0, 0);
            acc[0][1] = __builtin_amdgcn_mfma_f32_16x16x32_f16(a0, b1, acc[0][1], 0, 0, 0);
            acc[0][2] = __builtin_amdgcn_mfma_f32_16x16x32_f16(a0, b2, acc[0][2], 0, 0, 0);
            acc[0][3] = __builtin_amdgcn_mfma_f32_16x16x32_f16(a0, b3, acc[0][3], 0, 0, 0);
            acc[1][0] = __builtin_amdgcn_mfma_f32_16x16x32_f16(a1, b0, acc[1][0], 0, 0, 0);
            acc[1][1] = __builtin_amdgcn_mfma_f32_16x16x32_f16(a1, b1, acc[1][1], 0, 0, 0);
            acc[1][2] = __builtin_amdgcn_mfma_f32_16x16x32_f16(a1, b2, acc[1][2], 0, 0, 0);
            acc[1][3] = __builtin_amdgcn_mfma_f32_16x16x32_f16(a1, b3, acc[1][3], 0, 0, 0);
        }
    }

    float gv[4], bv[4];
    if (DO_LN) {
#pragma unroll
        for (int ct = 0; ct < 4; ++ct) { gv[ct] = gamma[ct * 16 + r16]; bv[ct] = beta[ct * 16 + r16]; }
    }
#pragma unroll
    for (int rt = 0; rt < 2; ++rt)
#pragma unroll
        for (int rg = 0; rg < 4; ++rg) {
            float v[4];
#pragma unroll
            for (int ct = 0; ct < 4; ++ct) v[ct] = elu_(acc[rt][ct][rg] + sB[ct * 16 + r16]);
            if (DO_LN) {
                float s  = v[0] + v[1] + v[2] + v[3];
                float qq = v[0]*v[0] + v[1]*v[1] + v[2]*v[2] + v[3]*v[3];
#pragma unroll
                for (int m = 1; m < 16; m <<= 1) { s += __shfl_xor(s, m, 64); qq += __shfl_xor(qq, m, 64); }
                float mean = s * (1.f / 64.f);
                float var  = qq * (1.f / 64.f) - mean * mean;
                float rstd = rsqrtf(var + 1e-5f);
#pragma unroll
                for (int ct = 0; ct < 4; ++ct) v[ct] = (v[ct] - mean) * rstd * gv[ct] + bv[ct];
            }
            const int t = w * 32 + rt * 16 + q * 4 + rg;
            const size_t ob = (((size_t)bn * T_ + t) * F_ + f) * H_ + r16;
#pragma unroll
            for (int ct = 0; ct < 4; ++ct) {
                if constexpr (sizeof(TOUT) == 2) out[ob + ct * 16] = f2h(v[ct]);
                else                             out[ob + ct * 16] = v[ct];
            }
        }
}

// ---------------- dense via MFMA: elu(concat(x, e) @ W + b) — fp16 in / fp16 out ----------------
template<int NE>
__global__ __launch_bounds__(256) void dense_mfma(const unsigned short* __restrict__ x,
                                                  const float* __restrict__ e,
                                                  const float* __restrict__ W,
                                                  const float* __restrict__ bias,
                                                  unsigned short* __restrict__ out)
{
    __shared__ __align__(16) unsigned short sA[128 * 104];  // [r][k], k=0..95 (64 x | NE emb | zero)
    __shared__ __align__(16) unsigned short sW[64 * 104];   // [g][k] transposed
    __shared__ float sB[64];

    const int row0 = blockIdx.x * 128;
    const int tid  = threadIdx.x;

    if (tid < 64) sB[tid] = bias[tid];
    // x -> cols 0..63 (ushort8 copies)
    for (int idx = tid; idx < 1024; idx += 256) {
        int r = idx >> 3, c8 = (idx & 7) * 8;
        *reinterpret_cast<ushort8*>(&sA[r * 104 + c8]) =
            *reinterpret_cast<const ushort8*>(&x[(size_t)(row0 + r) * 64 + c8]);
    }
    // emb / zero -> cols 64..95 (single writer loop)
    for (int idx = tid; idx < 4096; idx += 256) {
        int r = idx >> 5, c = idx & 31;
        unsigned short v = 0;
        if (c < NE) v = f2h(e[(size_t)(row0 + r) * NE + c]);
        sA[r * 104 + 64 + c] = v;
    }
    // W rows 0..63 transposed
    for (int idx = tid; idx < 4096; idx += 256) {
        int g = idx & 63, k = idx >> 6;
        sW[g * 104 + k] = f2h(W[k * 64 + g]);
    }
    // W rows 64..95 (emb rows or zero)
    for (int idx = tid; idx < 2048; idx += 256) {
        int g = idx >> 5, c = idx & 31;
        unsigned short v = 0;
        if (c < NE) v = f2h(W[(64 + c) * 64 + g]);
        sW[g * 104 + 64 + c] = v;
    }
    __syncthreads();

    const int lane = tid & 63, w = tid >> 6;
    const int r16 = lane & 15, q = lane >> 4;

    f32x4 dacc[2][4];
#pragma unroll
    for (int i = 0; i < 2; i++)
#pragma unroll
        for (int j = 0; j < 4; j++) dacc[i][j] = {0.f, 0.f, 0.f, 0.f};

#pragma unroll
    for (int ks = 0; ks < 3; ++ks) {
        const int ko = ks * 32 + q * 8;
        f16x8 a0 = *reinterpret_cast<const f16x8*>(&sA[(w * 32 + r16) * 104 + ko]);
        f16x8 a1 = *reinterpret_cast<const f16x8*>(&sA[(w * 32 + 16 + r16) * 104 + ko]);
#pragma unroll
        for (int nt = 0; nt < 4; ++nt) {
            f16x8 bb = *reinterpret_cast<const f16x8*>(&sW[(nt * 16 + r16) * 104 + ko]);
            dacc[0][nt] = __builtin_amdgcn_mfma_f32_16x16x32_f16(a0, bb, dacc[0][nt], 0, 0, 0);
            dacc[1][nt] = __builtin_amdgcn_mfma_f32_16x16x32_f16(a1, bb, dacc[1][nt], 0, 0, 0);
        }
    }

    float bg[4];
#pragma unroll
    for (int nt = 0; nt < 4; ++nt) bg[nt] = sB[nt * 16 + r16];
#pragma unroll
    for (int rt = 0; rt < 2; ++rt)
#pragma unroll
        for (int rg = 0; rg < 4; ++rg) {
            const int r = w * 32 + rt * 16 + q * 4 + rg;
            const size_t ob = (size_t)(row0 + r) * 64 + r16;
#pragma unroll
            for (int nt = 0; nt < 4; ++nt)
                out[ob + nt * 16] = f2h(elu_(dacc[rt][nt][rg] + bg[nt]));
        }
}

// ---------------- node mix via MFMA + LN_G — fp16 in / fp16 out ----------------
__global__ __launch_bounds__(256) void nodemix_mfma(const unsigned short* __restrict__ d1,
                                                    const float* __restrict__ adjG,
                                                    const float* __restrict__ gamma,
                                                    const float* __restrict__ beta,
                                                    unsigned short* __restrict__ nmo)
{
    __shared__ __align__(16) unsigned short sAdj[64 * 72];  // [m][n]
    __shared__ __align__(16) unsigned short sXT[64 * 88];   // [h][n]

    const int f = blockIdx.x & 15, t = (blockIdx.x >> 4) & 127, b = blockIdx.x >> 11;
    const int tid = threadIdx.x, lane = tid & 63, w = tid >> 6;

    for (int idx = tid; idx < 4096; idx += 256) {
        int m = idx >> 6, n = idx & 63;
        sAdj[m * 72 + n] = f2h(adjG[idx]);
    }
    {
        const int n = lane;
        const size_t base = (((size_t)(b * 64 + n) * T_ + t) * F_ + f) * H_;
#pragma unroll
        for (int p = 0; p < 2; ++p) {
            int c = w + p * 4;
            ushort8 v = *reinterpret_cast<const ushort8*>(&d1[base + c * 8]);
#pragma unroll
            for (int i = 0; i < 8; ++i) sXT[(c * 8 + i) * 88 + n] = v[i];
        }
    }
    __syncthreads();

    const int r16 = lane & 15, q = lane >> 4;
    f32x4 acc[4];
#pragma unroll
    for (int j = 0; j < 4; j++) acc[j] = {0.f, 0.f, 0.f, 0.f};

#pragma unroll
    for (int ks = 0; ks < 2; ++ks) {
        f16x8 af = *reinterpret_cast<const f16x8*>(&sAdj[(w * 16 + r16) * 72 + ks * 32 + q * 8]);
#pragma unroll
        for (int ht = 0; ht < 4; ++ht) {
            f16x8 bfv = *reinterpret_cast<const f16x8*>(&sXT[(ht * 16 + r16) * 88 + ks * 32 + q * 8]);
            acc[ht] = __builtin_amdgcn_mfma_f32_16x16x32_f16(af, bfv, acc[ht], 0, 0, 0);
        }
    }

    float gm[4], bt[4];
#pragma unroll
    for (int ht = 0; ht < 4; ++ht) { gm[ht] = gamma[ht * 16 + r16]; bt[ht] = beta[ht * 16 + r16]; }
#pragma unroll
    for (int reg = 0; reg < 4; ++reg) {
        const int m = w * 16 + q * 4 + reg;
        float v[4];
#pragma unroll
        for (int ht = 0; ht < 4; ++ht) v[ht] = acc[ht][reg];
        float s  = v[0] + v[1] + v[2] + v[3];
        float qq = v[0]*v[0] + v[1]*v[1] + v[2]*v[2] + v[3]*v[3];
#pragma unroll
        for (int msk = 1; msk < 16; msk <<= 1) { s += __shfl_xor(s, msk, 64); qq += __shfl_xor(qq, msk, 64); }
        float mean = s * (1.f / 64.f);
        float var  = qq * (1.f / 64.f) - mean * mean;
        float rstd = rsqrtf(var + 1e-5f);
        const size_t ob = (((size_t)(b * 64 + m) * T_ + t) * F_ + f) * H_ + r16;
#pragma unroll
        for (int ht = 0; ht < 4; ++ht)
            nmo[ob + ht * 16] = f2h((v[ht] - mean) * rstd * gm[ht] + bt[ht]);
    }
}

// ---------------- feature mix + LN + residual — NEW (g,hq) layout, fp16 input ----------------
__global__ __launch_bounds__(256) void featmix_v2(const unsigned short* __restrict__ e,
                                                  const float* __restrict__ adjg,
                                                  const float* __restrict__ gamma,
                                                  const float* __restrict__ beta,
                                                  const float* __restrict__ res,
                                                  float* __restrict__ out)
{
    __shared__ __align__(16) unsigned short se[16 * 64];   // [f][h]

    const int t = blockIdx.x & 127, bn = blockIdx.x >> 7;
    const int tid = threadIdx.x;
    const size_t base = ((size_t)bn * T_ + t) * F_ * H_;

    {   // stage 16x64 fp16: 4 shorts/thread, coalesced
        int f = tid >> 4, c4 = (tid & 15) * 4;
        *reinterpret_cast<ushort4*>(&se[f * 64 + c4]) =
            *reinterpret_cast<const ushort4*>(&e[base + f * 64 + c4]);
    }
    __syncthreads();

    const int g = tid >> 4, hq = tid & 15;   // thread owns (g, h=hq*4..hq*4+3)
    float ag[16];
#pragma unroll
    for (int f = 0; f < 16; ++f) ag[f] = adjg[g * 16 + f];

    float a[4] = {0.f, 0.f, 0.f, 0.f};
#pragma unroll
    for (int f = 0; f < 16; ++f) {
        ushort4 dv = *reinterpret_cast<const ushort4*>(&se[f * 64 + hq * 4]);
        float av = ag[f];
        a[0] = fmaf(av, h2f(dv.x), a[0]);
        a[1] = fmaf(av, h2f(dv.y), a[1]);
        a[2] = fmaf(av, h2f(dv.z), a[2]);
        a[3] = fmaf(av, h2f(dv.w), a[3]);
    }
    // LN over h: 16-lane group (same g), 4 h per thread -> 8 shuffle ops total
    float s  = a[0] + a[1] + a[2] + a[3];
    float qv = a[0]*a[0] + a[1]*a[1] + a[2]*a[2] + a[3]*a[3];
#pragma unroll
    for (int m = 1; m < 16; m <<= 1) { s += __shfl_xor(s, m, 64); qv += __shfl_xor(qv, m, 64); }
    float mean = s * (1.f / 64.f);
    float var  = qv * (1.f / 64.f) - mean * mean;
    float rstd = rsqrtf(var + 1e-5f);

    const size_t o = base + (size_t)g * 64 + hq * 4;
    float4 rv = *reinterpret_cast<const float4*>(res + o);
    float4 ov;
    ov.x = (a[0] - mean) * rstd * gamma[hq * 4 + 0] + beta[hq * 4 + 0] + rv.x;
    ov.y = (a[1] - mean) * rstd * gamma[hq * 4 + 1] + beta[hq * 4 + 1] + rv.y;
    ov.z = (a[2] - mean) * rstd * gamma[hq * 4 + 2] + beta[hq * 4 + 2] + rv.z;
    ov.w = (a[3] - mean) * rstd * gamma[hq * 4 + 3] + beta[hq * 4 + 3] + rv.w;
    *reinterpret_cast<float4*>(out + o) = ov;
}

extern "C" void kernel_launch(void* const* d_in, const int* in_sizes, int n_in,
                              void* d_out, int out_size, void* d_ws, size_t ws_size,
                              hipStream_t stream)
{
    const float* h_in    = (const float*)d_in[0];
    const float* embs_G  = (const float*)d_in[2];
    const float* embs_g  = (const float*)d_in[3];
    const float* adj_G   = (const float*)d_in[4];
    const float* adj_g   = (const float*)d_in[5];
    const float* Wt0 = (const float*)d_in[6];  const float* bt0 = (const float*)d_in[7];
    const float* Wt1 = (const float*)d_in[8];  const float* bt1 = (const float*)d_in[9];
    const float* Wt2 = (const float*)d_in[10]; const float* bt2 = (const float*)d_in[11];
    const float* gamma_t = (const float*)d_in[12]; const float* beta_t = (const float*)d_in[13];
    const float* W_G = (const float*)d_in[14]; const float* b_G = (const float*)d_in[15];
    const float* gamma_G = (const float*)d_in[16]; const float* beta_G = (const float*)d_in[17];
    const float* W_g = (const float*)d_in[18]; const float* b_g = (const float*)d_in[19];
    const float* gamma_g = (const float*)d_in[20]; const float* beta_g = (const float*)d_in[21];

    float* out = (float*)d_out;
    char*  ws  = (char*)d_ws;
    // fp16 64MiB regions: c0@0, c1@64, c2@128, d1@192; nm reuses c0; d2 reuses c1
    unsigned short* c0 = (unsigned short*)ws;
    unsigned short* c1 = (unsigned short*)(ws + ((size_t)64  << 20));
    unsigned short* c2 = (unsigned short*)(ws + ((size_t)128 << 20));
    unsigned short* d1 = (unsigned short*)(ws + ((size_t)192 << 20));
    unsigned short* nm = (unsigned short*)ws;                          // c0 dead
    unsigned short* d2 = (unsigned short*)(ws + ((size_t)64  << 20));  // c1 dead

    tconv_mfma<1, false, float,          unsigned short><<<4096, 256, 0, stream>>>(h_in, Wt0, bt0, nullptr, nullptr, c0);
    tconv_mfma<2, false, unsigned short, unsigned short><<<4096, 256, 0, stream>>>(c0,   Wt1, bt1, nullptr, nullptr, c1);
    tconv_mfma<4, true,  unsigned short, unsigned short><<<4096, 256, 0, stream>>>(c1,   Wt2, bt2, gamma_t, beta_t, c2);

    dense_mfma<16><<<4096, 256, 0, stream>>>(c2, embs_G, W_G, b_G, d1);
    nodemix_mfma<<<8192, 256, 0, stream>>>(d1, adj_G, gamma_G, beta_G, nm);
    dense_mfma<8><<<4096, 256, 0, stream>>>(nm, embs_g, W_g, b_g, d2);
    featmix_v2<<<32768, 256, 0, stream>>>(d2, adj_g, gamma_g, beta_g, h_in, out);
}

// Round 9
// 414.573 us; speedup vs baseline: 2.9946x; 1.0213x over previous
//
#include <hip/hip_runtime.h>

#define BN_ 256
#define T_  128
#define F_  16
#define H_  64

using f16x8   = __attribute__((ext_vector_type(8))) _Float16;
using f32x4   = __attribute__((ext_vector_type(4))) float;
using ushort8 = __attribute__((ext_vector_type(8))) unsigned short;

__device__ __forceinline__ float elu_(float x) { return x > 0.f ? x : __expf(x) - 1.f; }
__device__ __forceinline__ unsigned short f2h(float x) {
    union { _Float16 h; unsigned short u; } v; v.h = (_Float16)x; return v.u;
}
__device__ __forceinline__ float h2f(unsigned short u) {
    union { unsigned short u; _Float16 h; } v; v.u = u; return (float)v.h;
}

// ---------------- prep: conv weights -> fp16 transposed [l][f][g][192] ----------------
__global__ __launch_bounds__(256) void prep_w(const float* __restrict__ Wt0,
                                              const float* __restrict__ Wt1,
                                              const float* __restrict__ Wt2,
                                              unsigned short* __restrict__ pw)
{
    __shared__ unsigned short sW[64 * 200];
    const int lf = blockIdx.x, l = lf >> 4, f = lf & 15;
    const float* W = (l == 0) ? Wt0 : ((l == 1) ? Wt1 : Wt2);
    const int tid = threadIdx.x;

    for (int idx = tid; idx < 3 * 4096; idx += 256) {
        int tap = idx >> 12, rem = idx & 4095;
        int h = rem >> 6, g = rem & 63;
        sW[g * 200 + tap * 64 + h] = f2h(W[(size_t)(tap * 16 + f) * 4096 + rem]);
    }
    __syncthreads();
    for (int idx = tid; idx < 64 * 24; idx += 256) {
        int g = idx / 24, k8 = idx - g * 24;
        *reinterpret_cast<ushort8*>(&pw[((size_t)lf * 64 + g) * 192 + k8 * 8]) =
            *reinterpret_cast<const ushort8*>(&sW[g * 200 + k8 * 8]);
    }
}

// ---------------- prep: adjG [64][72], W_G [64][104], W_g [64][104] (fp16, zero-padded) ----------------
__global__ __launch_bounds__(256) void prep_small(const float* __restrict__ adjG,
                                                  const float* __restrict__ W_G,
                                                  const float* __restrict__ W_g,
                                                  unsigned short* __restrict__ padj,
                                                  unsigned short* __restrict__ pWG,
                                                  unsigned short* __restrict__ pWg)
{
    const int tid = threadIdx.x;
    for (int idx = tid; idx < 4608; idx += 256) {
        int m = idx / 72, n = idx - m * 72;
        padj[idx] = (n < 64) ? f2h(adjG[m * 64 + n]) : (unsigned short)0;
    }
    for (int idx = tid; idx < 6656; idx += 256) {
        int g = idx / 104, k = idx - g * 104;
        pWG[idx] = (k < 80) ? f2h(W_G[k * 64 + g]) : (unsigned short)0;
    }
    for (int idx = tid; idx < 6656; idx += 256) {
        int g = idx / 104, k = idx - g * 104;
        pWg[idx] = (k < 72) ? f2h(W_g[k * 64 + g]) : (unsigned short)0;
    }
}

// ---------------- temporal conv via MFMA, optional fused LN (compute verified; staging vectorized) ----------------
template<int DIL, bool DO_LN, typename TIN, typename TOUT>
__global__ __launch_bounds__(256) void tconv_mfma(const TIN* __restrict__ in,
                                                  const unsigned short* __restrict__ pwL,  // [f][g][192]
                                                  const float* __restrict__ bias,
                                                  const float* __restrict__ gamma,
                                                  const float* __restrict__ beta,
                                                  TOUT* __restrict__ out)
{
    __shared__ __align__(16) unsigned short sA[136 * 72];
    __shared__ __align__(16) unsigned short sW[64 * 200];
    __shared__ float sB[64];

    const int f   = blockIdx.x & 15;
    const int bn  = blockIdx.x >> 4;
    const int tid = threadIdx.x;

    if (tid < 64) sB[tid] = bias[f * 64 + tid];
    // weights: pure ushort8 copies from pre-transposed global
    {
        const unsigned short* wsrc = pwL + (size_t)f * 64 * 192;
        for (int idx = tid; idx < 1536; idx += 256) {
            int g = idx / 24, k8 = idx - g * 24;
            *reinterpret_cast<ushort8*>(&sW[g * 200 + k8 * 8]) =
                *reinterpret_cast<const ushort8*>(&wsrc[g * 192 + k8 * 8]);
        }
    }
    for (int idx = tid; idx < 136 * 16; idx += 256) {
        int r = idx >> 4, h4 = (idx & 15) * 4;
        int t = r - 4;
        ushort4 v = {0, 0, 0, 0};
        if (t >= 0 && t < T_) {
            const size_t base = (((size_t)bn * T_ + t) * F_ + f) * H_ + h4;
            if constexpr (sizeof(TIN) == 4) {
                float4 x = *reinterpret_cast<const float4*>(in + base);
                v.x = f2h(x.x); v.y = f2h(x.y); v.z = f2h(x.z); v.w = f2h(x.w);
            } else {
                v = *reinterpret_cast<const ushort4*>(in + base);
            }
        }
        *reinterpret_cast<ushort4*>(&sA[r * 72 + h4]) = v;
    }
    __syncthreads();

    const int lane = tid & 63, w = tid >> 6;
    const int r16 = lane & 15, q = lane >> 4;

    f32x4 acc[2][4];
#pragma unroll
    for (int i = 0; i < 2; i++)
#pragma unroll
        for (int j = 0; j < 4; j++) acc[i][j] = {0.f, 0.f, 0.f, 0.f};

#pragma unroll
    for (int tap = 0; tap < 3; ++tap) {
        const int row0 = w * 32 + r16 + 4 + (tap - 1) * DIL;
#pragma unroll
        for (int ks = 0; ks < 2; ++ks) {
            const int ko = ks * 32 + q * 8;
            f16x8 a0 = *reinterpret_cast<const f16x8*>(&sA[row0 * 72 + ko]);
            f16x8 a1 = *reinterpret_cast<const f16x8*>(&sA[(row0 + 16) * 72 + ko]);
            const int kb = tap * 64 + ko;
            f16x8 b0 = *reinterpret_cast<const f16x8*>(&sW[(r16     ) * 200 + kb]);
            f16x8 b1 = *reinterpret_cast<const f16x8*>(&sW[(r16 + 16) * 200 + kb]);
            f16x8 b2 = *reinterpret_cast<const f16x8*>(&sW[(r16 + 32) * 200 + kb]);
            f16x8 b3 = *reinterpret_cast<const f16x8*>(&sW[(r16 + 48) * 200 + kb]);
            acc[0][0] = __builtin_amdgcn_mfma_f32_16x16x32_f16(a0, b0, acc[0][0], 0, 0, 0);
            acc[0][1] = __builtin_amdgcn_mfma_f32_16x16x32_f16(a0, b1, acc[0][1], 0, 0, 0);
            acc[0][2] = __builtin_amdgcn_mfma_f32_16x16x32_f16(a0, b2, acc[0][2], 0, 0, 0);
            acc[0][3] = __builtin_amdgcn_mfma_f32_16x16x32_f16(a0, b3, acc[0][3], 0, 0, 0);
            acc[1][0] = __builtin_amdgcn_mfma_f32_16x16x32_f16(a1, b0, acc[1][0], 0, 0, 0);
            acc[1][1] = __builtin_amdgcn_mfma_f32_16x16x32_f16(a1, b1, acc[1][1], 0, 0, 0);
            acc[1][2] = __builtin_amdgcn_mfma_f32_16x16x32_f16(a1, b2, acc[1][2], 0, 0, 0);
            acc[1][3] = __builtin_amdgcn_mfma_f32_16x16x32_f16(a1, b3, acc[1][3], 0, 0, 0);
        }
    }

    float gv[4], bv[4];
    if (DO_LN) {
#pragma unroll
        for (int ct = 0; ct < 4; ++ct) { gv[ct] = gamma[ct * 16 + r16]; bv[ct] = beta[ct * 16 + r16]; }
    }
#pragma unroll
    for (int rt = 0; rt < 2; ++rt)
#pragma unroll
        for (int rg = 0; rg < 4; ++rg) {
            float v[4];
#pragma unroll
            for (int ct = 0; ct < 4; ++ct) v[ct] = elu_(acc[rt][ct][rg] + sB[ct * 16 + r16]);
            if (DO_LN) {
                float s  = v[0] + v[1] + v[2] + v[3];
                float qq = v[0]*v[0] + v[1]*v[1] + v[2]*v[2] + v[3]*v[3];
#pragma unroll
                for (int m = 1; m < 16; m <<= 1) { s += __shfl_xor(s, m, 64); qq += __shfl_xor(qq, m, 64); }
                float mean = s * (1.f / 64.f);
                float var  = qq * (1.f / 64.f) - mean * mean;
                float rstd = rsqrtf(var + 1e-5f);
#pragma unroll
                for (int ct = 0; ct < 4; ++ct) v[ct] = (v[ct] - mean) * rstd * gv[ct] + bv[ct];
            }
            const int t = w * 32 + rt * 16 + q * 4 + rg;
            const size_t ob = (((size_t)bn * T_ + t) * F_ + f) * H_ + r16;
#pragma unroll
            for (int ct = 0; ct < 4; ++ct) {
                if constexpr (sizeof(TOUT) == 2) out[ob + ct * 16] = f2h(v[ct]);
                else                             out[ob + ct * 16] = v[ct];
            }
        }
}

// ---------------- dense via MFMA (verified compute; weights from prep) ----------------
template<int NE>
__global__ __launch_bounds__(256) void dense_mfma(const unsigned short* __restrict__ x,
                                                  const float* __restrict__ e,
                                                  const unsigned short* __restrict__ pW,  // [64][104] padded
                                                  const float* __restrict__ bias,
                                                  unsigned short* __restrict__ out)
{
    __shared__ __align__(16) unsigned short sA[128 * 104];
    __shared__ __align__(16) unsigned short sW[64 * 104];
    __shared__ float sB[64];

    const int row0 = blockIdx.x * 128;
    const int tid  = threadIdx.x;

    if (tid < 64) sB[tid] = bias[tid];
    for (int idx = tid; idx < 832; idx += 256)
        reinterpret_cast<ushort8*>(sW)[idx] = reinterpret_cast<const ushort8*>(pW)[idx];
    for (int idx = tid; idx < 1024; idx += 256) {
        int r = idx >> 3, c8 = (idx & 7) * 8;
        *reinterpret_cast<ushort8*>(&sA[r * 104 + c8]) =
            *reinterpret_cast<const ushort8*>(&x[(size_t)(row0 + r) * 64 + c8]);
    }
    for (int idx = tid; idx < 4096; idx += 256) {
        int r = idx >> 5, c = idx & 31;
        unsigned short v = 0;
        if (c < NE) v = f2h(e[(size_t)(row0 + r) * NE + c]);
        sA[r * 104 + 64 + c] = v;
    }
    __syncthreads();

    const int lane = tid & 63, w = tid >> 6;
    const int r16 = lane & 15, q = lane >> 4;

    f32x4 dacc[2][4];
#pragma unroll
    for (int i = 0; i < 2; i++)
#pragma unroll
        for (int j = 0; j < 4; j++) dacc[i][j] = {0.f, 0.f, 0.f, 0.f};

#pragma unroll
    for (int ks = 0; ks < 3; ++ks) {
        const int ko = ks * 32 + q * 8;
        f16x8 a0 = *reinterpret_cast<const f16x8*>(&sA[(w * 32 + r16) * 104 + ko]);
        f16x8 a1 = *reinterpret_cast<const f16x8*>(&sA[(w * 32 + 16 + r16) * 104 + ko]);
#pragma unroll
        for (int nt = 0; nt < 4; ++nt) {
            f16x8 bb = *reinterpret_cast<const f16x8*>(&sW[(nt * 16 + r16) * 104 + ko]);
            dacc[0][nt] = __builtin_amdgcn_mfma_f32_16x16x32_f16(a0, bb, dacc[0][nt], 0, 0, 0);
            dacc[1][nt] = __builtin_amdgcn_mfma_f32_16x16x32_f16(a1, bb, dacc[1][nt], 0, 0, 0);
        }
    }

    float bg[4];
#pragma unroll
    for (int nt = 0; nt < 4; ++nt) bg[nt] = sB[nt * 16 + r16];
#pragma unroll
    for (int rt = 0; rt < 2; ++rt)
#pragma unroll
        for (int rg = 0; rg < 4; ++rg) {
            const int r = w * 32 + rt * 16 + q * 4 + rg;
            const size_t ob = (size_t)(row0 + r) * 64 + r16;
#pragma unroll
            for (int nt = 0; nt < 4; ++nt)
                out[ob + nt * 16] = f2h(elu_(dacc[rt][nt][rg] + bg[nt]));
        }
}

// ---------------- node mix via MFMA + LN_G (verified compute; adj from prep) ----------------
__global__ __launch_bounds__(256) void nodemix_mfma(const unsigned short* __restrict__ d1,
                                                    const unsigned short* __restrict__ padj,  // [64][72]
                                                    const float* __restrict__ gamma,
                                                    const float* __restrict__ beta,
                                                    unsigned short* __restrict__ nmo)
{
    __shared__ __align__(16) unsigned short sAdj[64 * 72];  // [m][n]
    __shared__ __align__(16) unsigned short sXT[64 * 88];   // [h][n]

    const int f = blockIdx.x & 15, t = (blockIdx.x >> 4) & 127, b = blockIdx.x >> 11;
    const int tid = threadIdx.x, lane = tid & 63, w = tid >> 6;

    for (int idx = tid; idx < 576; idx += 256)
        reinterpret_cast<ushort8*>(sAdj)[idx] = reinterpret_cast<const ushort8*>(padj)[idx];
    {
        const int n = lane;
        const size_t base = (((size_t)(b * 64 + n) * T_ + t) * F_ + f) * H_;
#pragma unroll
        for (int p = 0; p < 2; ++p) {
            int c = w + p * 4;
            ushort8 v = *reinterpret_cast<const ushort8*>(&d1[base + c * 8]);
#pragma unroll
            for (int i = 0; i < 8; ++i) sXT[(c * 8 + i) * 88 + n] = v[i];
        }
    }
    __syncthreads();

    const int r16 = lane & 15, q = lane >> 4;
    f32x4 acc[4];
#pragma unroll
    for (int j = 0; j < 4; j++) acc[j] = {0.f, 0.f, 0.f, 0.f};

#pragma unroll
    for (int ks = 0; ks < 2; ++ks) {
        f16x8 af = *reinterpret_cast<const f16x8*>(&sAdj[(w * 16 + r16) * 72 + ks * 32 + q * 8]);
#pragma unroll
        for (int ht = 0; ht < 4; ++ht) {
            f16x8 bfv = *reinterpret_cast<const f16x8*>(&sXT[(ht * 16 + r16) * 88 + ks * 32 + q * 8]);
            acc[ht] = __builtin_amdgcn_mfma_f32_16x16x32_f16(af, bfv, acc[ht], 0, 0, 0);
        }
    }

    float gm[4], bt[4];
#pragma unroll
    for (int ht = 0; ht < 4; ++ht) { gm[ht] = gamma[ht * 16 + r16]; bt[ht] = beta[ht * 16 + r16]; }
#pragma unroll
    for (int reg = 0; reg < 4; ++reg) {
        const int m = w * 16 + q * 4 + reg;
        float v[4];
#pragma unroll
        for (int ht = 0; ht < 4; ++ht) v[ht] = acc[ht][reg];
        float s  = v[0] + v[1] + v[2] + v[3];
        float qq = v[0]*v[0] + v[1]*v[1] + v[2]*v[2] + v[3]*v[3];
#pragma unroll
        for (int msk = 1; msk < 16; msk <<= 1) { s += __shfl_xor(s, msk, 64); qq += __shfl_xor(qq, msk, 64); }
        float mean = s * (1.f / 64.f);
        float var  = qq * (1.f / 64.f) - mean * mean;
        float rstd = rsqrtf(var + 1e-5f);
        const size_t ob = (((size_t)(b * 64 + m) * T_ + t) * F_ + f) * H_ + r16;
#pragma unroll
        for (int ht = 0; ht < 4; ++ht)
            nmo[ob + ht * 16] = f2h((v[ht] - mean) * rstd * gm[ht] + bt[ht]);
    }
}

// ---------------- feature mix + LN + residual (verified round 8) ----------------
__global__ __launch_bounds__(256) void featmix_v2(const unsigned short* __restrict__ e,
                                                  const float* __restrict__ adjg,
                                                  const float* __restrict__ gamma,
                                                  const float* __restrict__ beta,
                                                  const float* __restrict__ res,
                                                  float* __restrict__ out)
{
    __shared__ __align__(16) unsigned short se[16 * 64];   // [f][h]

    const int t = blockIdx.x & 127, bn = blockIdx.x >> 7;
    const int tid = threadIdx.x;
    const size_t base = ((size_t)bn * T_ + t) * F_ * H_;

    {
        int f = tid >> 4, c4 = (tid & 15) * 4;
        *reinterpret_cast<ushort4*>(&se[f * 64 + c4]) =
            *reinterpret_cast<const ushort4*>(&e[base + f * 64 + c4]);
    }
    __syncthreads();

    const int g = tid >> 4, hq = tid & 15;
    float ag[16];
#pragma unroll
    for (int f = 0; f < 16; ++f) ag[f] = adjg[g * 16 + f];

    float a[4] = {0.f, 0.f, 0.f, 0.f};
#pragma unroll
    for (int f = 0; f < 16; ++f) {
        ushort4 dv = *reinterpret_cast<const ushort4*>(&se[f * 64 + hq * 4]);
        float av = ag[f];
        a[0] = fmaf(av, h2f(dv.x), a[0]);
        a[1] = fmaf(av, h2f(dv.y), a[1]);
        a[2] = fmaf(av, h2f(dv.z), a[2]);
        a[3] = fmaf(av, h2f(dv.w), a[3]);
    }
    float s  = a[0] + a[1] + a[2] + a[3];
    float qv = a[0]*a[0] + a[1]*a[1] + a[2]*a[2] + a[3]*a[3];
#pragma unroll
    for (int m = 1; m < 16; m <<= 1) { s += __shfl_xor(s, m, 64); qv += __shfl_xor(qv, m, 64); }
    float mean = s * (1.f / 64.f);
    float var  = qv * (1.f / 64.f) - mean * mean;
    float rstd = rsqrtf(var + 1e-5f);

    const size_t o = base + (size_t)g * 64 + hq * 4;
    float4 rv = *reinterpret_cast<const float4*>(res + o);
    float4 ov;
    ov.x = (a[0] - mean) * rstd * gamma[hq * 4 + 0] + beta[hq * 4 + 0] + rv.x;
    ov.y = (a[1] - mean) * rstd * gamma[hq * 4 + 1] + beta[hq * 4 + 1] + rv.y;
    ov.z = (a[2] - mean) * rstd * gamma[hq * 4 + 2] + beta[hq * 4 + 2] + rv.z;
    ov.w = (a[3] - mean) * rstd * gamma[hq * 4 + 3] + beta[hq * 4 + 3] + rv.w;
    *reinterpret_cast<float4*>(out + o) = ov;
}

extern "C" void kernel_launch(void* const* d_in, const int* in_sizes, int n_in,
                              void* d_out, int out_size, void* d_ws, size_t ws_size,
                              hipStream_t stream)
{
    const float* h_in    = (const float*)d_in[0];
    const float* embs_G  = (const float*)d_in[2];
    const float* embs_g  = (const float*)d_in[3];
    const float* adj_G   = (const float*)d_in[4];
    const float* adj_g   = (const float*)d_in[5];
    const float* Wt0 = (const float*)d_in[6];  const float* bt0 = (const float*)d_in[7];
    const float* Wt1 = (const float*)d_in[8];  const float* bt1 = (const float*)d_in[9];
    const float* Wt2 = (const float*)d_in[10]; const float* bt2 = (const float*)d_in[11];
    const float* gamma_t = (const float*)d_in[12]; const float* beta_t = (const float*)d_in[13];
    const float* W_G = (const float*)d_in[14]; const float* b_G = (const float*)d_in[15];
    const float* gamma_G = (const float*)d_in[16]; const float* beta_G = (const float*)d_in[17];
    const float* W_g = (const float*)d_in[18]; const float* b_g = (const float*)d_in[19];
    const float* gamma_g = (const float*)d_in[20]; const float* beta_g = (const float*)d_in[21];

    float* out = (float*)d_out;
    char*  ws  = (char*)d_ws;
    // fp16 64MiB regions: buf A@0, B@64MiB, C@128MiB; prep @192MiB (~1.2MB)
    unsigned short* c0 = (unsigned short*)ws;
    unsigned short* c1 = (unsigned short*)(ws + ((size_t)64  << 20));
    unsigned short* c2 = (unsigned short*)(ws + ((size_t)128 << 20));
    unsigned short* d1 = c0;   // c0 dead after conv1
    unsigned short* nm = c1;   // c1 dead after conv2
    unsigned short* d2 = c2;   // c2 dead after dense1

    unsigned short* prep = (unsigned short*)(ws + ((size_t)192 << 20));
    unsigned short* pw   = prep;                 // 3*16*64*192 = 589824
    unsigned short* pWG  = prep + 589824;        // 6656
    unsigned short* pWg  = pWG + 6656;           // 6656
    unsigned short* padj = pWg + 6656;           // 4608

    prep_w<<<48, 256, 0, stream>>>(Wt0, Wt1, Wt2, pw);
    prep_small<<<1, 256, 0, stream>>>(adj_G, W_G, W_g, padj, pWG, pWg);

    const size_t LSTRIDE = (size_t)16 * 64 * 192;
    tconv_mfma<1, false, float,          unsigned short><<<4096, 256, 0, stream>>>(h_in, pw,               bt0, nullptr, nullptr, c0);
    tconv_mfma<2, false, unsigned short, unsigned short><<<4096, 256, 0, stream>>>(c0,   pw + LSTRIDE,     bt1, nullptr, nullptr, c1);
    tconv_mfma<4, true,  unsigned short, unsigned short><<<4096, 256, 0, stream>>>(c1,   pw + 2 * LSTRIDE, bt2, gamma_t, beta_t, c2);

    dense_mfma<16><<<4096, 256, 0, stream>>>(c2, embs_G, pWG, b_G, d1);
    nodemix_mfma<<<8192, 256, 0, stream>>>(d1, padj, gamma_G, beta_G, nm);
    dense_mfma<8><<<4096, 256, 0, stream>>>(nm, embs_g, pWg, b_g, d2);
    featmix_v2<<<32768, 256, 0, stream>>>(d2, adj_g, gamma_g, beta_g, h_in, out);
}

// Round 10
// 366.380 us; speedup vs baseline: 3.3885x; 1.1315x over previous
//
#include <hip/hip_runtime.h>

#define BN_ 256
#define T_  128
#define F_  16
#define H_  64

using f16x8   = __attribute__((ext_vector_type(8))) _Float16;
using f32x4   = __attribute__((ext_vector_type(4))) float;
using ushort8 = __attribute__((ext_vector_type(8))) unsigned short;

__device__ __forceinline__ float elu_(float x) { return x > 0.f ? x : __expf(x) - 1.f; }
__device__ __forceinline__ unsigned short f2h(float x) {
    union { _Float16 h; unsigned short u; } v; v.h = (_Float16)x; return v.u;
}
__device__ __forceinline__ float h2f(unsigned short u) {
    union { unsigned short u; _Float16 h; } v; v.u = u; return (float)v.h;
}

// ---------------- prep: conv weights -> fp16 transposed [l][f][g][192] ----------------
__global__ __launch_bounds__(256) void prep_w(const float* __restrict__ Wt0,
                                              const float* __restrict__ Wt1,
                                              const float* __restrict__ Wt2,
                                              unsigned short* __restrict__ pw)
{
    __shared__ unsigned short sW[64 * 200];
    const int lf = blockIdx.x, l = lf >> 4, f = lf & 15;
    const float* W = (l == 0) ? Wt0 : ((l == 1) ? Wt1 : Wt2);
    const int tid = threadIdx.x;

    for (int idx = tid; idx < 3 * 4096; idx += 256) {
        int tap = idx >> 12, rem = idx & 4095;
        int h = rem >> 6, g = rem & 63;
        sW[g * 200 + tap * 64 + h] = f2h(W[(size_t)(tap * 16 + f) * 4096 + rem]);
    }
    __syncthreads();
    for (int idx = tid; idx < 64 * 24; idx += 256) {
        int g = idx / 24, k8 = idx - g * 24;
        *reinterpret_cast<ushort8*>(&pw[((size_t)lf * 64 + g) * 192 + k8 * 8]) =
            *reinterpret_cast<const ushort8*>(&sW[g * 200 + k8 * 8]);
    }
}

// ---------------- prep: adjG [64][72], W_G [64][104], W_g [64][104] (fp16, zero-padded) ----------------
__global__ __launch_bounds__(256) void prep_small(const float* __restrict__ adjG,
                                                  const float* __restrict__ W_G,
                                                  const float* __restrict__ W_g,
                                                  unsigned short* __restrict__ padj,
                                                  unsigned short* __restrict__ pWG,
                                                  unsigned short* __restrict__ pWg)
{
    const int tid = threadIdx.x;
    for (int idx = tid; idx < 4608; idx += 256) {
        int m = idx / 72, n = idx - m * 72;
        padj[idx] = (n < 64) ? f2h(adjG[m * 64 + n]) : (unsigned short)0;
    }
    for (int idx = tid; idx < 6656; idx += 256) {
        int g = idx / 104, k = idx - g * 104;
        pWG[idx] = (k < 80) ? f2h(W_G[k * 64 + g]) : (unsigned short)0;
    }
    for (int idx = tid; idx < 6656; idx += 256) {
        int g = idx / 104, k = idx - g * 104;
        pWg[idx] = (k < 72) ? f2h(W_g[k * 64 + g]) : (unsigned short)0;
    }
}

// ---------------- fused: tconv x3 (+LN_t) + dense_G, all per (bn,f) tile ----------------
__global__ __launch_bounds__(256) void conv_chain(const float* __restrict__ in,
                                                  const unsigned short* __restrict__ pw,   // [l][f][g][192]
                                                  const float* __restrict__ bt0,
                                                  const float* __restrict__ bt1,
                                                  const float* __restrict__ bt2,
                                                  const float* __restrict__ gamma,
                                                  const float* __restrict__ beta,
                                                  const float* __restrict__ embs_G,
                                                  const unsigned short* __restrict__ pWG,  // [64][104]
                                                  const float* __restrict__ b_G,
                                                  unsigned short* __restrict__ d1)
{
    __shared__ __align__(16) char smem[45184];
    unsigned short* tile = (unsigned short*)smem;             // [136][72] conv tile (rows t=-4..131)
    unsigned short* sW   = (unsigned short*)(smem + 19584);   // [64][200] conv weights (stride 200: bank-safe)
    unsigned short* sA1  = (unsigned short*)smem;             // [128][104] dense A (overlay, conv tile dead)
    unsigned short* sWG  = (unsigned short*)(smem + 26624);   // [64][104] dense W (overlay, inside old sW)

    const int f   = blockIdx.x & 15;
    const int bn  = blockIdx.x >> 4;
    const int tid = threadIdx.x;
    const int lane = tid & 63, w = tid >> 6;
    const int r16 = lane & 15, q = lane >> 4;

    // ---- stage input tile (f32 -> fp16, zero halo) + layer-0 weights ----
    for (int idx = tid; idx < 136 * 16; idx += 256) {
        int r = idx >> 4, h4 = (idx & 15) * 4;
        int t = r - 4;
        ushort4 v = {0, 0, 0, 0};
        if (t >= 0 && t < T_) {
            float4 x = *reinterpret_cast<const float4*>(in + (((size_t)bn * T_ + t) * F_ + f) * H_ + h4);
            v.x = f2h(x.x); v.y = f2h(x.y); v.z = f2h(x.z); v.w = f2h(x.w);
        }
        *reinterpret_cast<ushort4*>(&tile[r * 72 + h4]) = v;
    }
    {
        const unsigned short* wsrc = pw + (size_t)f * 64 * 192;
        for (int idx = tid; idx < 1536; idx += 256) {
            int g = idx / 24, k8 = idx - g * 24;
            *reinterpret_cast<ushort8*>(&sW[g * 200 + k8 * 8]) =
                *reinterpret_cast<const ushort8*>(&wsrc[g * 192 + k8 * 8]);
        }
    }
    __syncthreads();

    float vv[2][4][4];   // [rt][rg][ct] epilogue registers

    // ---- conv layers 0..2 ----
    for (int l = 0; l < 3; ++l) {
        const int dil = 1 << l;
        const float* biasL = (l == 0) ? bt0 : ((l == 1) ? bt1 : bt2);

        f32x4 acc[2][4];
#pragma unroll
        for (int i = 0; i < 2; i++)
#pragma unroll
            for (int j = 0; j < 4; j++) acc[i][j] = {0.f, 0.f, 0.f, 0.f};

#pragma unroll
        for (int tap = 0; tap < 3; ++tap) {
            const int row0 = w * 32 + r16 + 4 + (tap - 1) * dil;
#pragma unroll
            for (int ks = 0; ks < 2; ++ks) {
                const int ko = ks * 32 + q * 8;
                f16x8 a0 = *reinterpret_cast<const f16x8*>(&tile[row0 * 72 + ko]);
                f16x8 a1 = *reinterpret_cast<const f16x8*>(&tile[(row0 + 16) * 72 + ko]);
                const int kb = tap * 64 + ko;
                f16x8 b0 = *reinterpret_cast<const f16x8*>(&sW[(r16     ) * 200 + kb]);
                f16x8 b1 = *reinterpret_cast<const f16x8*>(&sW[(r16 + 16) * 200 + kb]);
                f16x8 b2 = *reinterpret_cast<const f16x8*>(&sW[(r16 + 32) * 200 + kb]);
                f16x8 b3 = *reinterpret_cast<const f16x8*>(&sW[(r16 + 48) * 200 + kb]);
                acc[0][0] = __builtin_amdgcn_mfma_f32_16x16x32_f16(a0, b0, acc[0][0], 0, 0, 0);
                acc[0][1] = __builtin_amdgcn_mfma_f32_16x16x32_f16(a0, b1, acc[0][1], 0, 0, 0);
                acc[0][2] = __builtin_amdgcn_mfma_f32_16x16x32_f16(a0, b2, acc[0][2], 0, 0, 0);
                acc[0][3] = __builtin_amdgcn_mfma_f32_16x16x32_f16(a0, b3, acc[0][3], 0, 0, 0);
                acc[1][0] = __builtin_amdgcn_mfma_f32_16x16x32_f16(a1, b0, acc[1][0], 0, 0, 0);
                acc[1][1] = __builtin_amdgcn_mfma_f32_16x16x32_f16(a1, b1, acc[1][1], 0, 0, 0);
                acc[1][2] = __builtin_amdgcn_mfma_f32_16x16x32_f16(a1, b2, acc[1][2], 0, 0, 0);
                acc[1][3] = __builtin_amdgcn_mfma_f32_16x16x32_f16(a1, b3, acc[1][3], 0, 0, 0);
            }
        }

        // epilogue into regs: bias + ELU (+ LN_t on last layer)
        float bg[4];
#pragma unroll
        for (int ct = 0; ct < 4; ++ct) bg[ct] = biasL[f * 64 + ct * 16 + r16];
#pragma unroll
        for (int rt = 0; rt < 2; ++rt)
#pragma unroll
            for (int rg = 0; rg < 4; ++rg) {
#pragma unroll
                for (int ct = 0; ct < 4; ++ct) vv[rt][rg][ct] = elu_(acc[rt][ct][rg] + bg[ct]);
                if (l == 2) {
                    float s  = vv[rt][rg][0] + vv[rt][rg][1] + vv[rt][rg][2] + vv[rt][rg][3];
                    float qq = vv[rt][rg][0]*vv[rt][rg][0] + vv[rt][rg][1]*vv[rt][rg][1]
                             + vv[rt][rg][2]*vv[rt][rg][2] + vv[rt][rg][3]*vv[rt][rg][3];
#pragma unroll
                    for (int m = 1; m < 16; m <<= 1) { s += __shfl_xor(s, m, 64); qq += __shfl_xor(qq, m, 64); }
                    float mean = s * (1.f / 64.f);
                    float var  = qq * (1.f / 64.f) - mean * mean;
                    float rstd = rsqrtf(var + 1e-5f);
#pragma unroll
                    for (int ct = 0; ct < 4; ++ct)
                        vv[rt][rg][ct] = (vv[rt][rg][ct] - mean) * rstd * gamma[ct * 16 + r16] + beta[ct * 16 + r16];
                }
            }
        __syncthreads();   // all tile/sW reads for this layer complete

        if (l < 2) {
            // write layer output back into tile (halo rows stay zero), stage next layer's weights
#pragma unroll
            for (int rt = 0; rt < 2; ++rt)
#pragma unroll
                for (int rg = 0; rg < 4; ++rg) {
                    const int t = w * 32 + rt * 16 + q * 4 + rg;
#pragma unroll
                    for (int ct = 0; ct < 4; ++ct)
                        tile[(t + 4) * 72 + ct * 16 + r16] = f2h(vv[rt][rg][ct]);
                }
            const unsigned short* wsrc = pw + ((size_t)((l + 1) * 16 + f) * 64) * 192;
            for (int idx = tid; idx < 1536; idx += 256) {
                int g = idx / 24, k8 = idx - g * 24;
                *reinterpret_cast<ushort8*>(&sW[g * 200 + k8 * 8]) =
                    *reinterpret_cast<const ushort8*>(&wsrc[g * 192 + k8 * 8]);
            }
            __syncthreads();
        }
    }

    // ---- dense phase: sA1 = [t][ h(0..63) | embs_G(64..79) | 0(80..95) ], sWG from prep ----
#pragma unroll
    for (int rt = 0; rt < 2; ++rt)
#pragma unroll
        for (int rg = 0; rg < 4; ++rg) {
            const int t = w * 32 + rt * 16 + q * 4 + rg;
#pragma unroll
            for (int ct = 0; ct < 4; ++ct)
                sA1[t * 104 + ct * 16 + r16] = f2h(vv[rt][rg][ct]);
        }
    for (int idx = tid; idx < 4096; idx += 256) {
        int r = idx >> 5, c = idx & 31;
        unsigned short v = 0;
        if (c < 16) v = f2h(embs_G[(((size_t)bn * T_ + r) * F_ + f) * 16 + c]);
        sA1[r * 104 + 64 + c] = v;
    }
    for (int idx = tid; idx < 832; idx += 256)
        reinterpret_cast<ushort8*>(sWG)[idx] = reinterpret_cast<const ushort8*>(pWG)[idx];
    __syncthreads();

    f32x4 dacc[2][4];
#pragma unroll
    for (int i = 0; i < 2; i++)
#pragma unroll
        for (int j = 0; j < 4; j++) dacc[i][j] = {0.f, 0.f, 0.f, 0.f};

#pragma unroll
    for (int ks = 0; ks < 3; ++ks) {
        const int ko = ks * 32 + q * 8;
        f16x8 a0 = *reinterpret_cast<const f16x8*>(&sA1[(w * 32 + r16) * 104 + ko]);
        f16x8 a1 = *reinterpret_cast<const f16x8*>(&sA1[(w * 32 + 16 + r16) * 104 + ko]);
#pragma unroll
        for (int nt = 0; nt < 4; ++nt) {
            f16x8 bb = *reinterpret_cast<const f16x8*>(&sWG[(nt * 16 + r16) * 104 + ko]);
            dacc[0][nt] = __builtin_amdgcn_mfma_f32_16x16x32_f16(a0, bb, dacc[0][nt], 0, 0, 0);
            dacc[1][nt] = __builtin_amdgcn_mfma_f32_16x16x32_f16(a1, bb, dacc[1][nt], 0, 0, 0);
        }
    }

    float bG[4];
#pragma unroll
    for (int nt = 0; nt < 4; ++nt) bG[nt] = b_G[nt * 16 + r16];
#pragma unroll
    for (int rt = 0; rt < 2; ++rt)
#pragma unroll
        for (int rg = 0; rg < 4; ++rg) {
            const int t = w * 32 + rt * 16 + q * 4 + rg;
            const size_t ob = (((size_t)bn * T_ + t) * F_ + f) * H_ + r16;
#pragma unroll
            for (int nt = 0; nt < 4; ++nt)
                d1[ob + nt * 16] = f2h(elu_(dacc[rt][nt][rg] + bG[nt]));
        }
}

// ---------------- node mix via MFMA + LN_G (verified) ----------------
__global__ __launch_bounds__(256) void nodemix_mfma(const unsigned short* __restrict__ d1,
                                                    const unsigned short* __restrict__ padj,
                                                    const float* __restrict__ gamma,
                                                    const float* __restrict__ beta,
                                                    unsigned short* __restrict__ nmo)
{
    __shared__ __align__(16) unsigned short sAdj[64 * 72];
    __shared__ __align__(16) unsigned short sXT[64 * 88];

    const int f = blockIdx.x & 15, t = (blockIdx.x >> 4) & 127, b = blockIdx.x >> 11;
    const int tid = threadIdx.x, lane = tid & 63, w = tid >> 6;

    for (int idx = tid; idx < 576; idx += 256)
        reinterpret_cast<ushort8*>(sAdj)[idx] = reinterpret_cast<const ushort8*>(padj)[idx];
    {
        const int n = lane;
        const size_t base = (((size_t)(b * 64 + n) * T_ + t) * F_ + f) * H_;
#pragma unroll
        for (int p = 0; p < 2; ++p) {
            int c = w + p * 4;
            ushort8 v = *reinterpret_cast<const ushort8*>(&d1[base + c * 8]);
#pragma unroll
            for (int i = 0; i < 8; ++i) sXT[(c * 8 + i) * 88 + n] = v[i];
        }
    }
    __syncthreads();

    const int r16 = lane & 15, q = lane >> 4;
    f32x4 acc[4];
#pragma unroll
    for (int j = 0; j < 4; j++) acc[j] = {0.f, 0.f, 0.f, 0.f};

#pragma unroll
    for (int ks = 0; ks < 2; ++ks) {
        f16x8 af = *reinterpret_cast<const f16x8*>(&sAdj[(w * 16 + r16) * 72 + ks * 32 + q * 8]);
#pragma unroll
        for (int ht = 0; ht < 4; ++ht) {
            f16x8 bfv = *reinterpret_cast<const f16x8*>(&sXT[(ht * 16 + r16) * 88 + ks * 32 + q * 8]);
            acc[ht] = __builtin_amdgcn_mfma_f32_16x16x32_f16(af, bfv, acc[ht], 0, 0, 0);
        }
    }

    float gm[4], bt[4];
#pragma unroll
    for (int ht = 0; ht < 4; ++ht) { gm[ht] = gamma[ht * 16 + r16]; bt[ht] = beta[ht * 16 + r16]; }
#pragma unroll
    for (int reg = 0; reg < 4; ++reg) {
        const int m = w * 16 + q * 4 + reg;
        float v[4];
#pragma unroll
        for (int ht = 0; ht < 4; ++ht) v[ht] = acc[ht][reg];
        float s  = v[0] + v[1] + v[2] + v[3];
        float qq = v[0]*v[0] + v[1]*v[1] + v[2]*v[2] + v[3]*v[3];
#pragma unroll
        for (int msk = 1; msk < 16; msk <<= 1) { s += __shfl_xor(s, msk, 64); qq += __shfl_xor(qq, msk, 64); }
        float mean = s * (1.f / 64.f);
        float var  = qq * (1.f / 64.f) - mean * mean;
        float rstd = rsqrtf(var + 1e-5f);
        const size_t ob = (((size_t)(b * 64 + m) * T_ + t) * F_ + f) * H_ + r16;
#pragma unroll
        for (int ht = 0; ht < 4; ++ht)
            nmo[ob + ht * 16] = f2h((v[ht] - mean) * rstd * gm[ht] + bt[ht]);
    }
}

// ---------------- dense via MFMA (verified) ----------------
template<int NE>
__global__ __launch_bounds__(256) void dense_mfma(const unsigned short* __restrict__ x,
                                                  const float* __restrict__ e,
                                                  const unsigned short* __restrict__ pW,
                                                  const float* __restrict__ bias,
                                                  unsigned short* __restrict__ out)
{
    __shared__ __align__(16) unsigned short sA[128 * 104];
    __shared__ __align__(16) unsigned short sW[64 * 104];
    __shared__ float sB[64];

    const int row0 = blockIdx.x * 128;
    const int tid  = threadIdx.x;

    if (tid < 64) sB[tid] = bias[tid];
    for (int idx = tid; idx < 832; idx += 256)
        reinterpret_cast<ushort8*>(sW)[idx] = reinterpret_cast<const ushort8*>(pW)[idx];
    for (int idx = tid; idx < 1024; idx += 256) {
        int r = idx >> 3, c8 = (idx & 7) * 8;
        *reinterpret_cast<ushort8*>(&sA[r * 104 + c8]) =
            *reinterpret_cast<const ushort8*>(&x[(size_t)(row0 + r) * 64 + c8]);
    }
    for (int idx = tid; idx < 4096; idx += 256) {
        int r = idx >> 5, c = idx & 31;
        unsigned short v = 0;
        if (c < NE) v = f2h(e[(size_t)(row0 + r) * NE + c]);
        sA[r * 104 + 64 + c] = v;
    }
    __syncthreads();

    const int lane = tid & 63, w = tid >> 6;
    const int r16 = lane & 15, q = lane >> 4;

    f32x4 dacc[2][4];
#pragma unroll
    for (int i = 0; i < 2; i++)
#pragma unroll
        for (int j = 0; j < 4; j++) dacc[i][j] = {0.f, 0.f, 0.f, 0.f};

#pragma unroll
    for (int ks = 0; ks < 3; ++ks) {
        const int ko = ks * 32 + q * 8;
        f16x8 a0 = *reinterpret_cast<const f16x8*>(&sA[(w * 32 + r16) * 104 + ko]);
        f16x8 a1 = *reinterpret_cast<const f16x8*>(&sA[(w * 32 + 16 + r16) * 104 + ko]);
#pragma unroll
        for (int nt = 0; nt < 4; ++nt) {
            f16x8 bb = *reinterpret_cast<const f16x8*>(&sW[(nt * 16 + r16) * 104 + ko]);
            dacc[0][nt] = __builtin_amdgcn_mfma_f32_16x16x32_f16(a0, bb, dacc[0][nt], 0, 0, 0);
            dacc[1][nt] = __builtin_amdgcn_mfma_f32_16x16x32_f16(a1, bb, dacc[1][nt], 0, 0, 0);
        }
    }

    float bg[4];
#pragma unroll
    for (int nt = 0; nt < 4; ++nt) bg[nt] = sB[nt * 16 + r16];
#pragma unroll
    for (int rt = 0; rt < 2; ++rt)
#pragma unroll
        for (int rg = 0; rg < 4; ++rg) {
            const int r = w * 32 + rt * 16 + q * 4 + rg;
            const size_t ob = (size_t)(row0 + r) * 64 + r16;
#pragma unroll
            for (int nt = 0; nt < 4; ++nt)
                out[ob + nt * 16] = f2h(elu_(dacc[rt][nt][rg] + bg[nt]));
        }
}

// ---------------- feature mix + LN + residual (verified) ----------------
__global__ __launch_bounds__(256) void featmix_v2(const unsigned short* __restrict__ e,
                                                  const float* __restrict__ adjg,
                                                  const float* __restrict__ gamma,
                                                  const float* __restrict__ beta,
                                                  const float* __restrict__ res,
                                                  float* __restrict__ out)
{
    __shared__ __align__(16) unsigned short se[16 * 64];

    const int t = blockIdx.x & 127, bn = blockIdx.x >> 7;
    const int tid = threadIdx.x;
    const size_t base = ((size_t)bn * T_ + t) * F_ * H_;

    {
        int f = tid >> 4, c4 = (tid & 15) * 4;
        *reinterpret_cast<ushort4*>(&se[f * 64 + c4]) =
            *reinterpret_cast<const ushort4*>(&e[base + f * 64 + c4]);
    }
    __syncthreads();

    const int g = tid >> 4, hq = tid & 15;
    float ag[16];
#pragma unroll
    for (int f = 0; f < 16; ++f) ag[f] = adjg[g * 16 + f];

    float a[4] = {0.f, 0.f, 0.f, 0.f};
#pragma unroll
    for (int f = 0; f < 16; ++f) {
        ushort4 dv = *reinterpret_cast<const ushort4*>(&se[f * 64 + hq * 4]);
        float av = ag[f];
        a[0] = fmaf(av, h2f(dv.x), a[0]);
        a[1] = fmaf(av, h2f(dv.y), a[1]);
        a[2] = fmaf(av, h2f(dv.z), a[2]);
        a[3] = fmaf(av, h2f(dv.w), a[3]);
    }
    float s  = a[0] + a[1] + a[2] + a[3];
    float qv = a[0]*a[0] + a[1]*a[1] + a[2]*a[2] + a[3]*a[3];
#pragma unroll
    for (int m = 1; m < 16; m <<= 1) { s += __shfl_xor(s, m, 64); qv += __shfl_xor(qv, m, 64); }
    float mean = s * (1.f / 64.f);
    float var  = qv * (1.f / 64.f) - mean * mean;
    float rstd = rsqrtf(var + 1e-5f);

    const size_t o = base + (size_t)g * 64 + hq * 4;
    float4 rv = *reinterpret_cast<const float4*>(res + o);
    float4 ov;
    ov.x = (a[0] - mean) * rstd * gamma[hq * 4 + 0] + beta[hq * 4 + 0] + rv.x;
    ov.y = (a[1] - mean) * rstd * gamma[hq * 4 + 1] + beta[hq * 4 + 1] + rv.y;
    ov.z = (a[2] - mean) * rstd * gamma[hq * 4 + 2] + beta[hq * 4 + 2] + rv.z;
    ov.w = (a[3] - mean) * rstd * gamma[hq * 4 + 3] + beta[hq * 4 + 3] + rv.w;
    *reinterpret_cast<float4*>(out + o) = ov;
}

extern "C" void kernel_launch(void* const* d_in, const int* in_sizes, int n_in,
                              void* d_out, int out_size, void* d_ws, size_t ws_size,
                              hipStream_t stream)
{
    const float* h_in    = (const float*)d_in[0];
    const float* embs_G  = (const float*)d_in[2];
    const float* embs_g  = (const float*)d_in[3];
    const float* adj_G   = (const float*)d_in[4];
    const float* adj_g   = (const float*)d_in[5];
    const float* Wt0 = (const float*)d_in[6];  const float* bt0 = (const float*)d_in[7];
    const float* Wt1 = (const float*)d_in[8];  const float* bt1 = (const float*)d_in[9];
    const float* Wt2 = (const float*)d_in[10]; const float* bt2 = (const float*)d_in[11];
    const float* gamma_t = (const float*)d_in[12]; const float* beta_t = (const float*)d_in[13];
    const float* W_G = (const float*)d_in[14]; const float* b_G = (const float*)d_in[15];
    const float* gamma_G = (const float*)d_in[16]; const float* beta_G = (const float*)d_in[17];
    const float* W_g = (const float*)d_in[18]; const float* b_g = (const float*)d_in[19];
    const float* gamma_g = (const float*)d_in[20]; const float* beta_g = (const float*)d_in[21];

    float* out = (float*)d_out;
    char*  ws  = (char*)d_ws;
    unsigned short* d1 = (unsigned short*)ws;                          // 64 MiB
    unsigned short* nm = (unsigned short*)(ws + ((size_t)64  << 20));  // 64 MiB
    unsigned short* d2 = (unsigned short*)(ws + ((size_t)128 << 20));  // 64 MiB

    unsigned short* prep = (unsigned short*)(ws + ((size_t)192 << 20));
    unsigned short* pw   = prep;                 // 3*16*64*192
    unsigned short* pWG  = prep + 589824;
    unsigned short* pWg  = pWG + 6656;
    unsigned short* padj = pWg + 6656;

    prep_w<<<48, 256, 0, stream>>>(Wt0, Wt1, Wt2, pw);
    prep_small<<<1, 256, 0, stream>>>(adj_G, W_G, W_g, padj, pWG, pWg);

    conv_chain<<<4096, 256, 0, stream>>>(h_in, pw, bt0, bt1, bt2, gamma_t, beta_t,
                                         embs_G, pWG, b_G, d1);
    nodemix_mfma<<<8192, 256, 0, stream>>>(d1, padj, gamma_G, beta_G, nm);
    dense_mfma<8><<<4096, 256, 0, stream>>>(nm, embs_g, pWg, b_g, d2);
    featmix_v2<<<32768, 256, 0, stream>>>(d2, adj_g, gamma_g, beta_g, h_in, out);
}

// Round 11
// 320.967 us; speedup vs baseline: 3.8679x; 1.1415x over previous
//
#include <hip/hip_runtime.h>

#define BN_ 256
#define T_  128
#define F_  16
#define H_  64

using f16x8   = __attribute__((ext_vector_type(8))) _Float16;
using f32x4   = __attribute__((ext_vector_type(4))) float;
using ushort8 = __attribute__((ext_vector_type(8))) unsigned short;

__device__ __forceinline__ float elu_(float x) { return x > 0.f ? x : __expf(x) - 1.f; }
__device__ __forceinline__ unsigned short f2h(float x) {
    union { _Float16 h; unsigned short u; } v; v.h = (_Float16)x; return v.u;
}
__device__ __forceinline__ float h2f(unsigned short u) {
    union { unsigned short u; _Float16 h; } v; v.u = u; return (float)v.h;
}

// ---------------- prep: conv weights -> fp16 transposed [l][f][g][192] ----------------
__global__ __launch_bounds__(256) void prep_w(const float* __restrict__ Wt0,
                                              const float* __restrict__ Wt1,
                                              const float* __restrict__ Wt2,
                                              unsigned short* __restrict__ pw)
{
    __shared__ unsigned short sW[64 * 200];
    const int lf = blockIdx.x, l = lf >> 4, f = lf & 15;
    const float* W = (l == 0) ? Wt0 : ((l == 1) ? Wt1 : Wt2);
    const int tid = threadIdx.x;

    for (int idx = tid; idx < 3 * 4096; idx += 256) {
        int tap = idx >> 12, rem = idx & 4095;
        int h = rem >> 6, g = rem & 63;
        sW[g * 200 + tap * 64 + h] = f2h(W[(size_t)(tap * 16 + f) * 4096 + rem]);
    }
    __syncthreads();
    for (int idx = tid; idx < 64 * 24; idx += 256) {
        int g = idx / 24, k8 = idx - g * 24;
        *reinterpret_cast<ushort8*>(&pw[((size_t)lf * 64 + g) * 192 + k8 * 8]) =
            *reinterpret_cast<const ushort8*>(&sW[g * 200 + k8 * 8]);
    }
}

// ---------------- prep: adjG [64][72], W_G [64][104], W_g [64][104] ----------------
__global__ __launch_bounds__(256) void prep_small(const float* __restrict__ adjG,
                                                  const float* __restrict__ W_G,
                                                  const float* __restrict__ W_g,
                                                  unsigned short* __restrict__ padj,
                                                  unsigned short* __restrict__ pWG,
                                                  unsigned short* __restrict__ pWg)
{
    const int tid = threadIdx.x;
    for (int idx = tid; idx < 4608; idx += 256) {
        int m = idx / 72, n = idx - m * 72;
        padj[idx] = (n < 64) ? f2h(adjG[m * 64 + n]) : (unsigned short)0;
    }
    for (int idx = tid; idx < 6656; idx += 256) {
        int g = idx / 104, k = idx - g * 104;
        pWG[idx] = (k < 80) ? f2h(W_G[k * 64 + g]) : (unsigned short)0;
    }
    for (int idx = tid; idx < 6656; idx += 256) {
        int g = idx / 104, k = idx - g * 104;
        pWg[idx] = (k < 72) ? f2h(W_g[k * 64 + g]) : (unsigned short)0;
    }
}

// ---------------- fused: tconv x3 (+LN_t) + dense_G per (bn,f); swapped-operand MFMA ----------------
__global__ __launch_bounds__(256, 3) void conv_chain(const float* __restrict__ in,
                                                     const unsigned short* __restrict__ pw,   // [l][f][g][192]
                                                     const float* __restrict__ bt0,
                                                     const float* __restrict__ bt1,
                                                     const float* __restrict__ bt2,
                                                     const float* __restrict__ gamma,
                                                     const float* __restrict__ beta,
                                                     const float* __restrict__ embs_G,
                                                     const unsigned short* __restrict__ pWG,  // [64][104]
                                                     const float* __restrict__ b_G,
                                                     unsigned short* __restrict__ d1)
{
    __shared__ __align__(16) char smem[46720];
    unsigned short* tile = (unsigned short*)smem;             // [136][72] conv tile
    unsigned short* sW   = (unsigned short*)(smem + 19584);   // [64][200] conv weights
    float*          sCst = (float*)(smem + 45184);            // [6][64]: bt0,bt1,bt2,gamma,beta,bG
    unsigned short* sA1  = (unsigned short*)smem;             // [128][104] dense A (overlay)
    unsigned short* sWG  = (unsigned short*)(smem + 26624);   // [64][104] dense W (overlay)

    const int f   = blockIdx.x & 15;
    const int bn  = blockIdx.x >> 4;
    const int tid = threadIdx.x;
    const int lane = tid & 63, w = tid >> 6;
    const int r16 = lane & 15, q = lane >> 4;

    // prefetch embs_G tile (consumed in dense staging)
    const int et = (tid * 8) >> 4, ee = (tid * 8) & 15;
    const float* esrc = embs_G + ((((size_t)bn * T_ + et) * F_ + f) * 16 + ee);
    float4 ereg0 = *reinterpret_cast<const float4*>(esrc);
    float4 ereg1 = *reinterpret_cast<const float4*>(esrc + 4);

    // constants
    if (tid < 64) {
        sCst[0 * 64 + tid] = bt0[f * 64 + tid];
        sCst[1 * 64 + tid] = bt1[f * 64 + tid];
        sCst[2 * 64 + tid] = bt2[f * 64 + tid];
        sCst[3 * 64 + tid] = gamma[tid];
        sCst[4 * 64 + tid] = beta[tid];
        sCst[5 * 64 + tid] = b_G[tid];
    }
    // input tile (f32 -> fp16, zero halo)
    for (int idx = tid; idx < 136 * 16; idx += 256) {
        int r = idx >> 4, h4 = (idx & 15) * 4;
        int t = r - 4;
        ushort4 v = {0, 0, 0, 0};
        if (t >= 0 && t < T_) {
            float4 x = *reinterpret_cast<const float4*>(in + (((size_t)bn * T_ + t) * F_ + f) * H_ + h4);
            v.x = f2h(x.x); v.y = f2h(x.y); v.z = f2h(x.z); v.w = f2h(x.w);
        }
        *reinterpret_cast<ushort4*>(&tile[r * 72 + h4]) = v;
    }
    // layer-0 weights
    {
        const unsigned short* wsrc = pw + (size_t)f * 64 * 192;
        for (int idx = tid; idx < 1536; idx += 256) {
            int g = idx / 24, k8 = idx - g * 24;
            *reinterpret_cast<ushort8*>(&sW[g * 200 + k8 * 8]) =
                *reinterpret_cast<const ushort8*>(&wsrc[g * 192 + k8 * 8]);
        }
    }
    __syncthreads();

    float vv[2][4][4];   // [tt][gt][reg] : t = w*32+tt*16+r16, g = gt*16+q*4+reg

#pragma unroll
    for (int l = 0; l < 3; ++l) {
        const int dil = 1 << l;

        // prefetch next weights into regs (hidden under this layer's MFMA)
        ushort8 wreg[6];
        if (l < 2) {
            const unsigned short* wsrc = pw + ((size_t)((l + 1) * 16 + f) * 64) * 192;
#pragma unroll
            for (int j = 0; j < 6; ++j) {
                int idx = j * 256 + tid, g = idx / 24, k8 = idx - g * 24;
                wreg[j] = *reinterpret_cast<const ushort8*>(&wsrc[g * 192 + k8 * 8]);
            }
        }
        ushort8 wgreg[4];
        if (l == 2) {
#pragma unroll
            for (int j = 0; j < 4; ++j) {
                int idx = j * 256 + tid;
                if (idx < 832) wgreg[j] = reinterpret_cast<const ushort8*>(pWG)[idx];
            }
        }

        f32x4 acc[2][4];
#pragma unroll
        for (int i = 0; i < 2; i++)
#pragma unroll
            for (int j = 0; j < 4; j++) acc[i][j] = {0.f, 0.f, 0.f, 0.f};

#pragma unroll
        for (int tap = 0; tap < 3; ++tap) {
            const int row0 = w * 32 + r16 + 4 + (tap - 1) * dil;
#pragma unroll
            for (int ks = 0; ks < 2; ++ks) {
                const int ko = ks * 32 + q * 8;
                f16x8 a0 = *reinterpret_cast<const f16x8*>(&tile[row0 * 72 + ko]);
                f16x8 a1 = *reinterpret_cast<const f16x8*>(&tile[(row0 + 16) * 72 + ko]);
                const int kb = tap * 64 + ko;
                f16x8 b0 = *reinterpret_cast<const f16x8*>(&sW[(r16     ) * 200 + kb]);
                f16x8 b1 = *reinterpret_cast<const f16x8*>(&sW[(r16 + 16) * 200 + kb]);
                f16x8 b2 = *reinterpret_cast<const f16x8*>(&sW[(r16 + 32) * 200 + kb]);
                f16x8 b3 = *reinterpret_cast<const f16x8*>(&sW[(r16 + 48) * 200 + kb]);
                // swapped: D[g][t] -> lane owns fixed t (col=r16), g = gt*16+q*4+reg
                acc[0][0] = __builtin_amdgcn_mfma_f32_16x16x32_f16(b0, a0, acc[0][0], 0, 0, 0);
                acc[0][1] = __builtin_amdgcn_mfma_f32_16x16x32_f16(b1, a0, acc[0][1], 0, 0, 0);
                acc[0][2] = __builtin_amdgcn_mfma_f32_16x16x32_f16(b2, a0, acc[0][2], 0, 0, 0);
                acc[0][3] = __builtin_amdgcn_mfma_f32_16x16x32_f16(b3, a0, acc[0][3], 0, 0, 0);
                acc[1][0] = __builtin_amdgcn_mfma_f32_16x16x32_f16(b0, a1, acc[1][0], 0, 0, 0);
                acc[1][1] = __builtin_amdgcn_mfma_f32_16x16x32_f16(b1, a1, acc[1][1], 0, 0, 0);
                acc[1][2] = __builtin_amdgcn_mfma_f32_16x16x32_f16(b2, a1, acc[1][2], 0, 0, 0);
                acc[1][3] = __builtin_amdgcn_mfma_f32_16x16x32_f16(b3, a1, acc[1][3], 0, 0, 0);
            }
        }

        // epilogue: bias + ELU (+ LN on layer 2), all per-lane row t
#pragma unroll
        for (int tt = 0; tt < 2; ++tt) {
#pragma unroll
            for (int gt = 0; gt < 4; ++gt) {
                float4 b4 = *reinterpret_cast<const float4*>(&sCst[l * 64 + gt * 16 + q * 4]);
#pragma unroll
                for (int r = 0; r < 4; ++r) vv[tt][gt][r] = elu_(acc[tt][gt][r] + ((const float*)&b4)[r]);
            }
            if (l == 2) {
                float s = 0.f, qq = 0.f;
#pragma unroll
                for (int gt = 0; gt < 4; ++gt)
#pragma unroll
                    for (int r = 0; r < 4; ++r) { float v = vv[tt][gt][r]; s += v; qq += v * v; }
                s += __shfl_xor(s, 16, 64); qq += __shfl_xor(qq, 16, 64);
                s += __shfl_xor(s, 32, 64); qq += __shfl_xor(qq, 32, 64);
                float mean = s * (1.f / 64.f);
                float var  = qq * (1.f / 64.f) - mean * mean;
                float rstd = rsqrtf(var + 1e-5f);
#pragma unroll
                for (int gt = 0; gt < 4; ++gt) {
                    float4 g4 = *reinterpret_cast<const float4*>(&sCst[3 * 64 + gt * 16 + q * 4]);
                    float4 be4 = *reinterpret_cast<const float4*>(&sCst[4 * 64 + gt * 16 + q * 4]);
#pragma unroll
                    for (int r = 0; r < 4; ++r)
                        vv[tt][gt][r] = (vv[tt][gt][r] - mean) * rstd * ((const float*)&g4)[r] + ((const float*)&be4)[r];
                }
            }
        }
        __syncthreads();   // all tile/sW reads of this layer complete

        if (l < 2) {
            // write-back: lane owns row t, 4 consecutive g per (tt,gt) -> ushort4
#pragma unroll
            for (int tt = 0; tt < 2; ++tt) {
                const int t = w * 32 + tt * 16 + r16;
#pragma unroll
                for (int gt = 0; gt < 4; ++gt) {
                    ushort4 o = {f2h(vv[tt][gt][0]), f2h(vv[tt][gt][1]), f2h(vv[tt][gt][2]), f2h(vv[tt][gt][3])};
                    *reinterpret_cast<ushort4*>(&tile[(t + 4) * 72 + gt * 16 + q * 4]) = o;
                }
            }
#pragma unroll
            for (int j = 0; j < 6; ++j) {
                int idx = j * 256 + tid, g = idx / 24, k8 = idx - g * 24;
                *reinterpret_cast<ushort8*>(&sW[g * 200 + k8 * 8]) = wreg[j];
            }
            __syncthreads();
        } else {
            // dense staging: sA1 rows t = [h | embs | 0], sWG from prefetched regs
#pragma unroll
            for (int tt = 0; tt < 2; ++tt) {
                const int t = w * 32 + tt * 16 + r16;
#pragma unroll
                for (int gt = 0; gt < 4; ++gt) {
                    ushort4 o = {f2h(vv[tt][gt][0]), f2h(vv[tt][gt][1]), f2h(vv[tt][gt][2]), f2h(vv[tt][gt][3])};
                    *reinterpret_cast<ushort4*>(&sA1[t * 104 + gt * 16 + q * 4]) = o;
                }
            }
            {
                ushort4 e0 = {f2h(ereg0.x), f2h(ereg0.y), f2h(ereg0.z), f2h(ereg0.w)};
                ushort4 e1 = {f2h(ereg1.x), f2h(ereg1.y), f2h(ereg1.z), f2h(ereg1.w)};
                *reinterpret_cast<ushort4*>(&sA1[et * 104 + 64 + ee])     = e0;
                *reinterpret_cast<ushort4*>(&sA1[et * 104 + 64 + ee + 4]) = e1;
            }
            {   // zero cols 80..95: one ushort8 per thread
                int r = tid >> 1, half = tid & 1;
                ushort8 z = {0,0,0,0,0,0,0,0};
                *reinterpret_cast<ushort8*>(&sA1[r * 104 + 80 + half * 8]) = z;
            }
#pragma unroll
            for (int j = 0; j < 4; ++j) {
                int idx = j * 256 + tid;
                if (idx < 832) reinterpret_cast<ushort8*>(sWG)[idx] = wgreg[j];
            }
            __syncthreads();
        }
    }

    // dense MFMA (swapped): D[g][t]
    f32x4 dacc[2][4];
#pragma unroll
    for (int i = 0; i < 2; i++)
#pragma unroll
        for (int j = 0; j < 4; j++) dacc[i][j] = {0.f, 0.f, 0.f, 0.f};

#pragma unroll
    for (int ks = 0; ks < 3; ++ks) {
        const int ko = ks * 32 + q * 8;
        f16x8 a0 = *reinterpret_cast<const f16x8*>(&sA1[(w * 32 + r16) * 104 + ko]);
        f16x8 a1 = *reinterpret_cast<const f16x8*>(&sA1[(w * 32 + 16 + r16) * 104 + ko]);
#pragma unroll
        for (int gt = 0; gt < 4; ++gt) {
            f16x8 bb = *reinterpret_cast<const f16x8*>(&sWG[(gt * 16 + r16) * 104 + ko]);
            dacc[0][gt] = __builtin_amdgcn_mfma_f32_16x16x32_f16(bb, a0, dacc[0][gt], 0, 0, 0);
            dacc[1][gt] = __builtin_amdgcn_mfma_f32_16x16x32_f16(bb, a1, dacc[1][gt], 0, 0, 0);
        }
    }

#pragma unroll
    for (int tt = 0; tt < 2; ++tt) {
        const int t = w * 32 + tt * 16 + r16;
        const size_t ob = (((size_t)bn * T_ + t) * F_ + f) * H_;
#pragma unroll
        for (int gt = 0; gt < 4; ++gt) {
            float4 b4 = *reinterpret_cast<const float4*>(&sCst[5 * 64 + gt * 16 + q * 4]);
            ushort4 o = {f2h(elu_(dacc[tt][gt][0] + ((const float*)&b4)[0])),
                         f2h(elu_(dacc[tt][gt][1] + ((const float*)&b4)[1])),
                         f2h(elu_(dacc[tt][gt][2] + ((const float*)&b4)[2])),
                         f2h(elu_(dacc[tt][gt][3] + ((const float*)&b4)[3]))};
            *reinterpret_cast<ushort4*>(&d1[ob + gt * 16 + q * 4]) = o;
        }
    }
}

// ---------------- node mix via MFMA + LN_G (swapped operands) ----------------
__global__ __launch_bounds__(256) void nodemix_mfma(const unsigned short* __restrict__ d1,
                                                    const unsigned short* __restrict__ padj,
                                                    const float* __restrict__ gamma,
                                                    const float* __restrict__ beta,
                                                    unsigned short* __restrict__ nmo)
{
    __shared__ __align__(16) unsigned short sAdj[64 * 72];
    __shared__ __align__(16) unsigned short sXT[64 * 88];

    const int f = blockIdx.x & 15, t = (blockIdx.x >> 4) & 127, b = blockIdx.x >> 11;
    const int tid = threadIdx.x, lane = tid & 63, w = tid >> 6;

    for (int idx = tid; idx < 576; idx += 256)
        reinterpret_cast<ushort8*>(sAdj)[idx] = reinterpret_cast<const ushort8*>(padj)[idx];
    {
        const int n = lane;
        const size_t base = (((size_t)(b * 64 + n) * T_ + t) * F_ + f) * H_;
#pragma unroll
        for (int p = 0; p < 2; ++p) {
            int c = w + p * 4;
            ushort8 v = *reinterpret_cast<const ushort8*>(&d1[base + c * 8]);
#pragma unroll
            for (int i = 0; i < 8; ++i) sXT[(c * 8 + i) * 88 + n] = v[i];
        }
    }
    __syncthreads();

    const int r16 = lane & 15, q = lane >> 4;
    f32x4 acc[4];
#pragma unroll
    for (int j = 0; j < 4; j++) acc[j] = {0.f, 0.f, 0.f, 0.f};

#pragma unroll
    for (int ks = 0; ks < 2; ++ks) {
        f16x8 af = *reinterpret_cast<const f16x8*>(&sAdj[(w * 16 + r16) * 72 + ks * 32 + q * 8]);
#pragma unroll
        for (int ht = 0; ht < 4; ++ht) {
            f16x8 xf = *reinterpret_cast<const f16x8*>(&sXT[(ht * 16 + r16) * 88 + ks * 32 + q * 8]);
            // swapped: D[h][m] -> lane owns fixed m (col=r16), h = ht*16+q*4+reg
            acc[ht] = __builtin_amdgcn_mfma_f32_16x16x32_f16(xf, af, acc[ht], 0, 0, 0);
        }
    }

    const int m = w * 16 + r16;
    float s = 0.f, qq = 0.f;
#pragma unroll
    for (int ht = 0; ht < 4; ++ht)
#pragma unroll
        for (int r = 0; r < 4; ++r) { float v = acc[ht][r]; s += v; qq += v * v; }
    s += __shfl_xor(s, 16, 64); qq += __shfl_xor(qq, 16, 64);
    s += __shfl_xor(s, 32, 64); qq += __shfl_xor(qq, 32, 64);
    float mean = s * (1.f / 64.f);
    float var  = qq * (1.f / 64.f) - mean * mean;
    float rstd = rsqrtf(var + 1e-5f);

    const size_t ob = (((size_t)(b * 64 + m) * T_ + t) * F_ + f) * H_;
#pragma unroll
    for (int ht = 0; ht < 4; ++ht) {
        float4 g4  = *reinterpret_cast<const float4*>(&gamma[ht * 16 + q * 4]);
        float4 be4 = *reinterpret_cast<const float4*>(&beta[ht * 16 + q * 4]);
        ushort4 o = {f2h((acc[ht][0] - mean) * rstd * ((const float*)&g4)[0] + ((const float*)&be4)[0]),
                     f2h((acc[ht][1] - mean) * rstd * ((const float*)&g4)[1] + ((const float*)&be4)[1]),
                     f2h((acc[ht][2] - mean) * rstd * ((const float*)&g4)[2] + ((const float*)&be4)[2]),
                     f2h((acc[ht][3] - mean) * rstd * ((const float*)&g4)[3] + ((const float*)&be4)[3])};
        *reinterpret_cast<ushort4*>(&nmo[ob + ht * 16 + q * 4]) = o;
    }
}

// ---------------- dense via MFMA (swapped operands) ----------------
template<int NE>
__global__ __launch_bounds__(256) void dense_mfma(const unsigned short* __restrict__ x,
                                                  const float* __restrict__ e,
                                                  const unsigned short* __restrict__ pW,
                                                  const float* __restrict__ bias,
                                                  unsigned short* __restrict__ out)
{
    __shared__ __align__(16) unsigned short sA[128 * 104];
    __shared__ __align__(16) unsigned short sW[64 * 104];
    __shared__ float sB[64];

    const int row0 = blockIdx.x * 128;
    const int tid  = threadIdx.x;

    if (tid < 64) sB[tid] = bias[tid];
    for (int idx = tid; idx < 832; idx += 256)
        reinterpret_cast<ushort8*>(sW)[idx] = reinterpret_cast<const ushort8*>(pW)[idx];
    for (int idx = tid; idx < 1024; idx += 256) {
        int r = idx >> 3, c8 = (idx & 7) * 8;
        *reinterpret_cast<ushort8*>(&sA[r * 104 + c8]) =
            *reinterpret_cast<const ushort8*>(&x[(size_t)(row0 + r) * 64 + c8]);
    }
    for (int idx = tid; idx < 4096; idx += 256) {
        int r = idx >> 5, c = idx & 31;
        unsigned short v = 0;
        if (c < NE) v = f2h(e[(size_t)(row0 + r) * NE + c]);
        sA[r * 104 + 64 + c] = v;
    }
    __syncthreads();

    const int lane = tid & 63, w = tid >> 6;
    const int r16 = lane & 15, q = lane >> 4;

    f32x4 dacc[2][4];
#pragma unroll
    for (int i = 0; i < 2; i++)
#pragma unroll
        for (int j = 0; j < 4; j++) dacc[i][j] = {0.f, 0.f, 0.f, 0.f};

#pragma unroll
    for (int ks = 0; ks < 3; ++ks) {
        const int ko = ks * 32 + q * 8;
        f16x8 a0 = *reinterpret_cast<const f16x8*>(&sA[(w * 32 + r16) * 104 + ko]);
        f16x8 a1 = *reinterpret_cast<const f16x8*>(&sA[(w * 32 + 16 + r16) * 104 + ko]);
#pragma unroll
        for (int gt = 0; gt < 4; ++gt) {
            f16x8 bb = *reinterpret_cast<const f16x8*>(&sW[(gt * 16 + r16) * 104 + ko]);
            dacc[0][gt] = __builtin_amdgcn_mfma_f32_16x16x32_f16(bb, a0, dacc[0][gt], 0, 0, 0);
            dacc[1][gt] = __builtin_amdgcn_mfma_f32_16x16x32_f16(bb, a1, dacc[1][gt], 0, 0, 0);
        }
    }

#pragma unroll
    for (int tt = 0; tt < 2; ++tt) {
        const int r = w * 32 + tt * 16 + r16;
        const size_t ob = (size_t)(row0 + r) * 64;
#pragma unroll
        for (int gt = 0; gt < 4; ++gt) {
            float4 b4 = *reinterpret_cast<const float4*>(&sB[gt * 16 + q * 4]);
            ushort4 o = {f2h(elu_(dacc[tt][gt][0] + ((const float*)&b4)[0])),
                         f2h(elu_(dacc[tt][gt][1] + ((const float*)&b4)[1])),
                         f2h(elu_(dacc[tt][gt][2] + ((const float*)&b4)[2])),
                         f2h(elu_(dacc[tt][gt][3] + ((const float*)&b4)[3]))};
            *reinterpret_cast<ushort4*>(&out[ob + gt * 16 + q * 4]) = o;
        }
    }
}

// ---------------- feature mix + LN + residual (verified) ----------------
__global__ __launch_bounds__(256) void featmix_v2(const unsigned short* __restrict__ e,
                                                  const float* __restrict__ adjg,
                                                  const float* __restrict__ gamma,
                                                  const float* __restrict__ beta,
                                                  const float* __restrict__ res,
                                                  float* __restrict__ out)
{
    __shared__ __align__(16) unsigned short se[16 * 64];

    const int t = blockIdx.x & 127, bn = blockIdx.x >> 7;
    const int tid = threadIdx.x;
    const size_t base = ((size_t)bn * T_ + t) * F_ * H_;

    {
        int f = tid >> 4, c4 = (tid & 15) * 4;
        *reinterpret_cast<ushort4*>(&se[f * 64 + c4]) =
            *reinterpret_cast<const ushort4*>(&e[base + f * 64 + c4]);
    }
    __syncthreads();

    const int g = tid >> 4, hq = tid & 15;
    float ag[16];
#pragma unroll
    for (int f = 0; f < 16; ++f) ag[f] = adjg[g * 16 + f];

    float a[4] = {0.f, 0.f, 0.f, 0.f};
#pragma unroll
    for (int f = 0; f < 16; ++f) {
        ushort4 dv = *reinterpret_cast<const ushort4*>(&se[f * 64 + hq * 4]);
        float av = ag[f];
        a[0] = fmaf(av, h2f(dv.x), a[0]);
        a[1] = fmaf(av, h2f(dv.y), a[1]);
        a[2] = fmaf(av, h2f(dv.z), a[2]);
        a[3] = fmaf(av, h2f(dv.w), a[3]);
    }
    float s  = a[0] + a[1] + a[2] + a[3];
    float qv = a[0]*a[0] + a[1]*a[1] + a[2]*a[2] + a[3]*a[3];
#pragma unroll
    for (int m = 1; m < 16; m <<= 1) { s += __shfl_xor(s, m, 64); qv += __shfl_xor(qv, m, 64); }
    float mean = s * (1.f / 64.f);
    float var  = qv * (1.f / 64.f) - mean * mean;
    float rstd = rsqrtf(var + 1e-5f);

    const size_t o = base + (size_t)g * 64 + hq * 4;
    float4 rv = *reinterpret_cast<const float4*>(res + o);
    float4 ov;
    ov.x = (a[0] - mean) * rstd * gamma[hq * 4 + 0] + beta[hq * 4 + 0] + rv.x;
    ov.y = (a[1] - mean) * rstd * gamma[hq * 4 + 1] + beta[hq * 4 + 1] + rv.y;
    ov.z = (a[2] - mean) * rstd * gamma[hq * 4 + 2] + beta[hq * 4 + 2] + rv.z;
    ov.w = (a[3] - mean) * rstd * gamma[hq * 4 + 3] + beta[hq * 4 + 3] + rv.w;
    *reinterpret_cast<float4*>(out + o) = ov;
}

extern "C" void kernel_launch(void* const* d_in, const int* in_sizes, int n_in,
                              void* d_out, int out_size, void* d_ws, size_t ws_size,
                              hipStream_t stream)
{
    const float* h_in    = (const float*)d_in[0];
    const float* embs_G  = (const float*)d_in[2];
    const float* embs_g  = (const float*)d_in[3];
    const float* adj_G   = (const float*)d_in[4];
    const float* adj_g   = (const float*)d_in[5];
    const float* Wt0 = (const float*)d_in[6];  const float* bt0 = (const float*)d_in[7];
    const float* Wt1 = (const float*)d_in[8];  const float* bt1 = (const float*)d_in[9];
    const float* Wt2 = (const float*)d_in[10]; const float* bt2 = (const float*)d_in[11];
    const float* gamma_t = (const float*)d_in[12]; const float* beta_t = (const float*)d_in[13];
    const float* W_G = (const float*)d_in[14]; const float* b_G = (const float*)d_in[15];
    const float* gamma_G = (const float*)d_in[16]; const float* beta_G = (const float*)d_in[17];
    const float* W_g = (const float*)d_in[18]; const float* b_g = (const float*)d_in[19];
    const float* gamma_g = (const float*)d_in[20]; const float* beta_g = (const float*)d_in[21];

    float* out = (float*)d_out;
    char*  ws  = (char*)d_ws;
    unsigned short* d1 = (unsigned short*)ws;                          // 64 MiB
    unsigned short* nm = (unsigned short*)(ws + ((size_t)64  << 20));  // 64 MiB
    unsigned short* d2 = (unsigned short*)(ws + ((size_t)128 << 20));  // 64 MiB

    unsigned short* prep = (unsigned short*)(ws + ((size_t)192 << 20));
    unsigned short* pw   = prep;                 // 3*16*64*192
    unsigned short* pWG  = prep + 589824;
    unsigned short* pWg  = pWG + 6656;
    unsigned short* padj = pWg + 6656;

    prep_w<<<48, 256, 0, stream>>>(Wt0, Wt1, Wt2, pw);
    prep_small<<<1, 256, 0, stream>>>(adj_G, W_G, W_g, padj, pWG, pWg);

    conv_chain<<<4096, 256, 0, stream>>>(h_in, pw, bt0, bt1, bt2, gamma_t, beta_t,
                                         embs_G, pWG, b_G, d1);
    nodemix_mfma<<<8192, 256, 0, stream>>>(d1, padj, gamma_G, beta_G, nm);
    dense_mfma<8><<<4096, 256, 0, stream>>>(nm, embs_g, pWg, b_g, d2);
    featmix_v2<<<32768, 256, 0, stream>>>(d2, adj_g, gamma_g, beta_g, h_in, out);
}

// Round 13
// 320.912 us; speedup vs baseline: 3.8686x; 1.0002x over previous
//
#include <hip/hip_runtime.h>

#define BN_ 256
#define T_  128
#define F_  16
#define H_  64

using f16x8   = __attribute__((ext_vector_type(8))) _Float16;
using f32x4   = __attribute__((ext_vector_type(4))) float;
using ushort8 = __attribute__((ext_vector_type(8))) unsigned short;

__device__ __forceinline__ float elu_(float x) { return x > 0.f ? x : __expf(x) - 1.f; }
__device__ __forceinline__ unsigned short f2h(float x) {
    union { _Float16 h; unsigned short u; } v; v.h = (_Float16)x; return v.u;
}
__device__ __forceinline__ float h2f(unsigned short u) {
    union { unsigned short u; _Float16 h; } v; v.u = u; return (float)v.h;
}
// packed f32x2 -> f16x2 (one v_cvt_pkrtz_f16_f32)
__device__ __forceinline__ unsigned pk2(float a, float b) {
    auto h = __builtin_amdgcn_cvt_pkrtz(a, b);
    unsigned u; __builtin_memcpy(&u, &h, 4); return u;
}
// store 4 floats as 4 fp16 (2 cvt_pkrtz + 1 b64 store); p must be 8B-aligned
__device__ __forceinline__ void st4h(unsigned short* p, float a, float b, float c, float d) {
    uint2 v; v.x = pk2(a, b); v.y = pk2(c, d);
    *reinterpret_cast<uint2*>(p) = v;
}

// ---------------- prep: conv weights -> fp16 transposed [l][f][g][192] ----------------
__global__ __launch_bounds__(256) void prep_w(const float* __restrict__ Wt0,
                                              const float* __restrict__ Wt1,
                                              const float* __restrict__ Wt2,
                                              unsigned short* __restrict__ pw)
{
    __shared__ unsigned short sW[64 * 200];
    const int lf = blockIdx.x, l = lf >> 4, f = lf & 15;
    const float* W = (l == 0) ? Wt0 : ((l == 1) ? Wt1 : Wt2);
    const int tid = threadIdx.x;

    for (int idx = tid; idx < 3 * 4096; idx += 256) {
        int tap = idx >> 12, rem = idx & 4095;
        int h = rem >> 6, g = rem & 63;
        sW[g * 200 + tap * 64 + h] = f2h(W[(size_t)(tap * 16 + f) * 4096 + rem]);
    }
    __syncthreads();
    for (int idx = tid; idx < 64 * 24; idx += 256) {
        int g = idx / 24, k8 = idx - g * 24;
        *reinterpret_cast<ushort8*>(&pw[((size_t)lf * 64 + g) * 192 + k8 * 8]) =
            *reinterpret_cast<const ushort8*>(&sW[g * 200 + k8 * 8]);
    }
}

// ---------------- prep: adjG [64][72], W_G [64][104], W_g [64][104] ----------------
__global__ __launch_bounds__(256) void prep_small(const float* __restrict__ adjG,
                                                  const float* __restrict__ W_G,
                                                  const float* __restrict__ W_g,
                                                  unsigned short* __restrict__ padj,
                                                  unsigned short* __restrict__ pWG,
                                                  unsigned short* __restrict__ pWg)
{
    const int tid = threadIdx.x;
    for (int idx = tid; idx < 4608; idx += 256) {
        int m = idx / 72, n = idx - m * 72;
        padj[idx] = (n < 64) ? f2h(adjG[m * 64 + n]) : (unsigned short)0;
    }
    for (int idx = tid; idx < 6656; idx += 256) {
        int g = idx / 104, k = idx - g * 104;
        pWG[idx] = (k < 80) ? f2h(W_G[k * 64 + g]) : (unsigned short)0;
    }
    for (int idx = tid; idx < 6656; idx += 256) {
        int g = idx / 104, k = idx - g * 104;
        pWg[idx] = (k < 72) ? f2h(W_g[k * 64 + g]) : (unsigned short)0;
    }
}

// ---------------- fused: tconv x3 (+LN_t) + dense_G per (bn,f); swapped-operand MFMA ----------------
__global__ __launch_bounds__(256, 3) void conv_chain(const float* __restrict__ in,
                                                     const unsigned short* __restrict__ pw,
                                                     const float* __restrict__ bt0,
                                                     const float* __restrict__ bt1,
                                                     const float* __restrict__ bt2,
                                                     const float* __restrict__ gamma,
                                                     const float* __restrict__ beta,
                                                     const float* __restrict__ embs_G,
                                                     const unsigned short* __restrict__ pWG,
                                                     const float* __restrict__ b_G,
                                                     unsigned short* __restrict__ d1)
{
    __shared__ __align__(16) char smem[46720];
    unsigned short* tile = (unsigned short*)smem;             // [136][72]
    unsigned short* sW   = (unsigned short*)(smem + 19584);   // [64][200]
    float*          sCst = (float*)(smem + 45184);            // [6][64]
    unsigned short* sA1  = (unsigned short*)smem;             // [128][104] overlay
    unsigned short* sWG  = (unsigned short*)(smem + 26624);   // [64][104] overlay

    const int f   = blockIdx.x & 15;
    const int bn  = blockIdx.x >> 4;
    const int tid = threadIdx.x;
    const int lane = tid & 63, w = tid >> 6;
    const int r16 = lane & 15, q = lane >> 4;

    const int et = (tid * 8) >> 4, ee = (tid * 8) & 15;
    const float* esrc = embs_G + ((((size_t)bn * T_ + et) * F_ + f) * 16 + ee);
    float4 ereg0 = *reinterpret_cast<const float4*>(esrc);
    float4 ereg1 = *reinterpret_cast<const float4*>(esrc + 4);

    if (tid < 64) {
        sCst[0 * 64 + tid] = bt0[f * 64 + tid];
        sCst[1 * 64 + tid] = bt1[f * 64 + tid];
        sCst[2 * 64 + tid] = bt2[f * 64 + tid];
        sCst[3 * 64 + tid] = gamma[tid];
        sCst[4 * 64 + tid] = beta[tid];
        sCst[5 * 64 + tid] = b_G[tid];
    }
    for (int idx = tid; idx < 136 * 16; idx += 256) {
        int r = idx >> 4, h4 = (idx & 15) * 4;
        int t = r - 4;
        if (t >= 0 && t < T_) {
            float4 x = *reinterpret_cast<const float4*>(in + (((size_t)bn * T_ + t) * F_ + f) * H_ + h4);
            st4h(&tile[r * 72 + h4], x.x, x.y, x.z, x.w);
        } else {
            uint2 z = {0, 0};
            *reinterpret_cast<uint2*>(&tile[r * 72 + h4]) = z;
        }
    }
    {
        const unsigned short* wsrc = pw + (size_t)f * 64 * 192;
        for (int idx = tid; idx < 1536; idx += 256) {
            int g = idx / 24, k8 = idx - g * 24;
            *reinterpret_cast<ushort8*>(&sW[g * 200 + k8 * 8]) =
                *reinterpret_cast<const ushort8*>(&wsrc[g * 192 + k8 * 8]);
        }
    }
    __syncthreads();

    float vv[2][4][4];

#pragma unroll
    for (int l = 0; l < 3; ++l) {
        const int dil = 1 << l;

        ushort8 wreg[6];
        if (l < 2) {
            const unsigned short* wsrc = pw + ((size_t)((l + 1) * 16 + f) * 64) * 192;
#pragma unroll
            for (int j = 0; j < 6; ++j) {
                int idx = j * 256 + tid, g = idx / 24, k8 = idx - g * 24;
                wreg[j] = *reinterpret_cast<const ushort8*>(&wsrc[g * 192 + k8 * 8]);
            }
        }
        ushort8 wgreg[4];
        if (l == 2) {
#pragma unroll
            for (int j = 0; j < 4; ++j) {
                int idx = j * 256 + tid;
                if (idx < 832) wgreg[j] = reinterpret_cast<const ushort8*>(pWG)[idx];
            }
        }

        f32x4 acc[2][4];
#pragma unroll
        for (int i = 0; i < 2; i++)
#pragma unroll
            for (int j = 0; j < 4; j++) acc[i][j] = {0.f, 0.f, 0.f, 0.f};

#pragma unroll
        for (int tap = 0; tap < 3; ++tap) {
            const int row0 = w * 32 + r16 + 4 + (tap - 1) * dil;
#pragma unroll
            for (int ks = 0; ks < 2; ++ks) {
                const int ko = ks * 32 + q * 8;
                f16x8 a0 = *reinterpret_cast<const f16x8*>(&tile[row0 * 72 + ko]);
                f16x8 a1 = *reinterpret_cast<const f16x8*>(&tile[(row0 + 16) * 72 + ko]);
                const int kb = tap * 64 + ko;
                f16x8 b0 = *reinterpret_cast<const f16x8*>(&sW[(r16     ) * 200 + kb]);
                f16x8 b1 = *reinterpret_cast<const f16x8*>(&sW[(r16 + 16) * 200 + kb]);
                f16x8 b2 = *reinterpret_cast<const f16x8*>(&sW[(r16 + 32) * 200 + kb]);
                f16x8 b3 = *reinterpret_cast<const f16x8*>(&sW[(r16 + 48) * 200 + kb]);
                acc[0][0] = __builtin_amdgcn_mfma_f32_16x16x32_f16(b0, a0, acc[0][0], 0, 0, 0);
                acc[0][1] = __builtin_amdgcn_mfma_f32_16x16x32_f16(b1, a0, acc[0][1], 0, 0, 0);
                acc[0][2] = __builtin_amdgcn_mfma_f32_16x16x32_f16(b2, a0, acc[0][2], 0, 0, 0);
                acc[0][3] = __builtin_amdgcn_mfma_f32_16x16x32_f16(b3, a0, acc[0][3], 0, 0, 0);
                acc[1][0] = __builtin_amdgcn_mfma_f32_16x16x32_f16(b0, a1, acc[1][0], 0, 0, 0);
                acc[1][1] = __builtin_amdgcn_mfma_f32_16x16x32_f16(b1, a1, acc[1][1], 0, 0, 0);
                acc[1][2] = __builtin_amdgcn_mfma_f32_16x16x32_f16(b2, a1, acc[1][2], 0, 0, 0);
                acc[1][3] = __builtin_amdgcn_mfma_f32_16x16x32_f16(b3, a1, acc[1][3], 0, 0, 0);
            }
        }

#pragma unroll
        for (int tt = 0; tt < 2; ++tt) {
#pragma unroll
            for (int gt = 0; gt < 4; ++gt) {
                float4 b4 = *reinterpret_cast<const float4*>(&sCst[l * 64 + gt * 16 + q * 4]);
#pragma unroll
                for (int r = 0; r < 4; ++r) vv[tt][gt][r] = elu_(acc[tt][gt][r] + ((const float*)&b4)[r]);
            }
            if (l == 2) {
                float s = 0.f, qq = 0.f;
#pragma unroll
                for (int gt = 0; gt < 4; ++gt)
#pragma unroll
                    for (int r = 0; r < 4; ++r) { float v = vv[tt][gt][r]; s += v; qq += v * v; }
                s += __shfl_xor(s, 16, 64); qq += __shfl_xor(qq, 16, 64);
                s += __shfl_xor(s, 32, 64); qq += __shfl_xor(qq, 32, 64);
                float mean = s * (1.f / 64.f);
                float var  = qq * (1.f / 64.f) - mean * mean;
                float rstd = rsqrtf(var + 1e-5f);
#pragma unroll
                for (int gt = 0; gt < 4; ++gt) {
                    float4 g4 = *reinterpret_cast<const float4*>(&sCst[3 * 64 + gt * 16 + q * 4]);
                    float4 be4 = *reinterpret_cast<const float4*>(&sCst[4 * 64 + gt * 16 + q * 4]);
#pragma unroll
                    for (int r = 0; r < 4; ++r)
                        vv[tt][gt][r] = (vv[tt][gt][r] - mean) * rstd * ((const float*)&g4)[r] + ((const float*)&be4)[r];
                }
            }
        }
        __syncthreads();

        if (l < 2) {
#pragma unroll
            for (int tt = 0; tt < 2; ++tt) {
                const int t = w * 32 + tt * 16 + r16;
#pragma unroll
                for (int gt = 0; gt < 4; ++gt)
                    st4h(&tile[(t + 4) * 72 + gt * 16 + q * 4],
                         vv[tt][gt][0], vv[tt][gt][1], vv[tt][gt][2], vv[tt][gt][3]);
            }
#pragma unroll
            for (int j = 0; j < 6; ++j) {
                int idx = j * 256 + tid, g = idx / 24, k8 = idx - g * 24;
                *reinterpret_cast<ushort8*>(&sW[g * 200 + k8 * 8]) = wreg[j];
            }
            __syncthreads();
        } else {
#pragma unroll
            for (int tt = 0; tt < 2; ++tt) {
                const int t = w * 32 + tt * 16 + r16;
#pragma unroll
                for (int gt = 0; gt < 4; ++gt)
                    st4h(&sA1[t * 104 + gt * 16 + q * 4],
                         vv[tt][gt][0], vv[tt][gt][1], vv[tt][gt][2], vv[tt][gt][3]);
            }
            st4h(&sA1[et * 104 + 64 + ee],     ereg0.x, ereg0.y, ereg0.z, ereg0.w);
            st4h(&sA1[et * 104 + 64 + ee + 4], ereg1.x, ereg1.y, ereg1.z, ereg1.w);
            {
                int r = tid >> 1, half = tid & 1;
                ushort8 z = {0,0,0,0,0,0,0,0};
                *reinterpret_cast<ushort8*>(&sA1[r * 104 + 80 + half * 8]) = z;
            }
#pragma unroll
            for (int j = 0; j < 4; ++j) {
                int idx = j * 256 + tid;
                if (idx < 832) reinterpret_cast<ushort8*>(sWG)[idx] = wgreg[j];
            }
            __syncthreads();
        }
    }

    f32x4 dacc[2][4];
#pragma unroll
    for (int i = 0; i < 2; i++)
#pragma unroll
        for (int j = 0; j < 4; j++) dacc[i][j] = {0.f, 0.f, 0.f, 0.f};

#pragma unroll
    for (int ks = 0; ks < 3; ++ks) {
        const int ko = ks * 32 + q * 8;
        f16x8 a0 = *reinterpret_cast<const f16x8*>(&sA1[(w * 32 + r16) * 104 + ko]);
        f16x8 a1 = *reinterpret_cast<const f16x8*>(&sA1[(w * 32 + 16 + r16) * 104 + ko]);
#pragma unroll
        for (int gt = 0; gt < 4; ++gt) {
            f16x8 bb = *reinterpret_cast<const f16x8*>(&sWG[(gt * 16 + r16) * 104 + ko]);
            dacc[0][gt] = __builtin_amdgcn_mfma_f32_16x16x32_f16(bb, a0, dacc[0][gt], 0, 0, 0);
            dacc[1][gt] = __builtin_amdgcn_mfma_f32_16x16x32_f16(bb, a1, dacc[1][gt], 0, 0, 0);
        }
    }

#pragma unroll
    for (int tt = 0; tt < 2; ++tt) {
        const int t = w * 32 + tt * 16 + r16;
        const size_t ob = (((size_t)bn * T_ + t) * F_ + f) * H_;
#pragma unroll
        for (int gt = 0; gt < 4; ++gt) {
            float4 b4 = *reinterpret_cast<const float4*>(&sCst[5 * 64 + gt * 16 + q * 4]);
            st4h(&d1[ob + gt * 16 + q * 4],
                 elu_(dacc[tt][gt][0] + ((const float*)&b4)[0]),
                 elu_(dacc[tt][gt][1] + ((const float*)&b4)[1]),
                 elu_(dacc[tt][gt][2] + ((const float*)&b4)[2]),
                 elu_(dacc[tt][gt][3] + ((const float*)&b4)[3]));
        }
    }
}

// ---------------- node mix via MFMA + LN_G (swapped operands) ----------------
__global__ __launch_bounds__(256) void nodemix_mfma(const unsigned short* __restrict__ d1,
                                                    const unsigned short* __restrict__ padj,
                                                    const float* __restrict__ gamma,
                                                    const float* __restrict__ beta,
                                                    unsigned short* __restrict__ nmo)
{
    __shared__ __align__(16) unsigned short sAdj[64 * 72];
    __shared__ __align__(16) unsigned short sXT[64 * 88];

    const int f = blockIdx.x & 15, t = (blockIdx.x >> 4) & 127, b = blockIdx.x >> 11;
    const int tid = threadIdx.x, lane = tid & 63, w = tid >> 6;

    for (int idx = tid; idx < 576; idx += 256)
        reinterpret_cast<ushort8*>(sAdj)[idx] = reinterpret_cast<const ushort8*>(padj)[idx];
    {
        const int n = lane;
        const size_t base = (((size_t)(b * 64 + n) * T_ + t) * F_ + f) * H_;
#pragma unroll
        for (int p = 0; p < 2; ++p) {
            int c = w + p * 4;
            ushort8 v = *reinterpret_cast<const ushort8*>(&d1[base + c * 8]);
#pragma unroll
            for (int i = 0; i < 8; ++i) sXT[(c * 8 + i) * 88 + n] = v[i];
        }
    }
    __syncthreads();

    const int r16 = lane & 15, q = lane >> 4;
    f32x4 acc[4];
#pragma unroll
    for (int j = 0; j < 4; j++) acc[j] = {0.f, 0.f, 0.f, 0.f};

#pragma unroll
    for (int ks = 0; ks < 2; ++ks) {
        f16x8 af = *reinterpret_cast<const f16x8*>(&sAdj[(w * 16 + r16) * 72 + ks * 32 + q * 8]);
#pragma unroll
        for (int ht = 0; ht < 4; ++ht) {
            f16x8 xf = *reinterpret_cast<const f16x8*>(&sXT[(ht * 16 + r16) * 88 + ks * 32 + q * 8]);
            acc[ht] = __builtin_amdgcn_mfma_f32_16x16x32_f16(xf, af, acc[ht], 0, 0, 0);
        }
    }

    const int m = w * 16 + r16;
    float s = 0.f, qq = 0.f;
#pragma unroll
    for (int ht = 0; ht < 4; ++ht)
#pragma unroll
        for (int r = 0; r < 4; ++r) { float v = acc[ht][r]; s += v; qq += v * v; }
    s += __shfl_xor(s, 16, 64); qq += __shfl_xor(qq, 16, 64);
    s += __shfl_xor(s, 32, 64); qq += __shfl_xor(qq, 32, 64);
    float mean = s * (1.f / 64.f);
    float var  = qq * (1.f / 64.f) - mean * mean;
    float rstd = rsqrtf(var + 1e-5f);

    const size_t ob = (((size_t)(b * 64 + m) * T_ + t) * F_ + f) * H_;
#pragma unroll
    for (int ht = 0; ht < 4; ++ht) {
        float4 g4  = *reinterpret_cast<const float4*>(&gamma[ht * 16 + q * 4]);
        float4 be4 = *reinterpret_cast<const float4*>(&beta[ht * 16 + q * 4]);
        st4h(&nmo[ob + ht * 16 + q * 4],
             (acc[ht][0] - mean) * rstd * ((const float*)&g4)[0] + ((const float*)&be4)[0],
             (acc[ht][1] - mean) * rstd * ((const float*)&g4)[1] + ((const float*)&be4)[1],
             (acc[ht][2] - mean) * rstd * ((const float*)&g4)[2] + ((const float*)&be4)[2],
             (acc[ht][3] - mean) * rstd * ((const float*)&g4)[3] + ((const float*)&be4)[3]);
    }
}

// ---------------- dense via MFMA (swapped operands; verified round 11) ----------------
template<int NE>
__global__ __launch_bounds__(256) void dense_mfma(const unsigned short* __restrict__ x,
                                                  const float* __restrict__ e,
                                                  const unsigned short* __restrict__ pW,
                                                  const float* __restrict__ bias,
                                                  unsigned short* __restrict__ out)
{
    __shared__ __align__(16) unsigned short sA[128 * 104];
    __shared__ __align__(16) unsigned short sW[64 * 104];
    __shared__ float sB[64];

    const int row0 = blockIdx.x * 128;
    const int tid  = threadIdx.x;

    if (tid < 64) sB[tid] = bias[tid];
    for (int idx = tid; idx < 832; idx += 256)
        reinterpret_cast<ushort8*>(sW)[idx] = reinterpret_cast<const ushort8*>(pW)[idx];
    for (int idx = tid; idx < 1024; idx += 256) {
        int r = idx >> 3, c8 = (idx & 7) * 8;
        *reinterpret_cast<ushort8*>(&sA[r * 104 + c8]) =
            *reinterpret_cast<const ushort8*>(&x[(size_t)(row0 + r) * 64 + c8]);
    }
    for (int idx = tid; idx < 4096; idx += 256) {
        int r = idx >> 5, c = idx & 31;
        unsigned short v = 0;
        if (c < NE) v = f2h(e[(size_t)(row0 + r) * NE + c]);
        sA[r * 104 + 64 + c] = v;
    }
    __syncthreads();

    const int lane = tid & 63, w = tid >> 6;
    const int r16 = lane & 15, q = lane >> 4;

    f32x4 dacc[2][4];
#pragma unroll
    for (int i = 0; i < 2; i++)
#pragma unroll
        for (int j = 0; j < 4; j++) dacc[i][j] = {0.f, 0.f, 0.f, 0.f};

#pragma unroll
    for (int ks = 0; ks < 3; ++ks) {
        const int ko = ks * 32 + q * 8;
        f16x8 a0 = *reinterpret_cast<const f16x8*>(&sA[(w * 32 + r16) * 104 + ko]);
        f16x8 a1 = *reinterpret_cast<const f16x8*>(&sA[(w * 32 + 16 + r16) * 104 + ko]);
#pragma unroll
        for (int gt = 0; gt < 4; ++gt) {
            f16x8 bb = *reinterpret_cast<const f16x8*>(&sW[(gt * 16 + r16) * 104 + ko]);
            dacc[0][gt] = __builtin_amdgcn_mfma_f32_16x16x32_f16(bb, a0, dacc[0][gt], 0, 0, 0);
            dacc[1][gt] = __builtin_amdgcn_mfma_f32_16x16x32_f16(bb, a1, dacc[1][gt], 0, 0, 0);
        }
    }

#pragma unroll
    for (int tt = 0; tt < 2; ++tt) {
        const int r = w * 32 + tt * 16 + r16;
        const size_t ob = (size_t)(row0 + r) * 64;
#pragma unroll
        for (int gt = 0; gt < 4; ++gt) {
            float4 b4 = *reinterpret_cast<const float4*>(&sB[gt * 16 + q * 4]);
            st4h(&out[ob + gt * 16 + q * 4],
                 elu_(dacc[tt][gt][0] + ((const float*)&b4)[0]),
                 elu_(dacc[tt][gt][1] + ((const float*)&b4)[1]),
                 elu_(dacc[tt][gt][2] + ((const float*)&b4)[2]),
                 elu_(dacc[tt][gt][3] + ((const float*)&b4)[3]));
        }
    }
}

// ---------------- feature mix + LN + residual (verified round 8/11) ----------------
__global__ __launch_bounds__(256) void featmix_v2(const unsigned short* __restrict__ e,
                                                  const float* __restrict__ adjg,
                                                  const float* __restrict__ gamma,
                                                  const float* __restrict__ beta,
                                                  const float* __restrict__ res,
                                                  float* __restrict__ out)
{
    __shared__ __align__(16) unsigned short se[16 * 64];

    const int t = blockIdx.x & 127, bn = blockIdx.x >> 7;
    const int tid = threadIdx.x;
    const size_t base = ((size_t)bn * T_ + t) * F_ * H_;

    {
        int f = tid >> 4, c4 = (tid & 15) * 4;
        *reinterpret_cast<ushort4*>(&se[f * 64 + c4]) =
            *reinterpret_cast<const ushort4*>(&e[base + f * 64 + c4]);
    }
    __syncthreads();

    const int g = tid >> 4, hq = tid & 15;
    float ag[16];
#pragma unroll
    for (int f = 0; f < 16; ++f) ag[f] = adjg[g * 16 + f];

    float a[4] = {0.f, 0.f, 0.f, 0.f};
#pragma unroll
    for (int f = 0; f < 16; ++f) {
        ushort4 dv = *reinterpret_cast<const ushort4*>(&se[f * 64 + hq * 4]);
        float av = ag[f];
        a[0] = fmaf(av, h2f(dv.x), a[0]);
        a[1] = fmaf(av, h2f(dv.y), a[1]);
        a[2] = fmaf(av, h2f(dv.z), a[2]);
        a[3] = fmaf(av, h2f(dv.w), a[3]);
    }
    float s  = a[0] + a[1] + a[2] + a[3];
    float qv = a[0]*a[0] + a[1]*a[1] + a[2]*a[2] + a[3]*a[3];
#pragma unroll
    for (int m = 1; m < 16; m <<= 1) { s += __shfl_xor(s, m, 64); qv += __shfl_xor(qv, m, 64); }
    float mean = s * (1.f / 64.f);
    float var  = qv * (1.f / 64.f) - mean * mean;
    float rstd = rsqrtf(var + 1e-5f);

    const size_t o = base + (size_t)g * 64 + hq * 4;
    float4 rv = *reinterpret_cast<const float4*>(res + o);
    float4 ov;
    ov.x = (a[0] - mean) * rstd * gamma[hq * 4 + 0] + beta[hq * 4 + 0] + rv.x;
    ov.y = (a[1] - mean) * rstd * gamma[hq * 4 + 1] + beta[hq * 4 + 1] + rv.y;
    ov.z = (a[2] - mean) * rstd * gamma[hq * 4 + 2] + beta[hq * 4 + 2] + rv.z;
    ov.w = (a[3] - mean) * rstd * gamma[hq * 4 + 3] + beta[hq * 4 + 3] + rv.w;
    *reinterpret_cast<float4*>(out + o) = ov;
}

extern "C" void kernel_launch(void* const* d_in, const int* in_sizes, int n_in,
                              void* d_out, int out_size, void* d_ws, size_t ws_size,
                              hipStream_t stream)
{
    const float* h_in    = (const float*)d_in[0];
    const float* embs_G  = (const float*)d_in[2];
    const float* embs_g  = (const float*)d_in[3];
    const float* adj_G   = (const float*)d_in[4];
    const float* adj_g   = (const float*)d_in[5];
    const float* Wt0 = (const float*)d_in[6];  const float* bt0 = (const float*)d_in[7];
    const float* Wt1 = (const float*)d_in[8];  const float* bt1 = (const float*)d_in[9];
    const float* Wt2 = (const float*)d_in[10]; const float* bt2 = (const float*)d_in[11];
    const float* gamma_t = (const float*)d_in[12]; const float* beta_t = (const float*)d_in[13];
    const float* W_G = (const float*)d_in[14]; const float* b_G = (const float*)d_in[15];
    const float* gamma_G = (const float*)d_in[16]; const float* beta_G = (const float*)d_in[17];
    const float* W_g = (const float*)d_in[18]; const float* b_g = (const float*)d_in[19];
    const float* gamma_g = (const float*)d_in[20]; const float* beta_g = (const float*)d_in[21];

    float* out = (float*)d_out;
    char*  ws  = (char*)d_ws;
    unsigned short* d1 = (unsigned short*)ws;                          // 64 MiB
    unsigned short* nm = (unsigned short*)(ws + ((size_t)64  << 20));  // 64 MiB
    unsigned short* d2 = (unsigned short*)(ws + ((size_t)128 << 20));  // 64 MiB

    unsigned short* prep = (unsigned short*)(ws + ((size_t)192 << 20));
    unsigned short* pw   = prep;                 // 3*16*64*192
    unsigned short* pWG  = prep + 589824;
    unsigned short* pWg  = pWG + 6656;
    unsigned short* padj = pWg + 6656;

    prep_w<<<48, 256, 0, stream>>>(Wt0, Wt1, Wt2, pw);
    prep_small<<<1, 256, 0, stream>>>(adj_G, W_G, W_g, padj, pWG, pWg);

    conv_chain<<<4096, 256, 0, stream>>>(h_in, pw, bt0, bt1, bt2, gamma_t, beta_t,
                                         embs_G, pWG, b_G, d1);
    nodemix_mfma<<<8192, 256, 0, stream>>>(d1, padj, gamma_G, beta_G, nm);
    dense_mfma<8><<<4096, 256, 0, stream>>>(nm, embs_g, pWg, b_g, d2);
    featmix_v2<<<32768, 256, 0, stream>>>(d2, adj_g, gamma_g, beta_g, h_in, out);
}

// Round 14
// 306.625 us; speedup vs baseline: 4.0488x; 1.0466x over previous
//
#include <hip/hip_runtime.h>

#define BN_ 256
#define T_  128
#define F_  16
#define H_  64

using f16x8   = __attribute__((ext_vector_type(8))) _Float16;
using f32x4   = __attribute__((ext_vector_type(4))) float;
using ushort8 = __attribute__((ext_vector_type(8))) unsigned short;

__device__ __forceinline__ float elu_(float x) { return x > 0.f ? x : __expf(x) - 1.f; }
__device__ __forceinline__ unsigned short f2h(float x) {
    union { _Float16 h; unsigned short u; } v; v.h = (_Float16)x; return v.u;
}
__device__ __forceinline__ float h2f(unsigned short u) {
    union { unsigned short u; _Float16 h; } v; v.u = u; return (float)v.h;
}
__device__ __forceinline__ unsigned pk2(float a, float b) {
    auto h = __builtin_amdgcn_cvt_pkrtz(a, b);
    unsigned u; __builtin_memcpy(&u, &h, 4); return u;
}
__device__ __forceinline__ void st4h(unsigned short* p, float a, float b, float c, float d) {
    uint2 v; v.x = pk2(a, b); v.y = pk2(c, d);
    *reinterpret_cast<uint2*>(p) = v;
}

// ---------------- prep: conv weights -> fp16 transposed [l][f][g][192] ----------------
__global__ __launch_bounds__(256) void prep_w(const float* __restrict__ Wt0,
                                              const float* __restrict__ Wt1,
                                              const float* __restrict__ Wt2,
                                              unsigned short* __restrict__ pw)
{
    __shared__ unsigned short sW[64 * 200];
    const int lf = blockIdx.x, l = lf >> 4, f = lf & 15;
    const float* W = (l == 0) ? Wt0 : ((l == 1) ? Wt1 : Wt2);
    const int tid = threadIdx.x;

    for (int idx = tid; idx < 3 * 4096; idx += 256) {
        int tap = idx >> 12, rem = idx & 4095;
        int h = rem >> 6, g = rem & 63;
        sW[g * 200 + tap * 64 + h] = f2h(W[(size_t)(tap * 16 + f) * 4096 + rem]);
    }
    __syncthreads();
    for (int idx = tid; idx < 64 * 24; idx += 256) {
        int g = idx / 24, k8 = idx - g * 24;
        *reinterpret_cast<ushort8*>(&pw[((size_t)lf * 64 + g) * 192 + k8 * 8]) =
            *reinterpret_cast<const ushort8*>(&sW[g * 200 + k8 * 8]);
    }
}

// ---------------- prep: adjG [64][72], W_G [64][104], W_g [64][104] ----------------
__global__ __launch_bounds__(256) void prep_small(const float* __restrict__ adjG,
                                                  const float* __restrict__ W_G,
                                                  const float* __restrict__ W_g,
                                                  unsigned short* __restrict__ padj,
                                                  unsigned short* __restrict__ pWG,
                                                  unsigned short* __restrict__ pWg)
{
    const int tid = threadIdx.x;
    for (int idx = tid; idx < 4608; idx += 256) {
        int m = idx / 72, n = idx - m * 72;
        padj[idx] = (n < 64) ? f2h(adjG[m * 64 + n]) : (unsigned short)0;
    }
    for (int idx = tid; idx < 6656; idx += 256) {
        int g = idx / 104, k = idx - g * 104;
        pWG[idx] = (k < 80) ? f2h(W_G[k * 64 + g]) : (unsigned short)0;
    }
    for (int idx = tid; idx < 6656; idx += 256) {
        int g = idx / 104, k = idx - g * 104;
        pWg[idx] = (k < 72) ? f2h(W_g[k * 64 + g]) : (unsigned short)0;
    }
}

// ---------------- fused: tconv x3 (+LN_t) + dense_G per (bn,f); swapped-operand MFMA (verified r13) ----------------
__global__ __launch_bounds__(256, 3) void conv_chain(const float* __restrict__ in,
                                                     const unsigned short* __restrict__ pw,
                                                     const float* __restrict__ bt0,
                                                     const float* __restrict__ bt1,
                                                     const float* __restrict__ bt2,
                                                     const float* __restrict__ gamma,
                                                     const float* __restrict__ beta,
                                                     const float* __restrict__ embs_G,
                                                     const unsigned short* __restrict__ pWG,
                                                     const float* __restrict__ b_G,
                                                     unsigned short* __restrict__ d1)
{
    __shared__ __align__(16) char smem[46720];
    unsigned short* tile = (unsigned short*)smem;             // [136][72]
    unsigned short* sW   = (unsigned short*)(smem + 19584);   // [64][200]
    float*          sCst = (float*)(smem + 45184);            // [6][64]
    unsigned short* sA1  = (unsigned short*)smem;             // [128][104] overlay
    unsigned short* sWG  = (unsigned short*)(smem + 26624);   // [64][104] overlay

    const int f   = blockIdx.x & 15;
    const int bn  = blockIdx.x >> 4;
    const int tid = threadIdx.x;
    const int lane = tid & 63, w = tid >> 6;
    const int r16 = lane & 15, q = lane >> 4;

    const int et = (tid * 8) >> 4, ee = (tid * 8) & 15;
    const float* esrc = embs_G + ((((size_t)bn * T_ + et) * F_ + f) * 16 + ee);
    float4 ereg0 = *reinterpret_cast<const float4*>(esrc);
    float4 ereg1 = *reinterpret_cast<const float4*>(esrc + 4);

    if (tid < 64) {
        sCst[0 * 64 + tid] = bt0[f * 64 + tid];
        sCst[1 * 64 + tid] = bt1[f * 64 + tid];
        sCst[2 * 64 + tid] = bt2[f * 64 + tid];
        sCst[3 * 64 + tid] = gamma[tid];
        sCst[4 * 64 + tid] = beta[tid];
        sCst[5 * 64 + tid] = b_G[tid];
    }
    for (int idx = tid; idx < 136 * 16; idx += 256) {
        int r = idx >> 4, h4 = (idx & 15) * 4;
        int t = r - 4;
        if (t >= 0 && t < T_) {
            float4 x = *reinterpret_cast<const float4*>(in + (((size_t)bn * T_ + t) * F_ + f) * H_ + h4);
            st4h(&tile[r * 72 + h4], x.x, x.y, x.z, x.w);
        } else {
            uint2 z = {0, 0};
            *reinterpret_cast<uint2*>(&tile[r * 72 + h4]) = z;
        }
    }
    {
        const unsigned short* wsrc = pw + (size_t)f * 64 * 192;
        for (int idx = tid; idx < 1536; idx += 256) {
            int g = idx / 24, k8 = idx - g * 24;
            *reinterpret_cast<ushort8*>(&sW[g * 200 + k8 * 8]) =
                *reinterpret_cast<const ushort8*>(&wsrc[g * 192 + k8 * 8]);
        }
    }
    __syncthreads();

    float vv[2][4][4];

#pragma unroll
    for (int l = 0; l < 3; ++l) {
        const int dil = 1 << l;

        ushort8 wreg[6];
        if (l < 2) {
            const unsigned short* wsrc = pw + ((size_t)((l + 1) * 16 + f) * 64) * 192;
#pragma unroll
            for (int j = 0; j < 6; ++j) {
                int idx = j * 256 + tid, g = idx / 24, k8 = idx - g * 24;
                wreg[j] = *reinterpret_cast<const ushort8*>(&wsrc[g * 192 + k8 * 8]);
            }
        }
        ushort8 wgreg[4];
        if (l == 2) {
#pragma unroll
            for (int j = 0; j < 4; ++j) {
                int idx = j * 256 + tid;
                if (idx < 832) wgreg[j] = reinterpret_cast<const ushort8*>(pWG)[idx];
            }
        }

        f32x4 acc[2][4];
#pragma unroll
        for (int i = 0; i < 2; i++)
#pragma unroll
            for (int j = 0; j < 4; j++) acc[i][j] = {0.f, 0.f, 0.f, 0.f};

#pragma unroll
        for (int tap = 0; tap < 3; ++tap) {
            const int row0 = w * 32 + r16 + 4 + (tap - 1) * dil;
#pragma unroll
            for (int ks = 0; ks < 2; ++ks) {
                const int ko = ks * 32 + q * 8;
                f16x8 a0 = *reinterpret_cast<const f16x8*>(&tile[row0 * 72 + ko]);
                f16x8 a1 = *reinterpret_cast<const f16x8*>(&tile[(row0 + 16) * 72 + ko]);
                const int kb = tap * 64 + ko;
                f16x8 b0 = *reinterpret_cast<const f16x8*>(&sW[(r16     ) * 200 + kb]);
                f16x8 b1 = *reinterpret_cast<const f16x8*>(&sW[(r16 + 16) * 200 + kb]);
                f16x8 b2 = *reinterpret_cast<const f16x8*>(&sW[(r16 + 32) * 200 + kb]);
                f16x8 b3 = *reinterpret_cast<const f16x8*>(&sW[(r16 + 48) * 200 + kb]);
                acc[0][0] = __builtin_amdgcn_mfma_f32_16x16x32_f16(b0, a0, acc[0][0], 0, 0, 0);
                acc[0][1] = __builtin_amdgcn_mfma_f32_16x16x32_f16(b1, a0, acc[0][1], 0, 0, 0);
                acc[0][2] = __builtin_amdgcn_mfma_f32_16x16x32_f16(b2, a0, acc[0][2], 0, 0, 0);
                acc[0][3] = __builtin_amdgcn_mfma_f32_16x16x32_f16(b3, a0, acc[0][3], 0, 0, 0);
                acc[1][0] = __builtin_amdgcn_mfma_f32_16x16x32_f16(b0, a1, acc[1][0], 0, 0, 0);
                acc[1][1] = __builtin_amdgcn_mfma_f32_16x16x32_f16(b1, a1, acc[1][1], 0, 0, 0);
                acc[1][2] = __builtin_amdgcn_mfma_f32_16x16x32_f16(b2, a1, acc[1][2], 0, 0, 0);
                acc[1][3] = __builtin_amdgcn_mfma_f32_16x16x32_f16(b3, a1, acc[1][3], 0, 0, 0);
            }
        }

#pragma unroll
        for (int tt = 0; tt < 2; ++tt) {
#pragma unroll
            for (int gt = 0; gt < 4; ++gt) {
                float4 b4 = *reinterpret_cast<const float4*>(&sCst[l * 64 + gt * 16 + q * 4]);
#pragma unroll
                for (int r = 0; r < 4; ++r) vv[tt][gt][r] = elu_(acc[tt][gt][r] + ((const float*)&b4)[r]);
            }
            if (l == 2) {
                float s = 0.f, qq = 0.f;
#pragma unroll
                for (int gt = 0; gt < 4; ++gt)
#pragma unroll
                    for (int r = 0; r < 4; ++r) { float v = vv[tt][gt][r]; s += v; qq += v * v; }
                s += __shfl_xor(s, 16, 64); qq += __shfl_xor(qq, 16, 64);
                s += __shfl_xor(s, 32, 64); qq += __shfl_xor(qq, 32, 64);
                float mean = s * (1.f / 64.f);
                float var  = qq * (1.f / 64.f) - mean * mean;
                float rstd = rsqrtf(var + 1e-5f);
#pragma unroll
                for (int gt = 0; gt < 4; ++gt) {
                    float4 g4 = *reinterpret_cast<const float4*>(&sCst[3 * 64 + gt * 16 + q * 4]);
                    float4 be4 = *reinterpret_cast<const float4*>(&sCst[4 * 64 + gt * 16 + q * 4]);
#pragma unroll
                    for (int r = 0; r < 4; ++r)
                        vv[tt][gt][r] = (vv[tt][gt][r] - mean) * rstd * ((const float*)&g4)[r] + ((const float*)&be4)[r];
                }
            }
        }
        __syncthreads();

        if (l < 2) {
#pragma unroll
            for (int tt = 0; tt < 2; ++tt) {
                const int t = w * 32 + tt * 16 + r16;
#pragma unroll
                for (int gt = 0; gt < 4; ++gt)
                    st4h(&tile[(t + 4) * 72 + gt * 16 + q * 4],
                         vv[tt][gt][0], vv[tt][gt][1], vv[tt][gt][2], vv[tt][gt][3]);
            }
#pragma unroll
            for (int j = 0; j < 6; ++j) {
                int idx = j * 256 + tid, g = idx / 24, k8 = idx - g * 24;
                *reinterpret_cast<ushort8*>(&sW[g * 200 + k8 * 8]) = wreg[j];
            }
            __syncthreads();
        } else {
#pragma unroll
            for (int tt = 0; tt < 2; ++tt) {
                const int t = w * 32 + tt * 16 + r16;
#pragma unroll
                for (int gt = 0; gt < 4; ++gt)
                    st4h(&sA1[t * 104 + gt * 16 + q * 4],
                         vv[tt][gt][0], vv[tt][gt][1], vv[tt][gt][2], vv[tt][gt][3]);
            }
            st4h(&sA1[et * 104 + 64 + ee],     ereg0.x, ereg0.y, ereg0.z, ereg0.w);
            st4h(&sA1[et * 104 + 64 + ee + 4], ereg1.x, ereg1.y, ereg1.z, ereg1.w);
            {
                int r = tid >> 1, half = tid & 1;
                ushort8 z = {0,0,0,0,0,0,0,0};
                *reinterpret_cast<ushort8*>(&sA1[r * 104 + 80 + half * 8]) = z;
            }
#pragma unroll
            for (int j = 0; j < 4; ++j) {
                int idx = j * 256 + tid;
                if (idx < 832) reinterpret_cast<ushort8*>(sWG)[idx] = wgreg[j];
            }
            __syncthreads();
        }
    }

    f32x4 dacc[2][4];
#pragma unroll
    for (int i = 0; i < 2; i++)
#pragma unroll
        for (int j = 0; j < 4; j++) dacc[i][j] = {0.f, 0.f, 0.f, 0.f};

#pragma unroll
    for (int ks = 0; ks < 3; ++ks) {
        const int ko = ks * 32 + q * 8;
        f16x8 a0 = *reinterpret_cast<const f16x8*>(&sA1[(w * 32 + r16) * 104 + ko]);
        f16x8 a1 = *reinterpret_cast<const f16x8*>(&sA1[(w * 32 + 16 + r16) * 104 + ko]);
#pragma unroll
        for (int gt = 0; gt < 4; ++gt) {
            f16x8 bb = *reinterpret_cast<const f16x8*>(&sWG[(gt * 16 + r16) * 104 + ko]);
            dacc[0][gt] = __builtin_amdgcn_mfma_f32_16x16x32_f16(bb, a0, dacc[0][gt], 0, 0, 0);
            dacc[1][gt] = __builtin_amdgcn_mfma_f32_16x16x32_f16(bb, a1, dacc[1][gt], 0, 0, 0);
        }
    }

#pragma unroll
    for (int tt = 0; tt < 2; ++tt) {
        const int t = w * 32 + tt * 16 + r16;
        const size_t ob = (((size_t)bn * T_ + t) * F_ + f) * H_;
#pragma unroll
        for (int gt = 0; gt < 4; ++gt) {
            float4 b4 = *reinterpret_cast<const float4*>(&sCst[5 * 64 + gt * 16 + q * 4]);
            st4h(&d1[ob + gt * 16 + q * 4],
                 elu_(dacc[tt][gt][0] + ((const float*)&b4)[0]),
                 elu_(dacc[tt][gt][1] + ((const float*)&b4)[1]),
                 elu_(dacc[tt][gt][2] + ((const float*)&b4)[2]),
                 elu_(dacc[tt][gt][3] + ((const float*)&b4)[3]));
        }
    }
}

// ---------------- fused: node mix + LN_G + dense_g  (NO LDS overlay; 2 barriers) ----------------
__global__ __launch_bounds__(256) void nodemix_dense2(const unsigned short* __restrict__ d1,
                                                      const unsigned short* __restrict__ padj,
                                                      const float* __restrict__ gamma,
                                                      const float* __restrict__ beta,
                                                      const float* __restrict__ embs_g,
                                                      const unsigned short* __restrict__ pWg,
                                                      const float* __restrict__ b_g,
                                                      unsigned short* __restrict__ d2)
{
    __shared__ __align__(16) char smem[47360];
    unsigned short* sAdj = (unsigned short*)smem;            // [64][72]
    unsigned short* sXT  = (unsigned short*)(smem + 9216);   // [64][88]
    unsigned short* sA2  = (unsigned short*)(smem + 20480);  // [64][104] (disjoint!)
    unsigned short* sWg  = (unsigned short*)(smem + 33792);  // [64][104]
    float*          sBg  = (float*)(smem + 47104);           // [64]

    const int f = blockIdx.x & 15, t = (blockIdx.x >> 4) & 127, b = blockIdx.x >> 11;
    const int tid = threadIdx.x, lane = tid & 63, w = tid >> 6;

    if (tid < 64) sBg[tid] = b_g[tid];
    for (int idx = tid; idx < 576; idx += 256)
        reinterpret_cast<ushort8*>(sAdj)[idx] = reinterpret_cast<const ushort8*>(padj)[idx];
    for (int idx = tid; idx < 832; idx += 256)
        reinterpret_cast<ushort8*>(sWg)[idx] = reinterpret_cast<const ushort8*>(pWg)[idx];
    // embs_g -> sA2 cols 64..95 (c<8 real, else 0); rows m
    for (int idx = tid; idx < 2048; idx += 256) {
        int m = idx >> 5, c = idx & 31;
        unsigned short v = 0;
        if (c < 8) v = f2h(embs_g[(((size_t)(b * 64 + m) * T_ + t) * F_ + f) * 8 + c]);
        sA2[m * 104 + 64 + c] = v;
    }
    {   // X^T staging (verified r13 pattern)
        const int n = lane;
        const size_t base = (((size_t)(b * 64 + n) * T_ + t) * F_ + f) * H_;
#pragma unroll
        for (int p = 0; p < 2; ++p) {
            int c = w + p * 4;
            ushort8 v = *reinterpret_cast<const ushort8*>(&d1[base + c * 8]);
#pragma unroll
            for (int i = 0; i < 8; ++i) sXT[(c * 8 + i) * 88 + n] = v[i];
        }
    }
    __syncthreads();

    const int r16 = lane & 15, q = lane >> 4;
    f32x4 acc[4];
#pragma unroll
    for (int j = 0; j < 4; j++) acc[j] = {0.f, 0.f, 0.f, 0.f};

#pragma unroll
    for (int ks = 0; ks < 2; ++ks) {
        f16x8 af = *reinterpret_cast<const f16x8*>(&sAdj[(w * 16 + r16) * 72 + ks * 32 + q * 8]);
#pragma unroll
        for (int ht = 0; ht < 4; ++ht) {
            f16x8 xf = *reinterpret_cast<const f16x8*>(&sXT[(ht * 16 + r16) * 88 + ks * 32 + q * 8]);
            acc[ht] = __builtin_amdgcn_mfma_f32_16x16x32_f16(xf, af, acc[ht], 0, 0, 0);
        }
    }

    // LN over h for row m (verified r13), write into sA2 cols 0..63 (disjoint region, no hazard)
    const int m = w * 16 + r16;
    float s = 0.f, qq = 0.f;
#pragma unroll
    for (int ht = 0; ht < 4; ++ht)
#pragma unroll
        for (int r = 0; r < 4; ++r) { float v = acc[ht][r]; s += v; qq += v * v; }
    s += __shfl_xor(s, 16, 64); qq += __shfl_xor(qq, 16, 64);
    s += __shfl_xor(s, 32, 64); qq += __shfl_xor(qq, 32, 64);
    float mean = s * (1.f / 64.f);
    float var  = qq * (1.f / 64.f) - mean * mean;
    float rstd = rsqrtf(var + 1e-5f);

#pragma unroll
    for (int ht = 0; ht < 4; ++ht) {
        float4 g4  = *reinterpret_cast<const float4*>(&gamma[ht * 16 + q * 4]);
        float4 be4 = *reinterpret_cast<const float4*>(&beta[ht * 16 + q * 4]);
        st4h(&sA2[m * 104 + ht * 16 + q * 4],
             (acc[ht][0] - mean) * rstd * ((const float*)&g4)[0] + ((const float*)&be4)[0],
             (acc[ht][1] - mean) * rstd * ((const float*)&g4)[1] + ((const float*)&be4)[1],
             (acc[ht][2] - mean) * rstd * ((const float*)&g4)[2] + ((const float*)&be4)[2],
             (acc[ht][3] - mean) * rstd * ((const float*)&g4)[3] + ((const float*)&be4)[3]);
    }
    __syncthreads();

    // dense_g MFMA: D[g][m], A = sWg rows g (wave-owned 16), B = sA2 rows m (4 tiles)
    f32x4 dacc[4];
#pragma unroll
    for (int j = 0; j < 4; j++) dacc[j] = {0.f, 0.f, 0.f, 0.f};

#pragma unroll
    for (int ks = 0; ks < 3; ++ks) {
        const int ko = ks * 32 + q * 8;
        f16x8 aw = *reinterpret_cast<const f16x8*>(&sWg[(w * 16 + r16) * 104 + ko]);
#pragma unroll
        for (int mt = 0; mt < 4; ++mt) {
            f16x8 bx = *reinterpret_cast<const f16x8*>(&sA2[(mt * 16 + r16) * 104 + ko]);
            dacc[mt] = __builtin_amdgcn_mfma_f32_16x16x32_f16(aw, bx, dacc[mt], 0, 0, 0);
        }
    }

    float4 b4 = *reinterpret_cast<const float4*>(&sBg[w * 16 + q * 4]);  // bias indexed by g
#pragma unroll
    for (int mt = 0; mt < 4; ++mt) {
        const int mm = mt * 16 + r16;
        const size_t row = (((size_t)(b * 64 + mm) * T_ + t) * F_ + f);
        st4h(&d2[row * H_ + w * 16 + q * 4],
             elu_(dacc[mt][0] + b4.x), elu_(dacc[mt][1] + b4.y),
             elu_(dacc[mt][2] + b4.z), elu_(dacc[mt][3] + b4.w));
    }
}

// ---------------- feature mix + LN + residual, 8 t per block (same math as verified v2) ----------------
__global__ __launch_bounds__(256) void featmix_v3(const unsigned short* __restrict__ e,
                                                  const float* __restrict__ adjg,
                                                  const float* __restrict__ gamma,
                                                  const float* __restrict__ beta,
                                                  const float* __restrict__ res,
                                                  float* __restrict__ out)
{
    __shared__ __align__(16) unsigned short se[8 * 16 * 64];

    const int t0 = (blockIdx.x & 15) * 8, bn = blockIdx.x >> 4;
    const int tid = threadIdx.x;

    {
        int f = tid >> 4, c4 = (tid & 15) * 4;
#pragma unroll
        for (int tl = 0; tl < 8; ++tl)
            *reinterpret_cast<ushort4*>(&se[tl * 1024 + f * 64 + c4]) =
                *reinterpret_cast<const ushort4*>(&e[(((size_t)bn * T_ + t0 + tl) * F_ + f) * H_ + c4]);
    }
    __syncthreads();

    const int g = tid >> 4, hq = tid & 15;
    float ag[16];
#pragma unroll
    for (int f = 0; f < 16; ++f) ag[f] = adjg[g * 16 + f];
    float gm0 = gamma[hq * 4 + 0], gm1 = gamma[hq * 4 + 1], gm2 = gamma[hq * 4 + 2], gm3 = gamma[hq * 4 + 3];
    float be0 = beta[hq * 4 + 0],  be1 = beta[hq * 4 + 1],  be2 = beta[hq * 4 + 2],  be3 = beta[hq * 4 + 3];

    for (int tl = 0; tl < 8; ++tl) {
        float a0 = 0.f, a1 = 0.f, a2 = 0.f, a3 = 0.f;
#pragma unroll
        for (int f = 0; f < 16; ++f) {
            ushort4 dv = *reinterpret_cast<const ushort4*>(&se[tl * 1024 + f * 64 + hq * 4]);
            float av = ag[f];
            a0 = fmaf(av, h2f(dv.x), a0);
            a1 = fmaf(av, h2f(dv.y), a1);
            a2 = fmaf(av, h2f(dv.z), a2);
            a3 = fmaf(av, h2f(dv.w), a3);
        }
        float s  = a0 + a1 + a2 + a3;
        float qv = a0*a0 + a1*a1 + a2*a2 + a3*a3;
#pragma unroll
        for (int m = 1; m < 16; m <<= 1) { s += __shfl_xor(s, m, 64); qv += __shfl_xor(qv, m, 64); }
        float mean = s * (1.f / 64.f);
        float var  = qv * (1.f / 64.f) - mean * mean;
        float rstd = rsqrtf(var + 1e-5f);

        const size_t o = (((size_t)bn * T_ + t0 + tl) * F_ + g) * H_ + hq * 4;
        float4 rv = *reinterpret_cast<const float4*>(res + o);
        float4 ov;
        ov.x = (a0 - mean) * rstd * gm0 + be0 + rv.x;
        ov.y = (a1 - mean) * rstd * gm1 + be1 + rv.y;
        ov.z = (a2 - mean) * rstd * gm2 + be2 + rv.z;
        ov.w = (a3 - mean) * rstd * gm3 + be3 + rv.w;
        *reinterpret_cast<float4*>(out + o) = ov;
    }
}

extern "C" void kernel_launch(void* const* d_in, const int* in_sizes, int n_in,
                              void* d_out, int out_size, void* d_ws, size_t ws_size,
                              hipStream_t stream)
{
    const float* h_in    = (const float*)d_in[0];
    const float* embs_G  = (const float*)d_in[2];
    const float* embs_g  = (const float*)d_in[3];
    const float* adj_G   = (const float*)d_in[4];
    const float* adj_g   = (const float*)d_in[5];
    const float* Wt0 = (const float*)d_in[6];  const float* bt0 = (const float*)d_in[7];
    const float* Wt1 = (const float*)d_in[8];  const float* bt1 = (const float*)d_in[9];
    const float* Wt2 = (const float*)d_in[10]; const float* bt2 = (const float*)d_in[11];
    const float* gamma_t = (const float*)d_in[12]; const float* beta_t = (const float*)d_in[13];
    const float* W_G = (const float*)d_in[14]; const float* b_G = (const float*)d_in[15];
    const float* gamma_G = (const float*)d_in[16]; const float* beta_G = (const float*)d_in[17];
    const float* W_g = (const float*)d_in[18]; const float* b_g = (const float*)d_in[19];
    const float* gamma_g = (const float*)d_in[20]; const float* beta_g = (const float*)d_in[21];

    float* out = (float*)d_out;
    char*  ws  = (char*)d_ws;
    unsigned short* d1 = (unsigned short*)ws;                          // 64 MiB
    unsigned short* d2 = (unsigned short*)(ws + ((size_t)64 << 20));   // 64 MiB

    unsigned short* prep = (unsigned short*)(ws + ((size_t)192 << 20));
    unsigned short* pw   = prep;                 // 3*16*64*192
    unsigned short* pWG  = prep + 589824;
    unsigned short* pWg  = pWG + 6656;
    unsigned short* padj = pWg + 6656;

    prep_w<<<48, 256, 0, stream>>>(Wt0, Wt1, Wt2, pw);
    prep_small<<<1, 256, 0, stream>>>(adj_G, W_G, W_g, padj, pWG, pWg);

    conv_chain<<<4096, 256, 0, stream>>>(h_in, pw, bt0, bt1, bt2, gamma_t, beta_t,
                                         embs_G, pWG, b_G, d1);
    nodemix_dense2<<<8192, 256, 0, stream>>>(d1, padj, gamma_G, beta_G,
                                             embs_g, pWg, b_g, d2);
    featmix_v3<<<4096, 256, 0, stream>>>(d2, adj_g, gamma_g, beta_g, h_in, out);
}

// Round 15
// 256.444 us; speedup vs baseline: 4.8411x; 1.1957x over previous
//
#include <hip/hip_runtime.h>

#define BN_ 256
#define T_  128
#define F_  16
#define H_  64

using f16x8   = __attribute__((ext_vector_type(8))) _Float16;
using f32x4   = __attribute__((ext_vector_type(4))) float;
using ushort8 = __attribute__((ext_vector_type(8))) unsigned short;

__device__ __forceinline__ float elu_(float x) { return x > 0.f ? x : __expf(x) - 1.f; }
__device__ __forceinline__ unsigned short f2h(float x) {
    union { _Float16 h; unsigned short u; } v; v.h = (_Float16)x; return v.u;
}
__device__ __forceinline__ float h2f(unsigned short u) {
    union { unsigned short u; _Float16 h; } v; v.u = u; return (float)v.h;
}
__device__ __forceinline__ unsigned pk2(float a, float b) {
    auto h = __builtin_amdgcn_cvt_pkrtz(a, b);
    unsigned u; __builtin_memcpy(&u, &h, 4); return u;
}
__device__ __forceinline__ void st4h(unsigned short* p, float a, float b, float c, float d) {
    uint2 v; v.x = pk2(a, b); v.y = pk2(c, d);
    *reinterpret_cast<uint2*>(p) = v;
}

// ---------------- prep: conv weights -> fp16 transposed [l][f][g][192] ----------------
__global__ __launch_bounds__(256) void prep_w(const float* __restrict__ Wt0,
                                              const float* __restrict__ Wt1,
                                              const float* __restrict__ Wt2,
                                              unsigned short* __restrict__ pw)
{
    __shared__ unsigned short sW[64 * 200];
    const int lf = blockIdx.x, l = lf >> 4, f = lf & 15;
    const float* W = (l == 0) ? Wt0 : ((l == 1) ? Wt1 : Wt2);
    const int tid = threadIdx.x;

    for (int idx = tid; idx < 3 * 4096; idx += 256) {
        int tap = idx >> 12, rem = idx & 4095;
        int h = rem >> 6, g = rem & 63;
        sW[g * 200 + tap * 64 + h] = f2h(W[(size_t)(tap * 16 + f) * 4096 + rem]);
    }
    __syncthreads();
    for (int idx = tid; idx < 64 * 24; idx += 256) {
        int g = idx / 24, k8 = idx - g * 24;
        *reinterpret_cast<ushort8*>(&pw[((size_t)lf * 64 + g) * 192 + k8 * 8]) =
            *reinterpret_cast<const ushort8*>(&sW[g * 200 + k8 * 8]);
    }
}

// ---------------- prep: adjG [64][72], W_G [64][104], W_g [64][104] ----------------
__global__ __launch_bounds__(256) void prep_small(const float* __restrict__ adjG,
                                                  const float* __restrict__ W_G,
                                                  const float* __restrict__ W_g,
                                                  unsigned short* __restrict__ padj,
                                                  unsigned short* __restrict__ pWG,
                                                  unsigned short* __restrict__ pWg)
{
    const int tid = threadIdx.x;
    for (int idx = tid; idx < 4608; idx += 256) {
        int m = idx / 72, n = idx - m * 72;
        padj[idx] = (n < 64) ? f2h(adjG[m * 64 + n]) : (unsigned short)0;
    }
    for (int idx = tid; idx < 6656; idx += 256) {
        int g = idx / 104, k = idx - g * 104;
        pWG[idx] = (k < 80) ? f2h(W_G[k * 64 + g]) : (unsigned short)0;
    }
    for (int idx = tid; idx < 6656; idx += 256) {
        int g = idx / 104, k = idx - g * 104;
        pWg[idx] = (k < 72) ? f2h(W_g[k * 64 + g]) : (unsigned short)0;
    }
}

// ---------------- fused: tconv x3 (+LN_t) + dense_G per (bn,f); swapped-operand MFMA (verified r13/r14) ----------------
__global__ __launch_bounds__(256, 3) void conv_chain(const float* __restrict__ in,
                                                     const unsigned short* __restrict__ pw,
                                                     const float* __restrict__ bt0,
                                                     const float* __restrict__ bt1,
                                                     const float* __restrict__ bt2,
                                                     const float* __restrict__ gamma,
                                                     const float* __restrict__ beta,
                                                     const float* __restrict__ embs_G,
                                                     const unsigned short* __restrict__ pWG,
                                                     const float* __restrict__ b_G,
                                                     unsigned short* __restrict__ d1)
{
    __shared__ __align__(16) char smem[46720];
    unsigned short* tile = (unsigned short*)smem;             // [136][72]
    unsigned short* sW   = (unsigned short*)(smem + 19584);   // [64][200]
    float*          sCst = (float*)(smem + 45184);            // [6][64]
    unsigned short* sA1  = (unsigned short*)smem;             // [128][104] overlay
    unsigned short* sWG  = (unsigned short*)(smem + 26624);   // [64][104] overlay

    const int f   = blockIdx.x & 15;
    const int bn  = blockIdx.x >> 4;
    const int tid = threadIdx.x;
    const int lane = tid & 63, w = tid >> 6;
    const int r16 = lane & 15, q = lane >> 4;

    const int et = (tid * 8) >> 4, ee = (tid * 8) & 15;
    const float* esrc = embs_G + ((((size_t)bn * T_ + et) * F_ + f) * 16 + ee);
    float4 ereg0 = *reinterpret_cast<const float4*>(esrc);
    float4 ereg1 = *reinterpret_cast<const float4*>(esrc + 4);

    if (tid < 64) {
        sCst[0 * 64 + tid] = bt0[f * 64 + tid];
        sCst[1 * 64 + tid] = bt1[f * 64 + tid];
        sCst[2 * 64 + tid] = bt2[f * 64 + tid];
        sCst[3 * 64 + tid] = gamma[tid];
        sCst[4 * 64 + tid] = beta[tid];
        sCst[5 * 64 + tid] = b_G[tid];
    }
    for (int idx = tid; idx < 136 * 16; idx += 256) {
        int r = idx >> 4, h4 = (idx & 15) * 4;
        int t = r - 4;
        if (t >= 0 && t < T_) {
            float4 x = *reinterpret_cast<const float4*>(in + (((size_t)bn * T_ + t) * F_ + f) * H_ + h4);
            st4h(&tile[r * 72 + h4], x.x, x.y, x.z, x.w);
        } else {
            uint2 z = {0, 0};
            *reinterpret_cast<uint2*>(&tile[r * 72 + h4]) = z;
        }
    }
    {
        const unsigned short* wsrc = pw + (size_t)f * 64 * 192;
        for (int idx = tid; idx < 1536; idx += 256) {
            int g = idx / 24, k8 = idx - g * 24;
            *reinterpret_cast<ushort8*>(&sW[g * 200 + k8 * 8]) =
                *reinterpret_cast<const ushort8*>(&wsrc[g * 192 + k8 * 8]);
        }
    }
    __syncthreads();

    float vv[2][4][4];

#pragma unroll
    for (int l = 0; l < 3; ++l) {
        const int dil = 1 << l;

        ushort8 wreg[6];
        if (l < 2) {
            const unsigned short* wsrc = pw + ((size_t)((l + 1) * 16 + f) * 64) * 192;
#pragma unroll
            for (int j = 0; j < 6; ++j) {
                int idx = j * 256 + tid, g = idx / 24, k8 = idx - g * 24;
                wreg[j] = *reinterpret_cast<const ushort8*>(&wsrc[g * 192 + k8 * 8]);
            }
        }
        ushort8 wgreg[4];
        if (l == 2) {
#pragma unroll
            for (int j = 0; j < 4; ++j) {
                int idx = j * 256 + tid;
                if (idx < 832) wgreg[j] = reinterpret_cast<const ushort8*>(pWG)[idx];
            }
        }

        f32x4 acc[2][4];
#pragma unroll
        for (int i = 0; i < 2; i++)
#pragma unroll
            for (int j = 0; j < 4; j++) acc[i][j] = {0.f, 0.f, 0.f, 0.f};

#pragma unroll
        for (int tap = 0; tap < 3; ++tap) {
            const int row0 = w * 32 + r16 + 4 + (tap - 1) * dil;
#pragma unroll
            for (int ks = 0; ks < 2; ++ks) {
                const int ko = ks * 32 + q * 8;
                f16x8 a0 = *reinterpret_cast<const f16x8*>(&tile[row0 * 72 + ko]);
                f16x8 a1 = *reinterpret_cast<const f16x8*>(&tile[(row0 + 16) * 72 + ko]);
                const int kb = tap * 64 + ko;
                f16x8 b0 = *reinterpret_cast<const f16x8*>(&sW[(r16     ) * 200 + kb]);
                f16x8 b1 = *reinterpret_cast<const f16x8*>(&sW[(r16 + 16) * 200 + kb]);
                f16x8 b2 = *reinterpret_cast<const f16x8*>(&sW[(r16 + 32) * 200 + kb]);
                f16x8 b3 = *reinterpret_cast<const f16x8*>(&sW[(r16 + 48) * 200 + kb]);
                acc[0][0] = __builtin_amdgcn_mfma_f32_16x16x32_f16(b0, a0, acc[0][0], 0, 0, 0);
                acc[0][1] = __builtin_amdgcn_mfma_f32_16x16x32_f16(b1, a0, acc[0][1], 0, 0, 0);
                acc[0][2] = __builtin_amdgcn_mfma_f32_16x16x32_f16(b2, a0, acc[0][2], 0, 0, 0);
                acc[0][3] = __builtin_amdgcn_mfma_f32_16x16x32_f16(b3, a0, acc[0][3], 0, 0, 0);
                acc[1][0] = __builtin_amdgcn_mfma_f32_16x16x32_f16(b0, a1, acc[1][0], 0, 0, 0);
                acc[1][1] = __builtin_amdgcn_mfma_f32_16x16x32_f16(b1, a1, acc[1][1], 0, 0, 0);
                acc[1][2] = __builtin_amdgcn_mfma_f32_16x16x32_f16(b2, a1, acc[1][2], 0, 0, 0);
                acc[1][3] = __builtin_amdgcn_mfma_f32_16x16x32_f16(b3, a1, acc[1][3], 0, 0, 0);
            }
        }

#pragma unroll
        for (int tt = 0; tt < 2; ++tt) {
#pragma unroll
            for (int gt = 0; gt < 4; ++gt) {
                float4 b4 = *reinterpret_cast<const float4*>(&sCst[l * 64 + gt * 16 + q * 4]);
#pragma unroll
                for (int r = 0; r < 4; ++r) vv[tt][gt][r] = elu_(acc[tt][gt][r] + ((const float*)&b4)[r]);
            }
            if (l == 2) {
                float s = 0.f, qq = 0.f;
#pragma unroll
                for (int gt = 0; gt < 4; ++gt)
#pragma unroll
                    for (int r = 0; r < 4; ++r) { float v = vv[tt][gt][r]; s += v; qq += v * v; }
                s += __shfl_xor(s, 16, 64); qq += __shfl_xor(qq, 16, 64);
                s += __shfl_xor(s, 32, 64); qq += __shfl_xor(qq, 32, 64);
                float mean = s * (1.f / 64.f);
                float var  = qq * (1.f / 64.f) - mean * mean;
                float rstd = rsqrtf(var + 1e-5f);
#pragma unroll
                for (int gt = 0; gt < 4; ++gt) {
                    float4 g4 = *reinterpret_cast<const float4*>(&sCst[3 * 64 + gt * 16 + q * 4]);
                    float4 be4 = *reinterpret_cast<const float4*>(&sCst[4 * 64 + gt * 16 + q * 4]);
#pragma unroll
                    for (int r = 0; r < 4; ++r)
                        vv[tt][gt][r] = (vv[tt][gt][r] - mean) * rstd * ((const float*)&g4)[r] + ((const float*)&be4)[r];
                }
            }
        }
        __syncthreads();

        if (l < 2) {
#pragma unroll
            for (int tt = 0; tt < 2; ++tt) {
                const int t = w * 32 + tt * 16 + r16;
#pragma unroll
                for (int gt = 0; gt < 4; ++gt)
                    st4h(&tile[(t + 4) * 72 + gt * 16 + q * 4],
                         vv[tt][gt][0], vv[tt][gt][1], vv[tt][gt][2], vv[tt][gt][3]);
            }
#pragma unroll
            for (int j = 0; j < 6; ++j) {
                int idx = j * 256 + tid, g = idx / 24, k8 = idx - g * 24;
                *reinterpret_cast<ushort8*>(&sW[g * 200 + k8 * 8]) = wreg[j];
            }
            __syncthreads();
        } else {
#pragma unroll
            for (int tt = 0; tt < 2; ++tt) {
                const int t = w * 32 + tt * 16 + r16;
#pragma unroll
                for (int gt = 0; gt < 4; ++gt)
                    st4h(&sA1[t * 104 + gt * 16 + q * 4],
                         vv[tt][gt][0], vv[tt][gt][1], vv[tt][gt][2], vv[tt][gt][3]);
            }
            st4h(&sA1[et * 104 + 64 + ee],     ereg0.x, ereg0.y, ereg0.z, ereg0.w);
            st4h(&sA1[et * 104 + 64 + ee + 4], ereg1.x, ereg1.y, ereg1.z, ereg1.w);
            {
                int r = tid >> 1, half = tid & 1;
                ushort8 z = {0,0,0,0,0,0,0,0};
                *reinterpret_cast<ushort8*>(&sA1[r * 104 + 80 + half * 8]) = z;
            }
#pragma unroll
            for (int j = 0; j < 4; ++j) {
                int idx = j * 256 + tid;
                if (idx < 832) reinterpret_cast<ushort8*>(sWG)[idx] = wgreg[j];
            }
            __syncthreads();
        }
    }

    f32x4 dacc[2][4];
#pragma unroll
    for (int i = 0; i < 2; i++)
#pragma unroll
        for (int j = 0; j < 4; j++) dacc[i][j] = {0.f, 0.f, 0.f, 0.f};

#pragma unroll
    for (int ks = 0; ks < 3; ++ks) {
        const int ko = ks * 32 + q * 8;
        f16x8 a0 = *reinterpret_cast<const f16x8*>(&sA1[(w * 32 + r16) * 104 + ko]);
        f16x8 a1 = *reinterpret_cast<const f16x8*>(&sA1[(w * 32 + 16 + r16) * 104 + ko]);
#pragma unroll
        for (int gt = 0; gt < 4; ++gt) {
            f16x8 bb = *reinterpret_cast<const f16x8*>(&sWG[(gt * 16 + r16) * 104 + ko]);
            dacc[0][gt] = __builtin_amdgcn_mfma_f32_16x16x32_f16(bb, a0, dacc[0][gt], 0, 0, 0);
            dacc[1][gt] = __builtin_amdgcn_mfma_f32_16x16x32_f16(bb, a1, dacc[1][gt], 0, 0, 0);
        }
    }

#pragma unroll
    for (int tt = 0; tt < 2; ++tt) {
        const int t = w * 32 + tt * 16 + r16;
        const size_t ob = (((size_t)bn * T_ + t) * F_ + f) * H_;
#pragma unroll
        for (int gt = 0; gt < 4; ++gt) {
            float4 b4 = *reinterpret_cast<const float4*>(&sCst[5 * 64 + gt * 16 + q * 4]);
            st4h(&d1[ob + gt * 16 + q * 4],
                 elu_(dacc[tt][gt][0] + ((const float*)&b4)[0]),
                 elu_(dacc[tt][gt][1] + ((const float*)&b4)[1]),
                 elu_(dacc[tt][gt][2] + ((const float*)&b4)[2]),
                 elu_(dacc[tt][gt][3] + ((const float*)&b4)[3]));
        }
    }
}

// ---------------- fused: node mix + LN_G + dense_g, 4 t per block, reg-prefetched ----------------
__global__ __launch_bounds__(256) void nodemix_dense2(const unsigned short* __restrict__ d1,
                                                      const unsigned short* __restrict__ padj,
                                                      const float* __restrict__ gamma,
                                                      const float* __restrict__ beta,
                                                      const float* __restrict__ embs_g,
                                                      const unsigned short* __restrict__ pWg,
                                                      const float* __restrict__ b_g,
                                                      unsigned short* __restrict__ d2)
{
    __shared__ __align__(16) char smem[47872];
    unsigned short* sAdj = (unsigned short*)smem;            // [64][72]
    unsigned short* sXT  = (unsigned short*)(smem + 9216);   // [64][88]
    unsigned short* sA2  = (unsigned short*)(smem + 20480);  // [64][104]
    unsigned short* sWg  = (unsigned short*)(smem + 33792);  // [64][104]
    float*          sBg  = (float*)(smem + 47104);           // [64]
    float*          sGB  = (float*)(smem + 47360);           // [128] gamma|beta

    const int f  = blockIdx.x & 15;
    const int tq = (blockIdx.x >> 4) & 31;
    const int b  = blockIdx.x >> 9;
    const int t0 = tq * 4;
    const int tid = threadIdx.x, lane = tid & 63, w = tid >> 6;
    const int r16 = lane & 15, q = lane >> 4;

    if (tid < 64) sBg[tid] = b_g[tid];
    if (tid >= 64 && tid < 128) sGB[tid - 64] = gamma[tid - 64];
    if (tid >= 128 && tid < 192) sGB[tid - 64] = beta[tid - 128];
    for (int idx = tid; idx < 576; idx += 256)
        reinterpret_cast<ushort8*>(sAdj)[idx] = reinterpret_cast<const ushort8*>(padj)[idx];
    for (int idx = tid; idx < 832; idx += 256)
        reinterpret_cast<ushort8*>(sWg)[idx] = reinterpret_cast<const ushort8*>(pWg)[idx];
    // zero sA2 cols 72..95 once (never rewritten)
    for (int idx = tid; idx < 192; idx += 256) {
        int m = idx / 3, k8 = idx - m * 3;
        ushort8 z = {0,0,0,0,0,0,0,0};
        *reinterpret_cast<ushort8*>(&sA2[m * 104 + 72 + k8 * 8]) = z;
    }

    // prefetch t0: X^T fragments + embs
    const int n = lane;
    const int em = tid >> 2, ec = (tid & 3) * 2;
    ushort8 xr0, xr1;
    float2  er;
    {
        const size_t base = (((size_t)(b * 64 + n) * T_ + t0) * F_ + f) * H_;
        xr0 = *reinterpret_cast<const ushort8*>(&d1[base + (w    ) * 8]);
        xr1 = *reinterpret_cast<const ushort8*>(&d1[base + (w + 4) * 8]);
        er  = *reinterpret_cast<const float2*>(&embs_g[((((size_t)(b * 64 + em)) * T_ + t0) * F_ + f) * 8 + ec]);
    }

    for (int tt = 0; tt < 4; ++tt) {
        const int t = t0 + tt;

        // write staged regs -> LDS
        {
            int c0 = w, c1 = w + 4;
#pragma unroll
            for (int i = 0; i < 8; ++i) sXT[(c0 * 8 + i) * 88 + n] = xr0[i];
#pragma unroll
            for (int i = 0; i < 8; ++i) sXT[(c1 * 8 + i) * 88 + n] = xr1[i];
            *reinterpret_cast<unsigned*>(&sA2[em * 104 + 64 + ec]) = pk2(er.x, er.y);
        }
        // prefetch t+1
        if (tt < 3) {
            const size_t base = (((size_t)(b * 64 + n) * T_ + t + 1) * F_ + f) * H_;
            xr0 = *reinterpret_cast<const ushort8*>(&d1[base + (w    ) * 8]);
            xr1 = *reinterpret_cast<const ushort8*>(&d1[base + (w + 4) * 8]);
            er  = *reinterpret_cast<const float2*>(&embs_g[((((size_t)(b * 64 + em)) * T_ + t + 1) * F_ + f) * 8 + ec]);
        }
        __syncthreads();

        // nodemix MFMA (verified): D[h][m], lane owns fixed m = w*16+r16
        f32x4 acc[4];
#pragma unroll
        for (int j = 0; j < 4; j++) acc[j] = {0.f, 0.f, 0.f, 0.f};
#pragma unroll
        for (int ks = 0; ks < 2; ++ks) {
            f16x8 af = *reinterpret_cast<const f16x8*>(&sAdj[(w * 16 + r16) * 72 + ks * 32 + q * 8]);
#pragma unroll
            for (int ht = 0; ht < 4; ++ht) {
                f16x8 xf = *reinterpret_cast<const f16x8*>(&sXT[(ht * 16 + r16) * 88 + ks * 32 + q * 8]);
                acc[ht] = __builtin_amdgcn_mfma_f32_16x16x32_f16(xf, af, acc[ht], 0, 0, 0);
            }
        }

        const int m = w * 16 + r16;
        float s = 0.f, qq = 0.f;
#pragma unroll
        for (int ht = 0; ht < 4; ++ht)
#pragma unroll
            for (int r = 0; r < 4; ++r) { float v = acc[ht][r]; s += v; qq += v * v; }
        s += __shfl_xor(s, 16, 64); qq += __shfl_xor(qq, 16, 64);
        s += __shfl_xor(s, 32, 64); qq += __shfl_xor(qq, 32, 64);
        float mean = s * (1.f / 64.f);
        float var  = qq * (1.f / 64.f) - mean * mean;
        float rstd = rsqrtf(var + 1e-5f);

#pragma unroll
        for (int ht = 0; ht < 4; ++ht) {
            float4 g4  = *reinterpret_cast<const float4*>(&sGB[ht * 16 + q * 4]);
            float4 be4 = *reinterpret_cast<const float4*>(&sGB[64 + ht * 16 + q * 4]);
            st4h(&sA2[m * 104 + ht * 16 + q * 4],
                 (acc[ht][0] - mean) * rstd * ((const float*)&g4)[0] + ((const float*)&be4)[0],
                 (acc[ht][1] - mean) * rstd * ((const float*)&g4)[1] + ((const float*)&be4)[1],
                 (acc[ht][2] - mean) * rstd * ((const float*)&g4)[2] + ((const float*)&be4)[2],
                 (acc[ht][3] - mean) * rstd * ((const float*)&g4)[3] + ((const float*)&be4)[3]);
        }
        __syncthreads();

        // dense_g MFMA (verified): D[g][m]
        f32x4 dacc[4];
#pragma unroll
        for (int j = 0; j < 4; j++) dacc[j] = {0.f, 0.f, 0.f, 0.f};
#pragma unroll
        for (int ks = 0; ks < 3; ++ks) {
            const int ko = ks * 32 + q * 8;
            f16x8 aw = *reinterpret_cast<const f16x8*>(&sWg[(w * 16 + r16) * 104 + ko]);
#pragma unroll
            for (int mt = 0; mt < 4; ++mt) {
                f16x8 bx = *reinterpret_cast<const f16x8*>(&sA2[(mt * 16 + r16) * 104 + ko]);
                dacc[mt] = __builtin_amdgcn_mfma_f32_16x16x32_f16(aw, bx, dacc[mt], 0, 0, 0);
            }
        }

        float4 b4 = *reinterpret_cast<const float4*>(&sBg[w * 16 + q * 4]);
#pragma unroll
        for (int mt = 0; mt < 4; ++mt) {
            const int mm = mt * 16 + r16;
            const size_t row = (((size_t)(b * 64 + mm) * T_ + t) * F_ + f);
            st4h(&d2[row * H_ + w * 16 + q * 4],
                 elu_(dacc[mt][0] + b4.x), elu_(dacc[mt][1] + b4.y),
                 elu_(dacc[mt][2] + b4.z), elu_(dacc[mt][3] + b4.w));
        }
        __syncthreads();   // sXT/sA2 reads done before next iteration's writes
    }
}

// ---------------- feature mix + LN + residual, 8 t per block (verified r14) ----------------
__global__ __launch_bounds__(256) void featmix_v3(const unsigned short* __restrict__ e,
                                                  const float* __restrict__ adjg,
                                                  const float* __restrict__ gamma,
                                                  const float* __restrict__ beta,
                                                  const float* __restrict__ res,
                                                  float* __restrict__ out)
{
    __shared__ __align__(16) unsigned short se[8 * 16 * 64];

    const int t0 = (blockIdx.x & 15) * 8, bn = blockIdx.x >> 4;
    const int tid = threadIdx.x;

    {
        int f = tid >> 4, c4 = (tid & 15) * 4;
#pragma unroll
        for (int tl = 0; tl < 8; ++tl)
            *reinterpret_cast<ushort4*>(&se[tl * 1024 + f * 64 + c4]) =
                *reinterpret_cast<const ushort4*>(&e[(((size_t)bn * T_ + t0 + tl) * F_ + f) * H_ + c4]);
    }
    __syncthreads();

    const int g = tid >> 4, hq = tid & 15;
    float ag[16];
#pragma unroll
    for (int f = 0; f < 16; ++f) ag[f] = adjg[g * 16 + f];
    float gm0 = gamma[hq * 4 + 0], gm1 = gamma[hq * 4 + 1], gm2 = gamma[hq * 4 + 2], gm3 = gamma[hq * 4 + 3];
    float be0 = beta[hq * 4 + 0],  be1 = beta[hq * 4 + 1],  be2 = beta[hq * 4 + 2],  be3 = beta[hq * 4 + 3];

    for (int tl = 0; tl < 8; ++tl) {
        float a0 = 0.f, a1 = 0.f, a2 = 0.f, a3 = 0.f;
#pragma unroll
        for (int f = 0; f < 16; ++f) {
            ushort4 dv = *reinterpret_cast<const ushort4*>(&se[tl * 1024 + f * 64 + hq * 4]);
            float av = ag[f];
            a0 = fmaf(av, h2f(dv.x), a0);
            a1 = fmaf(av, h2f(dv.y), a1);
            a2 = fmaf(av, h2f(dv.z), a2);
            a3 = fmaf(av, h2f(dv.w), a3);
        }
        float s  = a0 + a1 + a2 + a3;
        float qv = a0*a0 + a1*a1 + a2*a2 + a3*a3;
#pragma unroll
        for (int m = 1; m < 16; m <<= 1) { s += __shfl_xor(s, m, 64); qv += __shfl_xor(qv, m, 64); }
        float mean = s * (1.f / 64.f);
        float var  = qv * (1.f / 64.f) - mean * mean;
        float rstd = rsqrtf(var + 1e-5f);

        const size_t o = (((size_t)bn * T_ + t0 + tl) * F_ + g) * H_ + hq * 4;
        float4 rv = *reinterpret_cast<const float4*>(res + o);
        float4 ov;
        ov.x = (a0 - mean) * rstd * gm0 + be0 + rv.x;
        ov.y = (a1 - mean) * rstd * gm1 + be1 + rv.y;
        ov.z = (a2 - mean) * rstd * gm2 + be2 + rv.z;
        ov.w = (a3 - mean) * rstd * gm3 + be3 + rv.w;
        *reinterpret_cast<float4*>(out + o) = ov;
    }
}

extern "C" void kernel_launch(void* const* d_in, const int* in_sizes, int n_in,
                              void* d_out, int out_size, void* d_ws, size_t ws_size,
                              hipStream_t stream)
{
    const float* h_in    = (const float*)d_in[0];
    const float* embs_G  = (const float*)d_in[2];
    const float* embs_g  = (const float*)d_in[3];
    const float* adj_G   = (const float*)d_in[4];
    const float* adj_g   = (const float*)d_in[5];
    const float* Wt0 = (const float*)d_in[6];  const float* bt0 = (const float*)d_in[7];
    const float* Wt1 = (const float*)d_in[8];  const float* bt1 = (const float*)d_in[9];
    const float* Wt2 = (const float*)d_in[10]; const float* bt2 = (const float*)d_in[11];
    const float* gamma_t = (const float*)d_in[12]; const float* beta_t = (const float*)d_in[13];
    const float* W_G = (const float*)d_in[14]; const float* b_G = (const float*)d_in[15];
    const float* gamma_G = (const float*)d_in[16]; const float* beta_G = (const float*)d_in[17];
    const float* W_g = (const float*)d_in[18]; const float* b_g = (const float*)d_in[19];
    const float* gamma_g = (const float*)d_in[20]; const float* beta_g = (const float*)d_in[21];

    float* out = (float*)d_out;
    char*  ws  = (char*)d_ws;
    unsigned short* d1 = (unsigned short*)ws;                          // 64 MiB
    unsigned short* d2 = (unsigned short*)(ws + ((size_t)64 << 20));   // 64 MiB

    unsigned short* prep = (unsigned short*)(ws + ((size_t)192 << 20));
    unsigned short* pw   = prep;                 // 3*16*64*192
    unsigned short* pWG  = prep + 589824;
    unsigned short* pWg  = pWG + 6656;
    unsigned short* padj = pWg + 6656;

    prep_w<<<48, 256, 0, stream>>>(Wt0, Wt1, Wt2, pw);
    prep_small<<<1, 256, 0, stream>>>(adj_G, W_G, W_g, padj, pWG, pWg);

    conv_chain<<<4096, 256, 0, stream>>>(h_in, pw, bt0, bt1, bt2, gamma_t, beta_t,
                                         embs_G, pWG, b_G, d1);
    nodemix_dense2<<<2048, 256, 0, stream>>>(d1, padj, gamma_G, beta_G,
                                             embs_g, pWg, b_g, d2);
    featmix_v3<<<4096, 256, 0, stream>>>(d2, adj_g, gamma_g, beta_g, h_in, out);
}

// Round 16
// 244.747 us; speedup vs baseline: 5.0725x; 1.0478x over previous
//
#include <hip/hip_runtime.h>

#define BN_ 256
#define T_  128
#define F_  16
#define H_  64

using f16x8   = __attribute__((ext_vector_type(8))) _Float16;
using f32x4   = __attribute__((ext_vector_type(4))) float;
using ushort8 = __attribute__((ext_vector_type(8))) unsigned short;

__device__ __forceinline__ float elu_(float x) { return x > 0.f ? x : __expf(x) - 1.f; }
__device__ __forceinline__ unsigned short f2h(float x) {
    union { _Float16 h; unsigned short u; } v; v.h = (_Float16)x; return v.u;
}
__device__ __forceinline__ float h2f(unsigned short u) {
    union { unsigned short u; _Float16 h; } v; v.u = u; return (float)v.h;
}
__device__ __forceinline__ unsigned pk2(float a, float b) {
    auto h = __builtin_amdgcn_cvt_pkrtz(a, b);
    unsigned u; __builtin_memcpy(&u, &h, 4); return u;
}
__device__ __forceinline__ void st4h(unsigned short* p, float a, float b, float c, float d) {
    uint2 v; v.x = pk2(a, b); v.y = pk2(c, d);
    *reinterpret_cast<uint2*>(p) = v;
}

// ---------------- prep: conv weights -> fp16 transposed [l][f][g][192] ----------------
__global__ __launch_bounds__(256) void prep_w(const float* __restrict__ Wt0,
                                              const float* __restrict__ Wt1,
                                              const float* __restrict__ Wt2,
                                              unsigned short* __restrict__ pw)
{
    __shared__ unsigned short sW[64 * 200];
    const int lf = blockIdx.x, l = lf >> 4, f = lf & 15;
    const float* W = (l == 0) ? Wt0 : ((l == 1) ? Wt1 : Wt2);
    const int tid = threadIdx.x;

    for (int idx = tid; idx < 3 * 4096; idx += 256) {
        int tap = idx >> 12, rem = idx & 4095;
        int h = rem >> 6, g = rem & 63;
        sW[g * 200 + tap * 64 + h] = f2h(W[(size_t)(tap * 16 + f) * 4096 + rem]);
    }
    __syncthreads();
    for (int idx = tid; idx < 64 * 24; idx += 256) {
        int g = idx / 24, k8 = idx - g * 24;
        *reinterpret_cast<ushort8*>(&pw[((size_t)lf * 64 + g) * 192 + k8 * 8]) =
            *reinterpret_cast<const ushort8*>(&sW[g * 200 + k8 * 8]);
    }
}

// ---------------- prep: adjG [64][72], W_G [64][104], W_g [64][104] ----------------
__global__ __launch_bounds__(256) void prep_small(const float* __restrict__ adjG,
                                                  const float* __restrict__ W_G,
                                                  const float* __restrict__ W_g,
                                                  unsigned short* __restrict__ padj,
                                                  unsigned short* __restrict__ pWG,
                                                  unsigned short* __restrict__ pWg)
{
    const int tid = threadIdx.x;
    for (int idx = tid; idx < 4608; idx += 256) {
        int m = idx / 72, n = idx - m * 72;
        padj[idx] = (n < 64) ? f2h(adjG[m * 64 + n]) : (unsigned short)0;
    }
    for (int idx = tid; idx < 6656; idx += 256) {
        int g = idx / 104, k = idx - g * 104;
        pWG[idx] = (k < 80) ? f2h(W_G[k * 64 + g]) : (unsigned short)0;
    }
    for (int idx = tid; idx < 6656; idx += 256) {
        int g = idx / 104, k = idx - g * 104;
        pWg[idx] = (k < 72) ? f2h(W_g[k * 64 + g]) : (unsigned short)0;
    }
}

// ---------------- fused: tconv x3 (+LN_t) + dense_G per (bn,f); 8 waves, 16-row strips ----------------
__global__ __launch_bounds__(512) void conv_chain(const float* __restrict__ in,
                                                  const unsigned short* __restrict__ pw,
                                                  const float* __restrict__ bt0,
                                                  const float* __restrict__ bt1,
                                                  const float* __restrict__ bt2,
                                                  const float* __restrict__ gamma,
                                                  const float* __restrict__ beta,
                                                  const float* __restrict__ embs_G,
                                                  const unsigned short* __restrict__ pWG,
                                                  const float* __restrict__ b_G,
                                                  unsigned short* __restrict__ d1)
{
    __shared__ __align__(16) char smem[46720];
    unsigned short* tile = (unsigned short*)smem;             // [136][72]
    unsigned short* sW   = (unsigned short*)(smem + 19584);   // [64][200]
    float*          sCst = (float*)(smem + 45184);            // [6][64]
    unsigned short* sA1  = (unsigned short*)smem;             // [128][104] overlay
    unsigned short* sWG  = (unsigned short*)(smem + 26624);   // [64][104] overlay

    const int f   = blockIdx.x & 15;
    const int bn  = blockIdx.x >> 4;
    const int tid = threadIdx.x;
    const int lane = tid & 63, w = tid >> 6;   // w = 0..7
    const int r16 = lane & 15, q = lane >> 4;

    // prefetch embs_G: one float4 per thread (512 x 4 = 2048)
    const int et = tid >> 2, ee = (tid & 3) * 4;
    float4 ereg = *reinterpret_cast<const float4*>(
        embs_G + ((((size_t)bn * T_ + et) * F_ + f) * 16 + ee));

    if (tid < 64) {
        sCst[0 * 64 + tid] = bt0[f * 64 + tid];
        sCst[1 * 64 + tid] = bt1[f * 64 + tid];
        sCst[2 * 64 + tid] = bt2[f * 64 + tid];
        sCst[3 * 64 + tid] = gamma[tid];
        sCst[4 * 64 + tid] = beta[tid];
        sCst[5 * 64 + tid] = b_G[tid];
    }
    for (int idx = tid; idx < 136 * 16; idx += 512) {
        int r = idx >> 4, h4 = (idx & 15) * 4;
        int t = r - 4;
        if (t >= 0 && t < T_) {
            float4 x = *reinterpret_cast<const float4*>(in + (((size_t)bn * T_ + t) * F_ + f) * H_ + h4);
            st4h(&tile[r * 72 + h4], x.x, x.y, x.z, x.w);
        } else {
            uint2 z = {0, 0};
            *reinterpret_cast<uint2*>(&tile[r * 72 + h4]) = z;
        }
    }
    {
        const unsigned short* wsrc = pw + (size_t)f * 64 * 192;
        for (int idx = tid; idx < 1536; idx += 512) {
            int g = idx / 24, k8 = idx - g * 24;
            *reinterpret_cast<ushort8*>(&sW[g * 200 + k8 * 8]) =
                *reinterpret_cast<const ushort8*>(&wsrc[g * 192 + k8 * 8]);
        }
    }
    __syncthreads();

    float vv[4][4];   // [gt][reg] : lane owns row t = w*16+r16, g = gt*16+q*4+reg

#pragma unroll
    for (int l = 0; l < 3; ++l) {
        const int dil = 1 << l;

        // prefetch next weights into regs (hidden under this layer's MFMA)
        ushort8 wreg[3];
        if (l < 2) {
            const unsigned short* wsrc = pw + ((size_t)((l + 1) * 16 + f) * 64) * 192;
#pragma unroll
            for (int j = 0; j < 3; ++j) {
                int idx = j * 512 + tid, g = idx / 24, k8 = idx - g * 24;
                wreg[j] = *reinterpret_cast<const ushort8*>(&wsrc[g * 192 + k8 * 8]);
            }
        }
        ushort8 wgreg[2];
        if (l == 2) {
#pragma unroll
            for (int j = 0; j < 2; ++j) {
                int idx = j * 512 + tid;
                if (idx < 832) wgreg[j] = reinterpret_cast<const ushort8*>(pWG)[idx];
            }
        }

        f32x4 acc[4];
#pragma unroll
        for (int j = 0; j < 4; j++) acc[j] = {0.f, 0.f, 0.f, 0.f};

#pragma unroll
        for (int tap = 0; tap < 3; ++tap) {
            const int row0 = w * 16 + r16 + 4 + (tap - 1) * dil;
#pragma unroll
            for (int ks = 0; ks < 2; ++ks) {
                const int ko = ks * 32 + q * 8;
                f16x8 a0 = *reinterpret_cast<const f16x8*>(&tile[row0 * 72 + ko]);
                const int kb = tap * 64 + ko;
                f16x8 b0 = *reinterpret_cast<const f16x8*>(&sW[(r16     ) * 200 + kb]);
                f16x8 b1 = *reinterpret_cast<const f16x8*>(&sW[(r16 + 16) * 200 + kb]);
                f16x8 b2 = *reinterpret_cast<const f16x8*>(&sW[(r16 + 32) * 200 + kb]);
                f16x8 b3 = *reinterpret_cast<const f16x8*>(&sW[(r16 + 48) * 200 + kb]);
                acc[0] = __builtin_amdgcn_mfma_f32_16x16x32_f16(b0, a0, acc[0], 0, 0, 0);
                acc[1] = __builtin_amdgcn_mfma_f32_16x16x32_f16(b1, a0, acc[1], 0, 0, 0);
                acc[2] = __builtin_amdgcn_mfma_f32_16x16x32_f16(b2, a0, acc[2], 0, 0, 0);
                acc[3] = __builtin_amdgcn_mfma_f32_16x16x32_f16(b3, a0, acc[3], 0, 0, 0);
            }
        }

        // epilogue: bias + ELU (+ LN on layer 2), lane owns full row t
#pragma unroll
        for (int gt = 0; gt < 4; ++gt) {
            float4 b4 = *reinterpret_cast<const float4*>(&sCst[l * 64 + gt * 16 + q * 4]);
#pragma unroll
            for (int r = 0; r < 4; ++r) vv[gt][r] = elu_(acc[gt][r] + ((const float*)&b4)[r]);
        }
        if (l == 2) {
            float s = 0.f, qq = 0.f;
#pragma unroll
            for (int gt = 0; gt < 4; ++gt)
#pragma unroll
                for (int r = 0; r < 4; ++r) { float v = vv[gt][r]; s += v; qq += v * v; }
            s += __shfl_xor(s, 16, 64); qq += __shfl_xor(qq, 16, 64);
            s += __shfl_xor(s, 32, 64); qq += __shfl_xor(qq, 32, 64);
            float mean = s * (1.f / 64.f);
            float var  = qq * (1.f / 64.f) - mean * mean;
            float rstd = rsqrtf(var + 1e-5f);
#pragma unroll
            for (int gt = 0; gt < 4; ++gt) {
                float4 g4 = *reinterpret_cast<const float4*>(&sCst[3 * 64 + gt * 16 + q * 4]);
                float4 be4 = *reinterpret_cast<const float4*>(&sCst[4 * 64 + gt * 16 + q * 4]);
#pragma unroll
                for (int r = 0; r < 4; ++r)
                    vv[gt][r] = (vv[gt][r] - mean) * rstd * ((const float*)&g4)[r] + ((const float*)&be4)[r];
            }
        }
        __syncthreads();   // all tile/sW reads of this layer complete

        if (l < 2) {
            const int t = w * 16 + r16;
#pragma unroll
            for (int gt = 0; gt < 4; ++gt)
                st4h(&tile[(t + 4) * 72 + gt * 16 + q * 4],
                     vv[gt][0], vv[gt][1], vv[gt][2], vv[gt][3]);
#pragma unroll
            for (int j = 0; j < 3; ++j) {
                int idx = j * 512 + tid, g = idx / 24, k8 = idx - g * 24;
                *reinterpret_cast<ushort8*>(&sW[g * 200 + k8 * 8]) = wreg[j];
            }
            __syncthreads();
        } else {
            const int t = w * 16 + r16;
#pragma unroll
            for (int gt = 0; gt < 4; ++gt)
                st4h(&sA1[t * 104 + gt * 16 + q * 4],
                     vv[gt][0], vv[gt][1], vv[gt][2], vv[gt][3]);
            st4h(&sA1[et * 104 + 64 + ee], ereg.x, ereg.y, ereg.z, ereg.w);
            if (tid < 256) {   // zero cols 80..95
                int r = tid >> 1, half = tid & 1;
                ushort8 z = {0,0,0,0,0,0,0,0};
                *reinterpret_cast<ushort8*>(&sA1[r * 104 + 80 + half * 8]) = z;
            }
#pragma unroll
            for (int j = 0; j < 2; ++j) {
                int idx = j * 512 + tid;
                if (idx < 832) reinterpret_cast<ushort8*>(sWG)[idx] = wgreg[j];
            }
            __syncthreads();
        }
    }

    // dense MFMA (swapped): D[g][t], lane owns row t = w*16+r16
    f32x4 dacc[4];
#pragma unroll
    for (int j = 0; j < 4; j++) dacc[j] = {0.f, 0.f, 0.f, 0.f};

#pragma unroll
    for (int ks = 0; ks < 3; ++ks) {
        const int ko = ks * 32 + q * 8;
        f16x8 a0 = *reinterpret_cast<const f16x8*>(&sA1[(w * 16 + r16) * 104 + ko]);
#pragma unroll
        for (int gt = 0; gt < 4; ++gt) {
            f16x8 bb = *reinterpret_cast<const f16x8*>(&sWG[(gt * 16 + r16) * 104 + ko]);
            dacc[gt] = __builtin_amdgcn_mfma_f32_16x16x32_f16(bb, a0, dacc[gt], 0, 0, 0);
        }
    }

    {
        const int t = w * 16 + r16;
        const size_t ob = (((size_t)bn * T_ + t) * F_ + f) * H_;
#pragma unroll
        for (int gt = 0; gt < 4; ++gt) {
            float4 b4 = *reinterpret_cast<const float4*>(&sCst[5 * 64 + gt * 16 + q * 4]);
            st4h(&d1[ob + gt * 16 + q * 4],
                 elu_(dacc[gt][0] + ((const float*)&b4)[0]),
                 elu_(dacc[gt][1] + ((const float*)&b4)[1]),
                 elu_(dacc[gt][2] + ((const float*)&b4)[2]),
                 elu_(dacc[gt][3] + ((const float*)&b4)[3]));
        }
    }
}

// ---------------- fused: node mix + LN_G + dense_g, 4 t per block, reg-prefetched (verified r15) ----------------
__global__ __launch_bounds__(256) void nodemix_dense2(const unsigned short* __restrict__ d1,
                                                      const unsigned short* __restrict__ padj,
                                                      const float* __restrict__ gamma,
                                                      const float* __restrict__ beta,
                                                      const float* __restrict__ embs_g,
                                                      const unsigned short* __restrict__ pWg,
                                                      const float* __restrict__ b_g,
                                                      unsigned short* __restrict__ d2)
{
    __shared__ __align__(16) char smem[47872];
    unsigned short* sAdj = (unsigned short*)smem;            // [64][72]
    unsigned short* sXT  = (unsigned short*)(smem + 9216);   // [64][88]
    unsigned short* sA2  = (unsigned short*)(smem + 20480);  // [64][104]
    unsigned short* sWg  = (unsigned short*)(smem + 33792);  // [64][104]
    float*          sBg  = (float*)(smem + 47104);           // [64]
    float*          sGB  = (float*)(smem + 47360);           // [128] gamma|beta

    const int f  = blockIdx.x & 15;
    const int tq = (blockIdx.x >> 4) & 31;
    const int b  = blockIdx.x >> 9;
    const int t0 = tq * 4;
    const int tid = threadIdx.x, lane = tid & 63, w = tid >> 6;
    const int r16 = lane & 15, q = lane >> 4;

    if (tid < 64) sBg[tid] = b_g[tid];
    if (tid >= 64 && tid < 128) sGB[tid - 64] = gamma[tid - 64];
    if (tid >= 128 && tid < 192) sGB[tid - 64] = beta[tid - 128];
    for (int idx = tid; idx < 576; idx += 256)
        reinterpret_cast<ushort8*>(sAdj)[idx] = reinterpret_cast<const ushort8*>(padj)[idx];
    for (int idx = tid; idx < 832; idx += 256)
        reinterpret_cast<ushort8*>(sWg)[idx] = reinterpret_cast<const ushort8*>(pWg)[idx];
    for (int idx = tid; idx < 192; idx += 256) {
        int m = idx / 3, k8 = idx - m * 3;
        ushort8 z = {0,0,0,0,0,0,0,0};
        *reinterpret_cast<ushort8*>(&sA2[m * 104 + 72 + k8 * 8]) = z;
    }

    const int n = lane;
    const int em = tid >> 2, ec = (tid & 3) * 2;
    ushort8 xr0, xr1;
    float2  er;
    {
        const size_t base = (((size_t)(b * 64 + n) * T_ + t0) * F_ + f) * H_;
        xr0 = *reinterpret_cast<const ushort8*>(&d1[base + (w    ) * 8]);
        xr1 = *reinterpret_cast<const ushort8*>(&d1[base + (w + 4) * 8]);
        er  = *reinterpret_cast<const float2*>(&embs_g[((((size_t)(b * 64 + em)) * T_ + t0) * F_ + f) * 8 + ec]);
    }

    for (int tt = 0; tt < 4; ++tt) {
        const int t = t0 + tt;

        {
            int c0 = w, c1 = w + 4;
#pragma unroll
            for (int i = 0; i < 8; ++i) sXT[(c0 * 8 + i) * 88 + n] = xr0[i];
#pragma unroll
            for (int i = 0; i < 8; ++i) sXT[(c1 * 8 + i) * 88 + n] = xr1[i];
            *reinterpret_cast<unsigned*>(&sA2[em * 104 + 64 + ec]) = pk2(er.x, er.y);
        }
        if (tt < 3) {
            const size_t base = (((size_t)(b * 64 + n) * T_ + t + 1) * F_ + f) * H_;
            xr0 = *reinterpret_cast<const ushort8*>(&d1[base + (w    ) * 8]);
            xr1 = *reinterpret_cast<const ushort8*>(&d1[base + (w + 4) * 8]);
            er  = *reinterpret_cast<const float2*>(&embs_g[((((size_t)(b * 64 + em)) * T_ + t + 1) * F_ + f) * 8 + ec]);
        }
        __syncthreads();

        f32x4 acc[4];
#pragma unroll
        for (int j = 0; j < 4; j++) acc[j] = {0.f, 0.f, 0.f, 0.f};
#pragma unroll
        for (int ks = 0; ks < 2; ++ks) {
            f16x8 af = *reinterpret_cast<const f16x8*>(&sAdj[(w * 16 + r16) * 72 + ks * 32 + q * 8]);
#pragma unroll
            for (int ht = 0; ht < 4; ++ht) {
                f16x8 xf = *reinterpret_cast<const f16x8*>(&sXT[(ht * 16 + r16) * 88 + ks * 32 + q * 8]);
                acc[ht] = __builtin_amdgcn_mfma_f32_16x16x32_f16(xf, af, acc[ht], 0, 0, 0);
            }
        }

        const int m = w * 16 + r16;
        float s = 0.f, qq = 0.f;
#pragma unroll
        for (int ht = 0; ht < 4; ++ht)
#pragma unroll
            for (int r = 0; r < 4; ++r) { float v = acc[ht][r]; s += v; qq += v * v; }
        s += __shfl_xor(s, 16, 64); qq += __shfl_xor(qq, 16, 64);
        s += __shfl_xor(s, 32, 64); qq += __shfl_xor(qq, 32, 64);
        float mean = s * (1.f / 64.f);
        float var  = qq * (1.f / 64.f) - mean * mean;
        float rstd = rsqrtf(var + 1e-5f);

#pragma unroll
        for (int ht = 0; ht < 4; ++ht) {
            float4 g4  = *reinterpret_cast<const float4*>(&sGB[ht * 16 + q * 4]);
            float4 be4 = *reinterpret_cast<const float4*>(&sGB[64 + ht * 16 + q * 4]);
            st4h(&sA2[m * 104 + ht * 16 + q * 4],
                 (acc[ht][0] - mean) * rstd * ((const float*)&g4)[0] + ((const float*)&be4)[0],
                 (acc[ht][1] - mean) * rstd * ((const float*)&g4)[1] + ((const float*)&be4)[1],
                 (acc[ht][2] - mean) * rstd * ((const float*)&g4)[2] + ((const float*)&be4)[2],
                 (acc[ht][3] - mean) * rstd * ((const float*)&g4)[3] + ((const float*)&be4)[3]);
        }
        __syncthreads();

        f32x4 dacc[4];
#pragma unroll
        for (int j = 0; j < 4; j++) dacc[j] = {0.f, 0.f, 0.f, 0.f};
#pragma unroll
        for (int ks = 0; ks < 3; ++ks) {
            const int ko = ks * 32 + q * 8;
            f16x8 aw = *reinterpret_cast<const f16x8*>(&sWg[(w * 16 + r16) * 104 + ko]);
#pragma unroll
            for (int mt = 0; mt < 4; ++mt) {
                f16x8 bx = *reinterpret_cast<const f16x8*>(&sA2[(mt * 16 + r16) * 104 + ko]);
                dacc[mt] = __builtin_amdgcn_mfma_f32_16x16x32_f16(aw, bx, dacc[mt], 0, 0, 0);
            }
        }

        float4 b4 = *reinterpret_cast<const float4*>(&sBg[w * 16 + q * 4]);
#pragma unroll
        for (int mt = 0; mt < 4; ++mt) {
            const int mm = mt * 16 + r16;
            const size_t row = (((size_t)(b * 64 + mm) * T_ + t) * F_ + f);
            st4h(&d2[row * H_ + w * 16 + q * 4],
                 elu_(dacc[mt][0] + b4.x), elu_(dacc[mt][1] + b4.y),
                 elu_(dacc[mt][2] + b4.z), elu_(dacc[mt][3] + b4.w));
        }
        __syncthreads();
    }
}

// ---------------- feature mix + LN + residual, 8 t per block (verified r14/r15) ----------------
__global__ __launch_bounds__(256) void featmix_v3(const unsigned short* __restrict__ e,
                                                  const float* __restrict__ adjg,
                                                  const float* __restrict__ gamma,
                                                  const float* __restrict__ beta,
                                                  const float* __restrict__ res,
                                                  float* __restrict__ out)
{
    __shared__ __align__(16) unsigned short se[8 * 16 * 64];

    const int t0 = (blockIdx.x & 15) * 8, bn = blockIdx.x >> 4;
    const int tid = threadIdx.x;

    {
        int f = tid >> 4, c4 = (tid & 15) * 4;
#pragma unroll
        for (int tl = 0; tl < 8; ++tl)
            *reinterpret_cast<ushort4*>(&se[tl * 1024 + f * 64 + c4]) =
                *reinterpret_cast<const ushort4*>(&e[(((size_t)bn * T_ + t0 + tl) * F_ + f) * H_ + c4]);
    }
    __syncthreads();

    const int g = tid >> 4, hq = tid & 15;
    float ag[16];
#pragma unroll
    for (int f = 0; f < 16; ++f) ag[f] = adjg[g * 16 + f];
    float gm0 = gamma[hq * 4 + 0], gm1 = gamma[hq * 4 + 1], gm2 = gamma[hq * 4 + 2], gm3 = gamma[hq * 4 + 3];
    float be0 = beta[hq * 4 + 0],  be1 = beta[hq * 4 + 1],  be2 = beta[hq * 4 + 2],  be3 = beta[hq * 4 + 3];

    for (int tl = 0; tl < 8; ++tl) {
        float a0 = 0.f, a1 = 0.f, a2 = 0.f, a3 = 0.f;
#pragma unroll
        for (int f = 0; f < 16; ++f) {
            ushort4 dv = *reinterpret_cast<const ushort4*>(&se[tl * 1024 + f * 64 + hq * 4]);
            float av = ag[f];
            a0 = fmaf(av, h2f(dv.x), a0);
            a1 = fmaf(av, h2f(dv.y), a1);
            a2 = fmaf(av, h2f(dv.z), a2);
            a3 = fmaf(av, h2f(dv.w), a3);
        }
        float s  = a0 + a1 + a2 + a3;
        float qv = a0*a0 + a1*a1 + a2*a2 + a3*a3;
#pragma unroll
        for (int m = 1; m < 16; m <<= 1) { s += __shfl_xor(s, m, 64); qv += __shfl_xor(qv, m, 64); }
        float mean = s * (1.f / 64.f);
        float var  = qv * (1.f / 64.f) - mean * mean;
        float rstd = rsqrtf(var + 1e-5f);

        const size_t o = (((size_t)bn * T_ + t0 + tl) * F_ + g) * H_ + hq * 4;
        float4 rv = *reinterpret_cast<const float4*>(res + o);
        float4 ov;
        ov.x = (a0 - mean) * rstd * gm0 + be0 + rv.x;
        ov.y = (a1 - mean) * rstd * gm1 + be1 + rv.y;
        ov.z = (a2 - mean) * rstd * gm2 + be2 + rv.z;
        ov.w = (a3 - mean) * rstd * gm3 + be3 + rv.w;
        *reinterpret_cast<float4*>(out + o) = ov;
    }
}

extern "C" void kernel_launch(void* const* d_in, const int* in_sizes, int n_in,
                              void* d_out, int out_size, void* d_ws, size_t ws_size,
                              hipStream_t stream)
{
    const float* h_in    = (const float*)d_in[0];
    const float* embs_G  = (const float*)d_in[2];
    const float* embs_g  = (const float*)d_in[3];
    const float* adj_G   = (const float*)d_in[4];
    const float* adj_g   = (const float*)d_in[5];
    const float* Wt0 = (const float*)d_in[6];  const float* bt0 = (const float*)d_in[7];
    const float* Wt1 = (const float*)d_in[8];  const float* bt1 = (const float*)d_in[9];
    const float* Wt2 = (const float*)d_in[10]; const float* bt2 = (const float*)d_in[11];
    const float* gamma_t = (const float*)d_in[12]; const float* beta_t = (const float*)d_in[13];
    const float* W_G = (const float*)d_in[14]; const float* b_G = (const float*)d_in[15];
    const float* gamma_G = (const float*)d_in[16]; const float* beta_G = (const float*)d_in[17];
    const float* W_g = (const float*)d_in[18]; const float* b_g = (const float*)d_in[19];
    const float* gamma_g = (const float*)d_in[20]; const float* beta_g = (const float*)d_in[21];

    float* out = (float*)d_out;
    char*  ws  = (char*)d_ws;
    unsigned short* d1 = (unsigned short*)ws;                          // 64 MiB
    unsigned short* d2 = (unsigned short*)(ws + ((size_t)64 << 20));   // 64 MiB

    unsigned short* prep = (unsigned short*)(ws + ((size_t)192 << 20));
    unsigned short* pw   = prep;                 // 3*16*64*192
    unsigned short* pWG  = prep + 589824;
    unsigned short* pWg  = pWG + 6656;
    unsigned short* padj = pWg + 6656;

    prep_w<<<48, 256, 0, stream>>>(Wt0, Wt1, Wt2, pw);
    prep_small<<<1, 256, 0, stream>>>(adj_G, W_G, W_g, padj, pWG, pWg);

    conv_chain<<<4096, 512, 0, stream>>>(h_in, pw, bt0, bt1, bt2, gamma_t, beta_t,
                                         embs_G, pWG, b_G, d1);
    nodemix_dense2<<<2048, 256, 0, stream>>>(d1, padj, gamma_G, beta_G,
                                             embs_g, pWg, b_g, d2);
    featmix_v3<<<4096, 256, 0, stream>>>(d2, adj_g, gamma_g, beta_g, h_in, out);
}

// Round 17
// 244.431 us; speedup vs baseline: 5.0790x; 1.0013x over previous
//
#include <hip/hip_runtime.h>

#define BN_ 256
#define T_  128
#define F_  16
#define H_  64

using f16x8   = __attribute__((ext_vector_type(8))) _Float16;
using f32x4   = __attribute__((ext_vector_type(4))) float;
using ushort8 = __attribute__((ext_vector_type(8))) unsigned short;

__device__ __forceinline__ float elu_(float x) { return x > 0.f ? x : __expf(x) - 1.f; }
__device__ __forceinline__ unsigned short f2h(float x) {
    union { _Float16 h; unsigned short u; } v; v.h = (_Float16)x; return v.u;
}
__device__ __forceinline__ float h2f(unsigned short u) {
    union { unsigned short u; _Float16 h; } v; v.u = u; return (float)v.h;
}
__device__ __forceinline__ unsigned pk2(float a, float b) {
    auto h = __builtin_amdgcn_cvt_pkrtz(a, b);
    unsigned u; __builtin_memcpy(&u, &h, 4); return u;
}
__device__ __forceinline__ void st4h(unsigned short* p, float a, float b, float c, float d) {
    uint2 v; v.x = pk2(a, b); v.y = pk2(c, d);
    *reinterpret_cast<uint2*>(p) = v;
}

// ---------------- prep: conv weights -> fp16 transposed [l][f][g][192] ----------------
__global__ __launch_bounds__(256) void prep_w(const float* __restrict__ Wt0,
                                              const float* __restrict__ Wt1,
                                              const float* __restrict__ Wt2,
                                              unsigned short* __restrict__ pw)
{
    __shared__ unsigned short sW[64 * 200];
    const int lf = blockIdx.x, l = lf >> 4, f = lf & 15;
    const float* W = (l == 0) ? Wt0 : ((l == 1) ? Wt1 : Wt2);
    const int tid = threadIdx.x;

    for (int idx = tid; idx < 3 * 4096; idx += 256) {
        int tap = idx >> 12, rem = idx & 4095;
        int h = rem >> 6, g = rem & 63;
        sW[g * 200 + tap * 64 + h] = f2h(W[(size_t)(tap * 16 + f) * 4096 + rem]);
    }
    __syncthreads();
    for (int idx = tid; idx < 64 * 24; idx += 256) {
        int g = idx / 24, k8 = idx - g * 24;
        *reinterpret_cast<ushort8*>(&pw[((size_t)lf * 64 + g) * 192 + k8 * 8]) =
            *reinterpret_cast<const ushort8*>(&sW[g * 200 + k8 * 8]);
    }
}

// ---------------- prep: adjG [64][72], W_G [64][104], W_g [64][104] ----------------
__global__ __launch_bounds__(256) void prep_small(const float* __restrict__ adjG,
                                                  const float* __restrict__ W_G,
                                                  const float* __restrict__ W_g,
                                                  unsigned short* __restrict__ padj,
                                                  unsigned short* __restrict__ pWG,
                                                  unsigned short* __restrict__ pWg)
{
    const int tid = threadIdx.x;
    for (int idx = tid; idx < 4608; idx += 256) {
        int m = idx / 72, n = idx - m * 72;
        padj[idx] = (n < 64) ? f2h(adjG[m * 64 + n]) : (unsigned short)0;
    }
    for (int idx = tid; idx < 6656; idx += 256) {
        int g = idx / 104, k = idx - g * 104;
        pWG[idx] = (k < 80) ? f2h(W_G[k * 64 + g]) : (unsigned short)0;
    }
    for (int idx = tid; idx < 6656; idx += 256) {
        int g = idx / 104, k = idx - g * 104;
        pWg[idx] = (k < 72) ? f2h(W_g[k * 64 + g]) : (unsigned short)0;
    }
}

// ---------------- fused: tconv x3 (+LN_t) + dense_G per (bn,f); 8 waves (verified r16) ----------------
// d1 OUTPUT LAYOUT CHANGED: pages [b][t][f][n][64h], page = ((b*T+t)*F+f)*4096 + n*64
__global__ __launch_bounds__(512) void conv_chain(const float* __restrict__ in,
                                                  const unsigned short* __restrict__ pw,
                                                  const float* __restrict__ bt0,
                                                  const float* __restrict__ bt1,
                                                  const float* __restrict__ bt2,
                                                  const float* __restrict__ gamma,
                                                  const float* __restrict__ beta,
                                                  const float* __restrict__ embs_G,
                                                  const unsigned short* __restrict__ pWG,
                                                  const float* __restrict__ b_G,
                                                  unsigned short* __restrict__ d1)
{
    __shared__ __align__(16) char smem[46720];
    unsigned short* tile = (unsigned short*)smem;             // [136][72]
    unsigned short* sW   = (unsigned short*)(smem + 19584);   // [64][200]
    float*          sCst = (float*)(smem + 45184);            // [6][64]
    unsigned short* sA1  = (unsigned short*)smem;             // [128][104] overlay
    unsigned short* sWG  = (unsigned short*)(smem + 26624);   // [64][104] overlay

    const int f   = blockIdx.x & 15;
    const int bn  = blockIdx.x >> 4;
    const int tid = threadIdx.x;
    const int lane = tid & 63, w = tid >> 6;   // w = 0..7
    const int r16 = lane & 15, q = lane >> 4;

    const int et = tid >> 2, ee = (tid & 3) * 4;
    float4 ereg = *reinterpret_cast<const float4*>(
        embs_G + ((((size_t)bn * T_ + et) * F_ + f) * 16 + ee));

    if (tid < 64) {
        sCst[0 * 64 + tid] = bt0[f * 64 + tid];
        sCst[1 * 64 + tid] = bt1[f * 64 + tid];
        sCst[2 * 64 + tid] = bt2[f * 64 + tid];
        sCst[3 * 64 + tid] = gamma[tid];
        sCst[4 * 64 + tid] = beta[tid];
        sCst[5 * 64 + tid] = b_G[tid];
    }
    for (int idx = tid; idx < 136 * 16; idx += 512) {
        int r = idx >> 4, h4 = (idx & 15) * 4;
        int t = r - 4;
        if (t >= 0 && t < T_) {
            float4 x = *reinterpret_cast<const float4*>(in + (((size_t)bn * T_ + t) * F_ + f) * H_ + h4);
            st4h(&tile[r * 72 + h4], x.x, x.y, x.z, x.w);
        } else {
            uint2 z = {0, 0};
            *reinterpret_cast<uint2*>(&tile[r * 72 + h4]) = z;
        }
    }
    {
        const unsigned short* wsrc = pw + (size_t)f * 64 * 192;
        for (int idx = tid; idx < 1536; idx += 512) {
            int g = idx / 24, k8 = idx - g * 24;
            *reinterpret_cast<ushort8*>(&sW[g * 200 + k8 * 8]) =
                *reinterpret_cast<const ushort8*>(&wsrc[g * 192 + k8 * 8]);
        }
    }
    __syncthreads();

    float vv[4][4];

#pragma unroll
    for (int l = 0; l < 3; ++l) {
        const int dil = 1 << l;

        ushort8 wreg[3];
        if (l < 2) {
            const unsigned short* wsrc = pw + ((size_t)((l + 1) * 16 + f) * 64) * 192;
#pragma unroll
            for (int j = 0; j < 3; ++j) {
                int idx = j * 512 + tid, g = idx / 24, k8 = idx - g * 24;
                wreg[j] = *reinterpret_cast<const ushort8*>(&wsrc[g * 192 + k8 * 8]);
            }
        }
        ushort8 wgreg[2];
        if (l == 2) {
#pragma unroll
            for (int j = 0; j < 2; ++j) {
                int idx = j * 512 + tid;
                if (idx < 832) wgreg[j] = reinterpret_cast<const ushort8*>(pWG)[idx];
            }
        }

        f32x4 acc[4];
#pragma unroll
        for (int j = 0; j < 4; j++) acc[j] = {0.f, 0.f, 0.f, 0.f};

#pragma unroll
        for (int tap = 0; tap < 3; ++tap) {
            const int row0 = w * 16 + r16 + 4 + (tap - 1) * dil;
#pragma unroll
            for (int ks = 0; ks < 2; ++ks) {
                const int ko = ks * 32 + q * 8;
                f16x8 a0 = *reinterpret_cast<const f16x8*>(&tile[row0 * 72 + ko]);
                const int kb = tap * 64 + ko;
                f16x8 b0 = *reinterpret_cast<const f16x8*>(&sW[(r16     ) * 200 + kb]);
                f16x8 b1 = *reinterpret_cast<const f16x8*>(&sW[(r16 + 16) * 200 + kb]);
                f16x8 b2 = *reinterpret_cast<const f16x8*>(&sW[(r16 + 32) * 200 + kb]);
                f16x8 b3 = *reinterpret_cast<const f16x8*>(&sW[(r16 + 48) * 200 + kb]);
                acc[0] = __builtin_amdgcn_mfma_f32_16x16x32_f16(b0, a0, acc[0], 0, 0, 0);
                acc[1] = __builtin_amdgcn_mfma_f32_16x16x32_f16(b1, a0, acc[1], 0, 0, 0);
                acc[2] = __builtin_amdgcn_mfma_f32_16x16x32_f16(b2, a0, acc[2], 0, 0, 0);
                acc[3] = __builtin_amdgcn_mfma_f32_16x16x32_f16(b3, a0, acc[3], 0, 0, 0);
            }
        }

#pragma unroll
        for (int gt = 0; gt < 4; ++gt) {
            float4 b4 = *reinterpret_cast<const float4*>(&sCst[l * 64 + gt * 16 + q * 4]);
#pragma unroll
            for (int r = 0; r < 4; ++r) vv[gt][r] = elu_(acc[gt][r] + ((const float*)&b4)[r]);
        }
        if (l == 2) {
            float s = 0.f, qq = 0.f;
#pragma unroll
            for (int gt = 0; gt < 4; ++gt)
#pragma unroll
                for (int r = 0; r < 4; ++r) { float v = vv[gt][r]; s += v; qq += v * v; }
            s += __shfl_xor(s, 16, 64); qq += __shfl_xor(qq, 16, 64);
            s += __shfl_xor(s, 32, 64); qq += __shfl_xor(qq, 32, 64);
            float mean = s * (1.f / 64.f);
            float var  = qq * (1.f / 64.f) - mean * mean;
            float rstd = rsqrtf(var + 1e-5f);
#pragma unroll
            for (int gt = 0; gt < 4; ++gt) {
                float4 g4 = *reinterpret_cast<const float4*>(&sCst[3 * 64 + gt * 16 + q * 4]);
                float4 be4 = *reinterpret_cast<const float4*>(&sCst[4 * 64 + gt * 16 + q * 4]);
#pragma unroll
                for (int r = 0; r < 4; ++r)
                    vv[gt][r] = (vv[gt][r] - mean) * rstd * ((const float*)&g4)[r] + ((const float*)&be4)[r];
            }
        }
        __syncthreads();

        if (l < 2) {
            const int t = w * 16 + r16;
#pragma unroll
            for (int gt = 0; gt < 4; ++gt)
                st4h(&tile[(t + 4) * 72 + gt * 16 + q * 4],
                     vv[gt][0], vv[gt][1], vv[gt][2], vv[gt][3]);
#pragma unroll
            for (int j = 0; j < 3; ++j) {
                int idx = j * 512 + tid, g = idx / 24, k8 = idx - g * 24;
                *reinterpret_cast<ushort8*>(&sW[g * 200 + k8 * 8]) = wreg[j];
            }
            __syncthreads();
        } else {
            const int t = w * 16 + r16;
#pragma unroll
            for (int gt = 0; gt < 4; ++gt)
                st4h(&sA1[t * 104 + gt * 16 + q * 4],
                     vv[gt][0], vv[gt][1], vv[gt][2], vv[gt][3]);
            st4h(&sA1[et * 104 + 64 + ee], ereg.x, ereg.y, ereg.z, ereg.w);
            if (tid < 256) {
                int r = tid >> 1, half = tid & 1;
                ushort8 z = {0,0,0,0,0,0,0,0};
                *reinterpret_cast<ushort8*>(&sA1[r * 104 + 80 + half * 8]) = z;
            }
#pragma unroll
            for (int j = 0; j < 2; ++j) {
                int idx = j * 512 + tid;
                if (idx < 832) reinterpret_cast<ushort8*>(sWG)[idx] = wgreg[j];
            }
            __syncthreads();
        }
    }

    f32x4 dacc[4];
#pragma unroll
    for (int j = 0; j < 4; j++) dacc[j] = {0.f, 0.f, 0.f, 0.f};

#pragma unroll
    for (int ks = 0; ks < 3; ++ks) {
        const int ko = ks * 32 + q * 8;
        f16x8 a0 = *reinterpret_cast<const f16x8*>(&sA1[(w * 16 + r16) * 104 + ko]);
#pragma unroll
        for (int gt = 0; gt < 4; ++gt) {
            f16x8 bb = *reinterpret_cast<const f16x8*>(&sWG[(gt * 16 + r16) * 104 + ko]);
            dacc[gt] = __builtin_amdgcn_mfma_f32_16x16x32_f16(bb, a0, dacc[gt], 0, 0, 0);
        }
    }

    {
        const int t = w * 16 + r16;
        const int b = bn >> 6, n = bn & 63;
        // transposed page layout: [b][t][f][n][64]
        const size_t ob = ((((size_t)b * T_ + t) * F_ + f) << 12) + (size_t)n * 64;
#pragma unroll
        for (int gt = 0; gt < 4; ++gt) {
            float4 b4 = *reinterpret_cast<const float4*>(&sCst[5 * 64 + gt * 16 + q * 4]);
            st4h(&d1[ob + gt * 16 + q * 4],
                 elu_(dacc[gt][0] + ((const float*)&b4)[0]),
                 elu_(dacc[gt][1] + ((const float*)&b4)[1]),
                 elu_(dacc[gt][2] + ((const float*)&b4)[2]),
                 elu_(dacc[gt][3] + ((const float*)&b4)[3]));
        }
    }
}

// ---------------- fused: node mix + LN_G + dense_g, 4 t per block, coalesced d1 pages ----------------
__global__ __launch_bounds__(256) void nodemix_dense2(const unsigned short* __restrict__ d1,
                                                      const unsigned short* __restrict__ padj,
                                                      const float* __restrict__ gamma,
                                                      const float* __restrict__ beta,
                                                      const float* __restrict__ embs_g,
                                                      const unsigned short* __restrict__ pWg,
                                                      const float* __restrict__ b_g,
                                                      unsigned short* __restrict__ d2)
{
    __shared__ __align__(16) char smem[47872];
    unsigned short* sAdj = (unsigned short*)smem;            // [64][72]
    unsigned short* sXT  = (unsigned short*)(smem + 9216);   // [64][88]
    unsigned short* sA2  = (unsigned short*)(smem + 20480);  // [64][104]
    unsigned short* sWg  = (unsigned short*)(smem + 33792);  // [64][104]
    float*          sBg  = (float*)(smem + 47104);           // [64]
    float*          sGB  = (float*)(smem + 47360);           // [128] gamma|beta

    const int f  = blockIdx.x & 15;
    const int tq = (blockIdx.x >> 4) & 31;
    const int b  = blockIdx.x >> 9;
    const int t0 = tq * 4;
    const int tid = threadIdx.x, lane = tid & 63, w = tid >> 6;
    const int r16 = lane & 15, q = lane >> 4;

    if (tid < 64) sBg[tid] = b_g[tid];
    if (tid >= 64 && tid < 128) sGB[tid - 64] = gamma[tid - 64];
    if (tid >= 128 && tid < 192) sGB[tid - 64] = beta[tid - 128];
    for (int idx = tid; idx < 576; idx += 256)
        reinterpret_cast<ushort8*>(sAdj)[idx] = reinterpret_cast<const ushort8*>(padj)[idx];
    for (int idx = tid; idx < 832; idx += 256)
        reinterpret_cast<ushort8*>(sWg)[idx] = reinterpret_cast<const ushort8*>(pWg)[idx];
    for (int idx = tid; idx < 192; idx += 256) {
        int m = idx / 3, k8 = idx - m * 3;
        ushort8 z = {0,0,0,0,0,0,0,0};
        *reinterpret_cast<ushort8*>(&sA2[m * 104 + 72 + k8 * 8]) = z;
    }

    // coalesced page reads: thread owns (n = tid>>2, h = (tid&3)*16 .. +15)
    const int pn = tid >> 2, ph = (tid & 3) * 16;
    const int em = tid >> 2, ec = (tid & 3) * 2;
    ushort8 xr0, xr1;
    float2  er;
    {
        const unsigned short* pg = d1 + (((((size_t)b * T_ + t0) * F_) + f) << 12);
        xr0 = *reinterpret_cast<const ushort8*>(&pg[pn * 64 + ph]);
        xr1 = *reinterpret_cast<const ushort8*>(&pg[pn * 64 + ph + 8]);
        er  = *reinterpret_cast<const float2*>(&embs_g[((((size_t)(b * 64 + em)) * T_ + t0) * F_ + f) * 8 + ec]);
    }

    for (int tt = 0; tt < 4; ++tt) {
        const int t = t0 + tt;

        {   // transpose into sXT[h][n]
#pragma unroll
            for (int i = 0; i < 8; ++i) sXT[(ph + i) * 88 + pn] = xr0[i];
#pragma unroll
            for (int i = 0; i < 8; ++i) sXT[(ph + 8 + i) * 88 + pn] = xr1[i];
            *reinterpret_cast<unsigned*>(&sA2[em * 104 + 64 + ec]) = pk2(er.x, er.y);
        }
        if (tt < 3) {
            const unsigned short* pg = d1 + (((((size_t)b * T_ + t + 1) * F_) + f) << 12);
            xr0 = *reinterpret_cast<const ushort8*>(&pg[pn * 64 + ph]);
            xr1 = *reinterpret_cast<const ushort8*>(&pg[pn * 64 + ph + 8]);
            er  = *reinterpret_cast<const float2*>(&embs_g[((((size_t)(b * 64 + em)) * T_ + t + 1) * F_ + f) * 8 + ec]);
        }
        __syncthreads();

        f32x4 acc[4];
#pragma unroll
        for (int j = 0; j < 4; j++) acc[j] = {0.f, 0.f, 0.f, 0.f};
#pragma unroll
        for (int ks = 0; ks < 2; ++ks) {
            f16x8 af = *reinterpret_cast<const f16x8*>(&sAdj[(w * 16 + r16) * 72 + ks * 32 + q * 8]);
#pragma unroll
            for (int ht = 0; ht < 4; ++ht) {
                f16x8 xf = *reinterpret_cast<const f16x8*>(&sXT[(ht * 16 + r16) * 88 + ks * 32 + q * 8]);
                acc[ht] = __builtin_amdgcn_mfma_f32_16x16x32_f16(xf, af, acc[ht], 0, 0, 0);
            }
        }

        const int m = w * 16 + r16;
        float s = 0.f, qq = 0.f;
#pragma unroll
        for (int ht = 0; ht < 4; ++ht)
#pragma unroll
            for (int r = 0; r < 4; ++r) { float v = acc[ht][r]; s += v; qq += v * v; }
        s += __shfl_xor(s, 16, 64); qq += __shfl_xor(qq, 16, 64);
        s += __shfl_xor(s, 32, 64); qq += __shfl_xor(qq, 32, 64);
        float mean = s * (1.f / 64.f);
        float var  = qq * (1.f / 64.f) - mean * mean;
        float rstd = rsqrtf(var + 1e-5f);

#pragma unroll
        for (int ht = 0; ht < 4; ++ht) {
            float4 g4  = *reinterpret_cast<const float4*>(&sGB[ht * 16 + q * 4]);
            float4 be4 = *reinterpret_cast<const float4*>(&sGB[64 + ht * 16 + q * 4]);
            st4h(&sA2[m * 104 + ht * 16 + q * 4],
                 (acc[ht][0] - mean) * rstd * ((const float*)&g4)[0] + ((const float*)&be4)[0],
                 (acc[ht][1] - mean) * rstd * ((const float*)&g4)[1] + ((const float*)&be4)[1],
                 (acc[ht][2] - mean) * rstd * ((const float*)&g4)[2] + ((const float*)&be4)[2],
                 (acc[ht][3] - mean) * rstd * ((const float*)&g4)[3] + ((const float*)&be4)[3]);
        }
        __syncthreads();

        f32x4 dacc[4];
#pragma unroll
        for (int j = 0; j < 4; j++) dacc[j] = {0.f, 0.f, 0.f, 0.f};
#pragma unroll
        for (int ks = 0; ks < 3; ++ks) {
            const int ko = ks * 32 + q * 8;
            f16x8 aw = *reinterpret_cast<const f16x8*>(&sWg[(w * 16 + r16) * 104 + ko]);
#pragma unroll
            for (int mt = 0; mt < 4; ++mt) {
                f16x8 bx = *reinterpret_cast<const f16x8*>(&sA2[(mt * 16 + r16) * 104 + ko]);
                dacc[mt] = __builtin_amdgcn_mfma_f32_16x16x32_f16(aw, bx, dacc[mt], 0, 0, 0);
            }
        }

        float4 b4 = *reinterpret_cast<const float4*>(&sBg[w * 16 + q * 4]);
#pragma unroll
        for (int mt = 0; mt < 4; ++mt) {
            const int mm = mt * 16 + r16;
            const size_t row = (((size_t)(b * 64 + mm) * T_ + t) * F_ + f);
            st4h(&d2[row * H_ + w * 16 + q * 4],
                 elu_(dacc[mt][0] + b4.x), elu_(dacc[mt][1] + b4.y),
                 elu_(dacc[mt][2] + b4.z), elu_(dacc[mt][3] + b4.w));
        }
        __syncthreads();
    }
}

// ---------------- feature mix + LN + residual, 8 t per block (verified r14-r16) ----------------
__global__ __launch_bounds__(256) void featmix_v3(const unsigned short* __restrict__ e,
                                                  const float* __restrict__ adjg,
                                                  const float* __restrict__ gamma,
                                                  const float* __restrict__ beta,
                                                  const float* __restrict__ res,
                                                  float* __restrict__ out)
{
    __shared__ __align__(16) unsigned short se[8 * 16 * 64];

    const int t0 = (blockIdx.x & 15) * 8, bn = blockIdx.x >> 4;
    const int tid = threadIdx.x;

    {
        int f = tid >> 4, c4 = (tid & 15) * 4;
#pragma unroll
        for (int tl = 0; tl < 8; ++tl)
            *reinterpret_cast<ushort4*>(&se[tl * 1024 + f * 64 + c4]) =
                *reinterpret_cast<const ushort4*>(&e[(((size_t)bn * T_ + t0 + tl) * F_ + f) * H_ + c4]);
    }
    __syncthreads();

    const int g = tid >> 4, hq = tid & 15;
    float ag[16];
#pragma unroll
    for (int f = 0; f < 16; ++f) ag[f] = adjg[g * 16 + f];
    float gm0 = gamma[hq * 4 + 0], gm1 = gamma[hq * 4 + 1], gm2 = gamma[hq * 4 + 2], gm3 = gamma[hq * 4 + 3];
    float be0 = beta[hq * 4 + 0],  be1 = beta[hq * 4 + 1],  be2 = beta[hq * 4 + 2],  be3 = beta[hq * 4 + 3];

    for (int tl = 0; tl < 8; ++tl) {
        float a0 = 0.f, a1 = 0.f, a2 = 0.f, a3 = 0.f;
#pragma unroll
        for (int f = 0; f < 16; ++f) {
            ushort4 dv = *reinterpret_cast<const ushort4*>(&se[tl * 1024 + f * 64 + hq * 4]);
            float av = ag[f];
            a0 = fmaf(av, h2f(dv.x), a0);
            a1 = fmaf(av, h2f(dv.y), a1);
            a2 = fmaf(av, h2f(dv.z), a2);
            a3 = fmaf(av, h2f(dv.w), a3);
        }
        float s  = a0 + a1 + a2 + a3;
        float qv = a0*a0 + a1*a1 + a2*a2 + a3*a3;
#pragma unroll
        for (int m = 1; m < 16; m <<= 1) { s += __shfl_xor(s, m, 64); qv += __shfl_xor(qv, m, 64); }
        float mean = s * (1.f / 64.f);
        float var  = qv * (1.f / 64.f) - mean * mean;
        float rstd = rsqrtf(var + 1e-5f);

        const size_t o = (((size_t)bn * T_ + t0 + tl) * F_ + g) * H_ + hq * 4;
        float4 rv = *reinterpret_cast<const float4*>(res + o);
        float4 ov;
        ov.x = (a0 - mean) * rstd * gm0 + be0 + rv.x;
        ov.y = (a1 - mean) * rstd * gm1 + be1 + rv.y;
        ov.z = (a2 - mean) * rstd * gm2 + be2 + rv.z;
        ov.w = (a3 - mean) * rstd * gm3 + be3 + rv.w;
        *reinterpret_cast<float4*>(out + o) = ov;
    }
}

extern "C" void kernel_launch(void* const* d_in, const int* in_sizes, int n_in,
                              void* d_out, int out_size, void* d_ws, size_t ws_size,
                              hipStream_t stream)
{
    const float* h_in    = (const float*)d_in[0];
    const float* embs_G  = (const float*)d_in[2];
    const float* embs_g  = (const float*)d_in[3];
    const float* adj_G   = (const float*)d_in[4];
    const float* adj_g   = (const float*)d_in[5];
    const float* Wt0 = (const float*)d_in[6];  const float* bt0 = (const float*)d_in[7];
    const float* Wt1 = (const float*)d_in[8];  const float* bt1 = (const float*)d_in[9];
    const float* Wt2 = (const float*)d_in[10]; const float* bt2 = (const float*)d_in[11];
    const float* gamma_t = (const float*)d_in[12]; const float* beta_t = (const float*)d_in[13];
    const float* W_G = (const float*)d_in[14]; const float* b_G = (const float*)d_in[15];
    const float* gamma_G = (const float*)d_in[16]; const float* beta_G = (const float*)d_in[17];
    const float* W_g = (const float*)d_in[18]; const float* b_g = (const float*)d_in[19];
    const float* gamma_g = (const float*)d_in[20]; const float* beta_g = (const float*)d_in[21];

    float* out = (float*)d_out;
    char*  ws  = (char*)d_ws;
    unsigned short* d1 = (unsigned short*)ws;                          // 64 MiB (paged layout)
    unsigned short* d2 = (unsigned short*)(ws + ((size_t)64 << 20));   // 64 MiB

    unsigned short* prep = (unsigned short*)(ws + ((size_t)192 << 20));
    unsigned short* pw   = prep;                 // 3*16*64*192
    unsigned short* pWG  = prep + 589824;
    unsigned short* pWg  = pWG + 6656;
    unsigned short* padj = pWg + 6656;

    prep_w<<<48, 256, 0, stream>>>(Wt0, Wt1, Wt2, pw);
    prep_small<<<1, 256, 0, stream>>>(adj_G, W_G, W_g, padj, pWG, pWg);

    conv_chain<<<4096, 512, 0, stream>>>(h_in, pw, bt0, bt1, bt2, gamma_t, beta_t,
                                         embs_G, pWG, b_G, d1);
    nodemix_dense2<<<2048, 256, 0, stream>>>(d1, padj, gamma_G, beta_G,
                                             embs_g, pWg, b_g, d2);
    featmix_v3<<<4096, 256, 0, stream>>>(d2, adj_g, gamma_g, beta_g, h_in, out);
}

// Round 18
// 229.067 us; speedup vs baseline: 5.4197x; 1.0671x over previous
//
#include <hip/hip_runtime.h>

#define BN_ 256
#define T_  128
#define F_  16
#define H_  64

using f16x8   = __attribute__((ext_vector_type(8))) _Float16;
using f32x4   = __attribute__((ext_vector_type(4))) float;
using ushort8 = __attribute__((ext_vector_type(8))) unsigned short;

__device__ __forceinline__ float elu_(float x) { return x > 0.f ? x : __expf(x) - 1.f; }
__device__ __forceinline__ unsigned short f2h(float x) {
    union { _Float16 h; unsigned short u; } v; v.h = (_Float16)x; return v.u;
}
__device__ __forceinline__ float h2f(unsigned short u) {
    union { unsigned short u; _Float16 h; } v; v.u = u; return (float)v.h;
}
__device__ __forceinline__ unsigned pk2(float a, float b) {
    auto h = __builtin_amdgcn_cvt_pkrtz(a, b);
    unsigned u; __builtin_memcpy(&u, &h, 4); return u;
}
__device__ __forceinline__ void st4h(unsigned short* p, float a, float b, float c, float d) {
    uint2 v; v.x = pk2(a, b); v.y = pk2(c, d);
    *reinterpret_cast<uint2*>(p) = v;
}

// ---------------- prep: conv weights -> fp16 transposed [l][f][g][192]; block 48 does small tensors ----------------
__global__ __launch_bounds__(256) void prep_all(const float* __restrict__ Wt0,
                                                const float* __restrict__ Wt1,
                                                const float* __restrict__ Wt2,
                                                const float* __restrict__ adjG,
                                                const float* __restrict__ W_G,
                                                const float* __restrict__ W_g,
                                                unsigned short* __restrict__ pw,
                                                unsigned short* __restrict__ padj,
                                                unsigned short* __restrict__ pWG,
                                                unsigned short* __restrict__ pWg)
{
    const int tid = threadIdx.x;
    if (blockIdx.x == 48) {
        for (int idx = tid; idx < 4608; idx += 256) {
            int m = idx / 72, n = idx - m * 72;
            padj[idx] = (n < 64) ? f2h(adjG[m * 64 + n]) : (unsigned short)0;
        }
        for (int idx = tid; idx < 6656; idx += 256) {
            int g = idx / 104, k = idx - g * 104;
            pWG[idx] = (k < 80) ? f2h(W_G[k * 64 + g]) : (unsigned short)0;
        }
        for (int idx = tid; idx < 6656; idx += 256) {
            int g = idx / 104, k = idx - g * 104;
            pWg[idx] = (k < 72) ? f2h(W_g[k * 64 + g]) : (unsigned short)0;
        }
        return;
    }
    __shared__ unsigned short sW[64 * 200];
    const int lf = blockIdx.x, l = lf >> 4, f = lf & 15;
    const float* W = (l == 0) ? Wt0 : ((l == 1) ? Wt1 : Wt2);

    for (int idx = tid; idx < 3 * 4096; idx += 256) {
        int tap = idx >> 12, rem = idx & 4095;
        int h = rem >> 6, g = rem & 63;
        sW[g * 200 + tap * 64 + h] = f2h(W[(size_t)(tap * 16 + f) * 4096 + rem]);
    }
    __syncthreads();
    for (int idx = tid; idx < 64 * 24; idx += 256) {
        int g = idx / 24, k8 = idx - g * 24;
        *reinterpret_cast<ushort8*>(&pw[((size_t)lf * 64 + g) * 192 + k8 * 8]) =
            *reinterpret_cast<const ushort8*>(&sW[g * 200 + k8 * 8]);
    }
}

// ---------------- fused: tconv x3 (+LN_t) + dense_G per (bn,f); 8 waves (verified r16/r17) ----------------
// d1 layout: pages [b][t][f][n][64h]
__global__ __launch_bounds__(512) void conv_chain(const float* __restrict__ in,
                                                  const unsigned short* __restrict__ pw,
                                                  const float* __restrict__ bt0,
                                                  const float* __restrict__ bt1,
                                                  const float* __restrict__ bt2,
                                                  const float* __restrict__ gamma,
                                                  const float* __restrict__ beta,
                                                  const float* __restrict__ embs_G,
                                                  const unsigned short* __restrict__ pWG,
                                                  const float* __restrict__ b_G,
                                                  unsigned short* __restrict__ d1)
{
    __shared__ __align__(16) char smem[46720];
    unsigned short* tile = (unsigned short*)smem;             // [136][72]
    unsigned short* sW   = (unsigned short*)(smem + 19584);   // [64][200]
    float*          sCst = (float*)(smem + 45184);            // [6][64]
    unsigned short* sA1  = (unsigned short*)smem;             // [128][104] overlay
    unsigned short* sWG  = (unsigned short*)(smem + 26624);   // [64][104] overlay

    const int f   = blockIdx.x & 15;
    const int bn  = blockIdx.x >> 4;
    const int tid = threadIdx.x;
    const int lane = tid & 63, w = tid >> 6;
    const int r16 = lane & 15, q = lane >> 4;

    const int et = tid >> 2, ee = (tid & 3) * 4;
    float4 ereg = *reinterpret_cast<const float4*>(
        embs_G + ((((size_t)bn * T_ + et) * F_ + f) * 16 + ee));

    if (tid < 64) {
        sCst[0 * 64 + tid] = bt0[f * 64 + tid];
        sCst[1 * 64 + tid] = bt1[f * 64 + tid];
        sCst[2 * 64 + tid] = bt2[f * 64 + tid];
        sCst[3 * 64 + tid] = gamma[tid];
        sCst[4 * 64 + tid] = beta[tid];
        sCst[5 * 64 + tid] = b_G[tid];
    }
    // halo rows (0..3, 132..135) zero
    if (tid < 128) {
        int hr = tid >> 4;
        int r = (hr < 4) ? hr : 128 + hr;
        uint2 z = {0, 0};
        *reinterpret_cast<uint2*>(&tile[r * 72 + (tid & 15) * 4]) = z;
    }
    // body rows: exactly 4 branch-free iterations
#pragma unroll
    for (int it = 0; it < 4; ++it) {
        int idx = it * 512 + tid;
        int r = idx >> 4, h4 = (idx & 15) * 4;
        float4 x = *reinterpret_cast<const float4*>(in + (((size_t)bn * T_ + r) * F_ + f) * H_ + h4);
        st4h(&tile[(r + 4) * 72 + h4], x.x, x.y, x.z, x.w);
    }
    {
        const unsigned short* wsrc = pw + (size_t)f * 64 * 192;
        for (int idx = tid; idx < 1536; idx += 512) {
            int g = idx / 24, k8 = idx - g * 24;
            *reinterpret_cast<ushort8*>(&sW[g * 200 + k8 * 8]) =
                *reinterpret_cast<const ushort8*>(&wsrc[g * 192 + k8 * 8]);
        }
    }
    __syncthreads();

    float vv[4][4];

#pragma unroll
    for (int l = 0; l < 3; ++l) {
        const int dil = 1 << l;

        ushort8 wreg[3];
        if (l < 2) {
            const unsigned short* wsrc = pw + ((size_t)((l + 1) * 16 + f) * 64) * 192;
#pragma unroll
            for (int j = 0; j < 3; ++j) {
                int idx = j * 512 + tid, g = idx / 24, k8 = idx - g * 24;
                wreg[j] = *reinterpret_cast<const ushort8*>(&wsrc[g * 192 + k8 * 8]);
            }
        }
        ushort8 wgreg[2];
        if (l == 2) {
#pragma unroll
            for (int j = 0; j < 2; ++j) {
                int idx = j * 512 + tid;
                if (idx < 832) wgreg[j] = reinterpret_cast<const ushort8*>(pWG)[idx];
            }
        }

        f32x4 acc[4];
#pragma unroll
        for (int j = 0; j < 4; j++) acc[j] = {0.f, 0.f, 0.f, 0.f};

#pragma unroll
        for (int tap = 0; tap < 3; ++tap) {
            const int row0 = w * 16 + r16 + 4 + (tap - 1) * dil;
#pragma unroll
            for (int ks = 0; ks < 2; ++ks) {
                const int ko = ks * 32 + q * 8;
                f16x8 a0 = *reinterpret_cast<const f16x8*>(&tile[row0 * 72 + ko]);
                const int kb = tap * 64 + ko;
                f16x8 b0 = *reinterpret_cast<const f16x8*>(&sW[(r16     ) * 200 + kb]);
                f16x8 b1 = *reinterpret_cast<const f16x8*>(&sW[(r16 + 16) * 200 + kb]);
                f16x8 b2 = *reinterpret_cast<const f16x8*>(&sW[(r16 + 32) * 200 + kb]);
                f16x8 b3 = *reinterpret_cast<const f16x8*>(&sW[(r16 + 48) * 200 + kb]);
                acc[0] = __builtin_amdgcn_mfma_f32_16x16x32_f16(b0, a0, acc[0], 0, 0, 0);
                acc[1] = __builtin_amdgcn_mfma_f32_16x16x32_f16(b1, a0, acc[1], 0, 0, 0);
                acc[2] = __builtin_amdgcn_mfma_f32_16x16x32_f16(b2, a0, acc[2], 0, 0, 0);
                acc[3] = __builtin_amdgcn_mfma_f32_16x16x32_f16(b3, a0, acc[3], 0, 0, 0);
            }
        }

#pragma unroll
        for (int gt = 0; gt < 4; ++gt) {
            float4 b4 = *reinterpret_cast<const float4*>(&sCst[l * 64 + gt * 16 + q * 4]);
#pragma unroll
            for (int r = 0; r < 4; ++r) vv[gt][r] = elu_(acc[gt][r] + ((const float*)&b4)[r]);
        }
        if (l == 2) {
            float s = 0.f, qq = 0.f;
#pragma unroll
            for (int gt = 0; gt < 4; ++gt)
#pragma unroll
                for (int r = 0; r < 4; ++r) { float v = vv[gt][r]; s += v; qq += v * v; }
            s += __shfl_xor(s, 16, 64); qq += __shfl_xor(qq, 16, 64);
            s += __shfl_xor(s, 32, 64); qq += __shfl_xor(qq, 32, 64);
            float mean = s * (1.f / 64.f);
            float var  = qq * (1.f / 64.f) - mean * mean;
            float rstd = rsqrtf(var + 1e-5f);
#pragma unroll
            for (int gt = 0; gt < 4; ++gt) {
                float4 g4 = *reinterpret_cast<const float4*>(&sCst[3 * 64 + gt * 16 + q * 4]);
                float4 be4 = *reinterpret_cast<const float4*>(&sCst[4 * 64 + gt * 16 + q * 4]);
#pragma unroll
                for (int r = 0; r < 4; ++r)
                    vv[gt][r] = (vv[gt][r] - mean) * rstd * ((const float*)&g4)[r] + ((const float*)&be4)[r];
            }
        }
        __syncthreads();

        if (l < 2) {
            const int t = w * 16 + r16;
#pragma unroll
            for (int gt = 0; gt < 4; ++gt)
                st4h(&tile[(t + 4) * 72 + gt * 16 + q * 4],
                     vv[gt][0], vv[gt][1], vv[gt][2], vv[gt][3]);
#pragma unroll
            for (int j = 0; j < 3; ++j) {
                int idx = j * 512 + tid, g = idx / 24, k8 = idx - g * 24;
                *reinterpret_cast<ushort8*>(&sW[g * 200 + k8 * 8]) = wreg[j];
            }
            __syncthreads();
        } else {
            const int t = w * 16 + r16;
#pragma unroll
            for (int gt = 0; gt < 4; ++gt)
                st4h(&sA1[t * 104 + gt * 16 + q * 4],
                     vv[gt][0], vv[gt][1], vv[gt][2], vv[gt][3]);
            st4h(&sA1[et * 104 + 64 + ee], ereg.x, ereg.y, ereg.z, ereg.w);
            if (tid < 256) {
                int r = tid >> 1, half = tid & 1;
                ushort8 z = {0,0,0,0,0,0,0,0};
                *reinterpret_cast<ushort8*>(&sA1[r * 104 + 80 + half * 8]) = z;
            }
#pragma unroll
            for (int j = 0; j < 2; ++j) {
                int idx = j * 512 + tid;
                if (idx < 832) reinterpret_cast<ushort8*>(sWG)[idx] = wgreg[j];
            }
            __syncthreads();
        }
    }

    f32x4 dacc[4];
#pragma unroll
    for (int j = 0; j < 4; j++) dacc[j] = {0.f, 0.f, 0.f, 0.f};

#pragma unroll
    for (int ks = 0; ks < 3; ++ks) {
        const int ko = ks * 32 + q * 8;
        f16x8 a0 = *reinterpret_cast<const f16x8*>(&sA1[(w * 16 + r16) * 104 + ko]);
#pragma unroll
        for (int gt = 0; gt < 4; ++gt) {
            f16x8 bb = *reinterpret_cast<const f16x8*>(&sWG[(gt * 16 + r16) * 104 + ko]);
            dacc[gt] = __builtin_amdgcn_mfma_f32_16x16x32_f16(bb, a0, dacc[gt], 0, 0, 0);
        }
    }

    {
        const int t = w * 16 + r16;
        const int b = bn >> 6, n = bn & 63;
        const size_t ob = ((((size_t)b * T_ + t) * F_ + f) << 12) + (size_t)n * 64;
#pragma unroll
        for (int gt = 0; gt < 4; ++gt) {
            float4 b4 = *reinterpret_cast<const float4*>(&sCst[5 * 64 + gt * 16 + q * 4]);
            st4h(&d1[ob + gt * 16 + q * 4],
                 elu_(dacc[gt][0] + ((const float*)&b4)[0]),
                 elu_(dacc[gt][1] + ((const float*)&b4)[1]),
                 elu_(dacc[gt][2] + ((const float*)&b4)[2]),
                 elu_(dacc[gt][3] + ((const float*)&b4)[3]));
        }
    }
}

// ---------------- fused: node mix + LN_G + dense_g, 4 t per block, coalesced d1 pages (verified r17) ----------------
__global__ __launch_bounds__(256) void nodemix_dense2(const unsigned short* __restrict__ d1,
                                                      const unsigned short* __restrict__ padj,
                                                      const float* __restrict__ gamma,
                                                      const float* __restrict__ beta,
                                                      const float* __restrict__ embs_g,
                                                      const unsigned short* __restrict__ pWg,
                                                      const float* __restrict__ b_g,
                                                      unsigned short* __restrict__ d2)
{
    __shared__ __align__(16) char smem[47872];
    unsigned short* sAdj = (unsigned short*)smem;            // [64][72]
    unsigned short* sXT  = (unsigned short*)(smem + 9216);   // [64][88]
    unsigned short* sA2  = (unsigned short*)(smem + 20480);  // [64][104]
    unsigned short* sWg  = (unsigned short*)(smem + 33792);  // [64][104]
    float*          sBg  = (float*)(smem + 47104);           // [64]
    float*          sGB  = (float*)(smem + 47360);           // [128] gamma|beta

    const int f  = blockIdx.x & 15;
    const int tq = (blockIdx.x >> 4) & 31;
    const int b  = blockIdx.x >> 9;
    const int t0 = tq * 4;
    const int tid = threadIdx.x, lane = tid & 63, w = tid >> 6;
    const int r16 = lane & 15, q = lane >> 4;

    if (tid < 64) sBg[tid] = b_g[tid];
    if (tid >= 64 && tid < 128) sGB[tid - 64] = gamma[tid - 64];
    if (tid >= 128 && tid < 192) sGB[tid - 64] = beta[tid - 128];
    for (int idx = tid; idx < 576; idx += 256)
        reinterpret_cast<ushort8*>(sAdj)[idx] = reinterpret_cast<const ushort8*>(padj)[idx];
    for (int idx = tid; idx < 832; idx += 256)
        reinterpret_cast<ushort8*>(sWg)[idx] = reinterpret_cast<const ushort8*>(pWg)[idx];
    for (int idx = tid; idx < 192; idx += 256) {
        int m = idx / 3, k8 = idx - m * 3;
        ushort8 z = {0,0,0,0,0,0,0,0};
        *reinterpret_cast<ushort8*>(&sA2[m * 104 + 72 + k8 * 8]) = z;
    }

    const int pn = tid >> 2, ph = (tid & 3) * 16;
    const int em = tid >> 2, ec = (tid & 3) * 2;
    ushort8 xr0, xr1;
    float2  er;
    {
        const unsigned short* pg = d1 + (((((size_t)b * T_ + t0) * F_) + f) << 12);
        xr0 = *reinterpret_cast<const ushort8*>(&pg[pn * 64 + ph]);
        xr1 = *reinterpret_cast<const ushort8*>(&pg[pn * 64 + ph + 8]);
        er  = *reinterpret_cast<const float2*>(&embs_g[((((size_t)(b * 64 + em)) * T_ + t0) * F_ + f) * 8 + ec]);
    }

    for (int tt = 0; tt < 4; ++tt) {
        const int t = t0 + tt;

        {
#pragma unroll
            for (int i = 0; i < 8; ++i) sXT[(ph + i) * 88 + pn] = xr0[i];
#pragma unroll
            for (int i = 0; i < 8; ++i) sXT[(ph + 8 + i) * 88 + pn] = xr1[i];
            *reinterpret_cast<unsigned*>(&sA2[em * 104 + 64 + ec]) = pk2(er.x, er.y);
        }
        if (tt < 3) {
            const unsigned short* pg = d1 + (((((size_t)b * T_ + t + 1) * F_) + f) << 12);
            xr0 = *reinterpret_cast<const ushort8*>(&pg[pn * 64 + ph]);
            xr1 = *reinterpret_cast<const ushort8*>(&pg[pn * 64 + ph + 8]);
            er  = *reinterpret_cast<const float2*>(&embs_g[((((size_t)(b * 64 + em)) * T_ + t + 1) * F_ + f) * 8 + ec]);
        }
        __syncthreads();

        f32x4 acc[4];
#pragma unroll
        for (int j = 0; j < 4; j++) acc[j] = {0.f, 0.f, 0.f, 0.f};
#pragma unroll
        for (int ks = 0; ks < 2; ++ks) {
            f16x8 af = *reinterpret_cast<const f16x8*>(&sAdj[(w * 16 + r16) * 72 + ks * 32 + q * 8]);
#pragma unroll
            for (int ht = 0; ht < 4; ++ht) {
                f16x8 xf = *reinterpret_cast<const f16x8*>(&sXT[(ht * 16 + r16) * 88 + ks * 32 + q * 8]);
                acc[ht] = __builtin_amdgcn_mfma_f32_16x16x32_f16(xf, af, acc[ht], 0, 0, 0);
            }
        }

        const int m = w * 16 + r16;
        float s = 0.f, qq = 0.f;
#pragma unroll
        for (int ht = 0; ht < 4; ++ht)
#pragma unroll
            for (int r = 0; r < 4; ++r) { float v = acc[ht][r]; s += v; qq += v * v; }
        s += __shfl_xor(s, 16, 64); qq += __shfl_xor(qq, 16, 64);
        s += __shfl_xor(s, 32, 64); qq += __shfl_xor(qq, 32, 64);
        float mean = s * (1.f / 64.f);
        float var  = qq * (1.f / 64.f) - mean * mean;
        float rstd = rsqrtf(var + 1e-5f);

#pragma unroll
        for (int ht = 0; ht < 4; ++ht) {
            float4 g4  = *reinterpret_cast<const float4*>(&sGB[ht * 16 + q * 4]);
            float4 be4 = *reinterpret_cast<const float4*>(&sGB[64 + ht * 16 + q * 4]);
            st4h(&sA2[m * 104 + ht * 16 + q * 4],
                 (acc[ht][0] - mean) * rstd * ((const float*)&g4)[0] + ((const float*)&be4)[0],
                 (acc[ht][1] - mean) * rstd * ((const float*)&g4)[1] + ((const float*)&be4)[1],
                 (acc[ht][2] - mean) * rstd * ((const float*)&g4)[2] + ((const float*)&be4)[2],
                 (acc[ht][3] - mean) * rstd * ((const float*)&g4)[3] + ((const float*)&be4)[3]);
        }
        __syncthreads();

        f32x4 dacc[4];
#pragma unroll
        for (int j = 0; j < 4; j++) dacc[j] = {0.f, 0.f, 0.f, 0.f};
#pragma unroll
        for (int ks = 0; ks < 3; ++ks) {
            const int ko = ks * 32 + q * 8;
            f16x8 aw = *reinterpret_cast<const f16x8*>(&sWg[(w * 16 + r16) * 104 + ko]);
#pragma unroll
            for (int mt = 0; mt < 4; ++mt) {
                f16x8 bx = *reinterpret_cast<const f16x8*>(&sA2[(mt * 16 + r16) * 104 + ko]);
                dacc[mt] = __builtin_amdgcn_mfma_f32_16x16x32_f16(aw, bx, dacc[mt], 0, 0, 0);
            }
        }

        float4 b4 = *reinterpret_cast<const float4*>(&sBg[w * 16 + q * 4]);
#pragma unroll
        for (int mt = 0; mt < 4; ++mt) {
            const int mm = mt * 16 + r16;
            const size_t row = (((size_t)(b * 64 + mm) * T_ + t) * F_ + f);
            st4h(&d2[row * H_ + w * 16 + q * 4],
                 elu_(dacc[mt][0] + b4.x), elu_(dacc[mt][1] + b4.y),
                 elu_(dacc[mt][2] + b4.z), elu_(dacc[mt][3] + b4.w));
        }
        __syncthreads();
    }
}

// ---------------- feature mix + LN + residual, 8 t per block (verified r14-r17) ----------------
__global__ __launch_bounds__(256) void featmix_v3(const unsigned short* __restrict__ e,
                                                  const float* __restrict__ adjg,
                                                  const float* __restrict__ gamma,
                                                  const float* __restrict__ beta,
                                                  const float* __restrict__ res,
                                                  float* __restrict__ out)
{
    __shared__ __align__(16) unsigned short se[8 * 16 * 64];

    const int t0 = (blockIdx.x & 15) * 8, bn = blockIdx.x >> 4;
    const int tid = threadIdx.x;

    {
        int f = tid >> 4, c4 = (tid & 15) * 4;
#pragma unroll
        for (int tl = 0; tl < 8; ++tl)
            *reinterpret_cast<ushort4*>(&se[tl * 1024 + f * 64 + c4]) =
                *reinterpret_cast<const ushort4*>(&e[(((size_t)bn * T_ + t0 + tl) * F_ + f) * H_ + c4]);
    }
    __syncthreads();

    const int g = tid >> 4, hq = tid & 15;
    float ag[16];
#pragma unroll
    for (int f = 0; f < 16; ++f) ag[f] = adjg[g * 16 + f];
    float gm0 = gamma[hq * 4 + 0], gm1 = gamma[hq * 4 + 1], gm2 = gamma[hq * 4 + 2], gm3 = gamma[hq * 4 + 3];
    float be0 = beta[hq * 4 + 0],  be1 = beta[hq * 4 + 1],  be2 = beta[hq * 4 + 2],  be3 = beta[hq * 4 + 3];

    for (int tl = 0; tl < 8; ++tl) {
        float a0 = 0.f, a1 = 0.f, a2 = 0.f, a3 = 0.f;
#pragma unroll
        for (int f = 0; f < 16; ++f) {
            ushort4 dv = *reinterpret_cast<const ushort4*>(&se[tl * 1024 + f * 64 + hq * 4]);
            float av = ag[f];
            a0 = fmaf(av, h2f(dv.x), a0);
            a1 = fmaf(av, h2f(dv.y), a1);
            a2 = fmaf(av, h2f(dv.z), a2);
            a3 = fmaf(av, h2f(dv.w), a3);
        }
        float s  = a0 + a1 + a2 + a3;
        float qv = a0*a0 + a1*a1 + a2*a2 + a3*a3;
#pragma unroll
        for (int m = 1; m < 16; m <<= 1) { s += __shfl_xor(s, m, 64); qv += __shfl_xor(qv, m, 64); }
        float mean = s * (1.f / 64.f);
        float var  = qv * (1.f / 64.f) - mean * mean;
        float rstd = rsqrtf(var + 1e-5f);

        const size_t o = (((size_t)bn * T_ + t0 + tl) * F_ + g) * H_ + hq * 4;
        float4 rv = *reinterpret_cast<const float4*>(res + o);
        float4 ov;
        ov.x = (a0 - mean) * rstd * gm0 + be0 + rv.x;
        ov.y = (a1 - mean) * rstd * gm1 + be1 + rv.y;
        ov.z = (a2 - mean) * rstd * gm2 + be2 + rv.z;
        ov.w = (a3 - mean) * rstd * gm3 + be3 + rv.w;
        *reinterpret_cast<float4*>(out + o) = ov;
    }
}

extern "C" void kernel_launch(void* const* d_in, const int* in_sizes, int n_in,
                              void* d_out, int out_size, void* d_ws, size_t ws_size,
                              hipStream_t stream)
{
    const float* h_in    = (const float*)d_in[0];
    const float* embs_G  = (const float*)d_in[2];
    const float* embs_g  = (const float*)d_in[3];
    const float* adj_G   = (const float*)d_in[4];
    const float* adj_g   = (const float*)d_in[5];
    const float* Wt0 = (const float*)d_in[6];  const float* bt0 = (const float*)d_in[7];
    const float* Wt1 = (const float*)d_in[8];  const float* bt1 = (const float*)d_in[9];
    const float* Wt2 = (const float*)d_in[10]; const float* bt2 = (const float*)d_in[11];
    const float* gamma_t = (const float*)d_in[12]; const float* beta_t = (const float*)d_in[13];
    const float* W_G = (const float*)d_in[14]; const float* b_G = (const float*)d_in[15];
    const float* gamma_G = (const float*)d_in[16]; const float* beta_G = (const float*)d_in[17];
    const float* W_g = (const float*)d_in[18]; const float* b_g = (const float*)d_in[19];
    const float* gamma_g = (const float*)d_in[20]; const float* beta_g = (const float*)d_in[21];

    float* out = (float*)d_out;
    char*  ws  = (char*)d_ws;
    unsigned short* d1 = (unsigned short*)ws;                          // 64 MiB (paged layout)
    unsigned short* d2 = (unsigned short*)(ws + ((size_t)64 << 20));   // 64 MiB

    unsigned short* prep = (unsigned short*)(ws + ((size_t)192 << 20));
    unsigned short* pw   = prep;                 // 3*16*64*192
    unsigned short* pWG  = prep + 589824;
    unsigned short* pWg  = pWG + 6656;
    unsigned short* padj = pWg + 6656;

    prep_all<<<49, 256, 0, stream>>>(Wt0, Wt1, Wt2, adj_G, W_G, W_g, pw, padj, pWG, pWg);

    conv_chain<<<4096, 512, 0, stream>>>(h_in, pw, bt0, bt1, bt2, gamma_t, beta_t,
                                         embs_G, pWG, b_G, d1);
    nodemix_dense2<<<2048, 256, 0, stream>>>(d1, padj, gamma_G, beta_G,
                                             embs_g, pWg, b_g, d2);
    featmix_v3<<<4096, 256, 0, stream>>>(d2, adj_g, gamma_g, beta_g, h_in, out);
}

// Round 19
// 224.210 us; speedup vs baseline: 5.5371x; 1.0217x over previous
//
#include <hip/hip_runtime.h>

#define BN_ 256
#define T_  128
#define F_  16
#define H_  64

using f16x8   = __attribute__((ext_vector_type(8))) _Float16;
using f32x4   = __attribute__((ext_vector_type(4))) float;
using ushort8 = __attribute__((ext_vector_type(8))) unsigned short;

__device__ __forceinline__ float elu_(float x) { return x > 0.f ? x : __expf(x) - 1.f; }
__device__ __forceinline__ unsigned short f2h(float x) {
    union { _Float16 h; unsigned short u; } v; v.h = (_Float16)x; return v.u;
}
__device__ __forceinline__ float h2f(unsigned short u) {
    union { unsigned short u; _Float16 h; } v; v.u = u; return (float)v.h;
}
__device__ __forceinline__ unsigned pk2(float a, float b) {
    auto h = __builtin_amdgcn_cvt_pkrtz(a, b);
    unsigned u; __builtin_memcpy(&u, &h, 4); return u;
}
__device__ __forceinline__ void st4h(unsigned short* p, float a, float b, float c, float d) {
    uint2 v; v.x = pk2(a, b); v.y = pk2(c, d);
    *reinterpret_cast<uint2*>(p) = v;
}

// ---------------- prep: conv weights -> fp16 transposed [l][f][g][192]; block 48 does small tensors ----------------
__global__ __launch_bounds__(256) void prep_all(const float* __restrict__ Wt0,
                                                const float* __restrict__ Wt1,
                                                const float* __restrict__ Wt2,
                                                const float* __restrict__ adjG,
                                                const float* __restrict__ W_G,
                                                const float* __restrict__ W_g,
                                                unsigned short* __restrict__ pw,
                                                unsigned short* __restrict__ padj,
                                                unsigned short* __restrict__ pWG,
                                                unsigned short* __restrict__ pWg)
{
    const int tid = threadIdx.x;
    if (blockIdx.x == 48) {
        for (int idx = tid; idx < 4608; idx += 256) {
            int m = idx / 72, n = idx - m * 72;
            padj[idx] = (n < 64) ? f2h(adjG[m * 64 + n]) : (unsigned short)0;
        }
        for (int idx = tid; idx < 6656; idx += 256) {
            int g = idx / 104, k = idx - g * 104;
            pWG[idx] = (k < 80) ? f2h(W_G[k * 64 + g]) : (unsigned short)0;
        }
        for (int idx = tid; idx < 6656; idx += 256) {
            int g = idx / 104, k = idx - g * 104;
            pWg[idx] = (k < 72) ? f2h(W_g[k * 64 + g]) : (unsigned short)0;
        }
        return;
    }
    __shared__ unsigned short sW[64 * 200];
    const int lf = blockIdx.x, l = lf >> 4, f = lf & 15;
    const float* W = (l == 0) ? Wt0 : ((l == 1) ? Wt1 : Wt2);

    for (int idx = tid; idx < 3 * 4096; idx += 256) {
        int tap = idx >> 12, rem = idx & 4095;
        int h = rem >> 6, g = rem & 63;
        sW[g * 200 + tap * 64 + h] = f2h(W[(size_t)(tap * 16 + f) * 4096 + rem]);
    }
    __syncthreads();
    for (int idx = tid; idx < 64 * 24; idx += 256) {
        int g = idx / 24, k8 = idx - g * 24;
        *reinterpret_cast<ushort8*>(&pw[((size_t)lf * 64 + g) * 192 + k8 * 8]) =
            *reinterpret_cast<const ushort8*>(&sW[g * 200 + k8 * 8]);
    }
}

// ---------------- fused: tconv x3 (+LN_t) + dense_G per (bn,f); 8 waves; re-padded LDS ----------------
// tile stride 80 (4-way), sW stride 208 (4-way). d1 layout: pages [b][t][f][n][64h]
__global__ __launch_bounds__(512) void conv_chain(const float* __restrict__ in,
                                                  const unsigned short* __restrict__ pw,
                                                  const float* __restrict__ bt0,
                                                  const float* __restrict__ bt1,
                                                  const float* __restrict__ bt2,
                                                  const float* __restrict__ gamma,
                                                  const float* __restrict__ beta,
                                                  const float* __restrict__ embs_G,
                                                  const unsigned short* __restrict__ pWG,
                                                  const float* __restrict__ b_G,
                                                  unsigned short* __restrict__ d1)
{
    __shared__ __align__(16) char smem[49920];
    unsigned short* tile = (unsigned short*)smem;             // [136][80] = 21760 B
    unsigned short* sW   = (unsigned short*)(smem + 21760);   // [64][208] = 26624 B -> 48384
    float*          sCst = (float*)(smem + 48384);            // [6][64] = 1536 -> 49920
    unsigned short* sA1  = (unsigned short*)smem;             // [128][104] overlay (0..26624)
    unsigned short* sWG  = (unsigned short*)(smem + 26624);   // [64][104] overlay (26624..39936)

    const int f   = blockIdx.x & 15;
    const int bn  = blockIdx.x >> 4;
    const int tid = threadIdx.x;
    const int lane = tid & 63, w = tid >> 6;
    const int r16 = lane & 15, q = lane >> 4;

    const int et = tid >> 2, ee = (tid & 3) * 4;
    float4 ereg = *reinterpret_cast<const float4*>(
        embs_G + ((((size_t)bn * T_ + et) * F_ + f) * 16 + ee));

    if (tid < 64) {
        sCst[0 * 64 + tid] = bt0[f * 64 + tid];
        sCst[1 * 64 + tid] = bt1[f * 64 + tid];
        sCst[2 * 64 + tid] = bt2[f * 64 + tid];
        sCst[3 * 64 + tid] = gamma[tid];
        sCst[4 * 64 + tid] = beta[tid];
        sCst[5 * 64 + tid] = b_G[tid];
    }
    // halo rows (0..3, 132..135) zero
    if (tid < 128) {
        int hr = tid >> 4;
        int r = (hr < 4) ? hr : 128 + hr;
        uint2 z = {0, 0};
        *reinterpret_cast<uint2*>(&tile[r * 80 + (tid & 15) * 4]) = z;
    }
    // body rows: exactly 4 branch-free iterations
#pragma unroll
    for (int it = 0; it < 4; ++it) {
        int idx = it * 512 + tid;
        int r = idx >> 4, h4 = (idx & 15) * 4;
        float4 x = *reinterpret_cast<const float4*>(in + (((size_t)bn * T_ + r) * F_ + f) * H_ + h4);
        st4h(&tile[(r + 4) * 80 + h4], x.x, x.y, x.z, x.w);
    }
    {
        const unsigned short* wsrc = pw + (size_t)f * 64 * 192;
        for (int idx = tid; idx < 1536; idx += 512) {
            int g = idx / 24, k8 = idx - g * 24;
            *reinterpret_cast<ushort8*>(&sW[g * 208 + k8 * 8]) =
                *reinterpret_cast<const ushort8*>(&wsrc[g * 192 + k8 * 8]);
        }
    }
    __syncthreads();

    float vv[4][4];

#pragma unroll
    for (int l = 0; l < 3; ++l) {
        const int dil = 1 << l;

        ushort8 wreg[3];
        if (l < 2) {
            const unsigned short* wsrc = pw + ((size_t)((l + 1) * 16 + f) * 64) * 192;
#pragma unroll
            for (int j = 0; j < 3; ++j) {
                int idx = j * 512 + tid, g = idx / 24, k8 = idx - g * 24;
                wreg[j] = *reinterpret_cast<const ushort8*>(&wsrc[g * 192 + k8 * 8]);
            }
        }
        ushort8 wgreg[2];
        if (l == 2) {
#pragma unroll
            for (int j = 0; j < 2; ++j) {
                int idx = j * 512 + tid;
                if (idx < 832) wgreg[j] = reinterpret_cast<const ushort8*>(pWG)[idx];
            }
        }

        f32x4 acc[4];
#pragma unroll
        for (int j = 0; j < 4; j++) acc[j] = {0.f, 0.f, 0.f, 0.f};

#pragma unroll
        for (int tap = 0; tap < 3; ++tap) {
            const int row0 = w * 16 + r16 + 4 + (tap - 1) * dil;
#pragma unroll
            for (int ks = 0; ks < 2; ++ks) {
                const int ko = ks * 32 + q * 8;
                f16x8 a0 = *reinterpret_cast<const f16x8*>(&tile[row0 * 80 + ko]);
                const int kb = tap * 64 + ko;
                f16x8 b0 = *reinterpret_cast<const f16x8*>(&sW[(r16     ) * 208 + kb]);
                f16x8 b1 = *reinterpret_cast<const f16x8*>(&sW[(r16 + 16) * 208 + kb]);
                f16x8 b2 = *reinterpret_cast<const f16x8*>(&sW[(r16 + 32) * 208 + kb]);
                f16x8 b3 = *reinterpret_cast<const f16x8*>(&sW[(r16 + 48) * 208 + kb]);
                acc[0] = __builtin_amdgcn_mfma_f32_16x16x32_f16(b0, a0, acc[0], 0, 0, 0);
                acc[1] = __builtin_amdgcn_mfma_f32_16x16x32_f16(b1, a0, acc[1], 0, 0, 0);
                acc[2] = __builtin_amdgcn_mfma_f32_16x16x32_f16(b2, a0, acc[2], 0, 0, 0);
                acc[3] = __builtin_amdgcn_mfma_f32_16x16x32_f16(b3, a0, acc[3], 0, 0, 0);
            }
        }

#pragma unroll
        for (int gt = 0; gt < 4; ++gt) {
            float4 b4 = *reinterpret_cast<const float4*>(&sCst[l * 64 + gt * 16 + q * 4]);
#pragma unroll
            for (int r = 0; r < 4; ++r) vv[gt][r] = elu_(acc[gt][r] + ((const float*)&b4)[r]);
        }
        if (l == 2) {
            float s = 0.f, qq = 0.f;
#pragma unroll
            for (int gt = 0; gt < 4; ++gt)
#pragma unroll
                for (int r = 0; r < 4; ++r) { float v = vv[gt][r]; s += v; qq += v * v; }
            s += __shfl_xor(s, 16, 64); qq += __shfl_xor(qq, 16, 64);
            s += __shfl_xor(s, 32, 64); qq += __shfl_xor(qq, 32, 64);
            float mean = s * (1.f / 64.f);
            float var  = qq * (1.f / 64.f) - mean * mean;
            float rstd = rsqrtf(var + 1e-5f);
#pragma unroll
            for (int gt = 0; gt < 4; ++gt) {
                float4 g4 = *reinterpret_cast<const float4*>(&sCst[3 * 64 + gt * 16 + q * 4]);
                float4 be4 = *reinterpret_cast<const float4*>(&sCst[4 * 64 + gt * 16 + q * 4]);
#pragma unroll
                for (int r = 0; r < 4; ++r)
                    vv[gt][r] = (vv[gt][r] - mean) * rstd * ((const float*)&g4)[r] + ((const float*)&be4)[r];
            }
        }
        __syncthreads();

        if (l < 2) {
            const int t = w * 16 + r16;
#pragma unroll
            for (int gt = 0; gt < 4; ++gt)
                st4h(&tile[(t + 4) * 80 + gt * 16 + q * 4],
                     vv[gt][0], vv[gt][1], vv[gt][2], vv[gt][3]);
#pragma unroll
            for (int j = 0; j < 3; ++j) {
                int idx = j * 512 + tid, g = idx / 24, k8 = idx - g * 24;
                *reinterpret_cast<ushort8*>(&sW[g * 208 + k8 * 8]) = wreg[j];
            }
            __syncthreads();
        } else {
            const int t = w * 16 + r16;
#pragma unroll
            for (int gt = 0; gt < 4; ++gt)
                st4h(&sA1[t * 104 + gt * 16 + q * 4],
                     vv[gt][0], vv[gt][1], vv[gt][2], vv[gt][3]);
            st4h(&sA1[et * 104 + 64 + ee], ereg.x, ereg.y, ereg.z, ereg.w);
            if (tid < 256) {
                int r = tid >> 1, half = tid & 1;
                ushort8 z = {0,0,0,0,0,0,0,0};
                *reinterpret_cast<ushort8*>(&sA1[r * 104 + 80 + half * 8]) = z;
            }
#pragma unroll
            for (int j = 0; j < 2; ++j) {
                int idx = j * 512 + tid;
                if (idx < 832) reinterpret_cast<ushort8*>(sWG)[idx] = wgreg[j];
            }
            __syncthreads();
        }
    }

    f32x4 dacc[4];
#pragma unroll
    for (int j = 0; j < 4; j++) dacc[j] = {0.f, 0.f, 0.f, 0.f};

#pragma unroll
    for (int ks = 0; ks < 3; ++ks) {
        const int ko = ks * 32 + q * 8;
        f16x8 a0 = *reinterpret_cast<const f16x8*>(&sA1[(w * 16 + r16) * 104 + ko]);
#pragma unroll
        for (int gt = 0; gt < 4; ++gt) {
            f16x8 bb = *reinterpret_cast<const f16x8*>(&sWG[(gt * 16 + r16) * 104 + ko]);
            dacc[gt] = __builtin_amdgcn_mfma_f32_16x16x32_f16(bb, a0, dacc[gt], 0, 0, 0);
        }
    }

    {
        const int t = w * 16 + r16;
        const int b = bn >> 6, n = bn & 63;
        const size_t ob = ((((size_t)b * T_ + t) * F_ + f) << 12) + (size_t)n * 64;
#pragma unroll
        for (int gt = 0; gt < 4; ++gt) {
            float4 b4 = *reinterpret_cast<const float4*>(&sCst[5 * 64 + gt * 16 + q * 4]);
            st4h(&d1[ob + gt * 16 + q * 4],
                 elu_(dacc[gt][0] + ((const float*)&b4)[0]),
                 elu_(dacc[gt][1] + ((const float*)&b4)[1]),
                 elu_(dacc[gt][2] + ((const float*)&b4)[2]),
                 elu_(dacc[gt][3] + ((const float*)&b4)[3]));
        }
    }
}

// ---------------- fused: node mix + LN_G + dense_g, 4 t per block; sXT re-padded to 104 ----------------
__global__ __launch_bounds__(256) void nodemix_dense2(const unsigned short* __restrict__ d1,
                                                      const unsigned short* __restrict__ padj,
                                                      const float* __restrict__ gamma,
                                                      const float* __restrict__ beta,
                                                      const float* __restrict__ embs_g,
                                                      const unsigned short* __restrict__ pWg,
                                                      const float* __restrict__ b_g,
                                                      unsigned short* __restrict__ d2)
{
    __shared__ __align__(16) char smem[49920];
    unsigned short* sAdj = (unsigned short*)smem;             // [64][72]  = 9216
    unsigned short* sXT  = (unsigned short*)(smem + 9216);    // [64][104] = 13312 -> 22528
    unsigned short* sA2  = (unsigned short*)(smem + 22528);   // [64][104] = 13312 -> 35840
    unsigned short* sWg  = (unsigned short*)(smem + 35840);   // [64][104] = 13312 -> 49152
    float*          sBg  = (float*)(smem + 49152);            // 256 -> 49408
    float*          sGB  = (float*)(smem + 49408);            // 512 -> 49920

    const int f  = blockIdx.x & 15;
    const int tq = (blockIdx.x >> 4) & 31;
    const int b  = blockIdx.x >> 9;
    const int t0 = tq * 4;
    const int tid = threadIdx.x, lane = tid & 63, w = tid >> 6;
    const int r16 = lane & 15, q = lane >> 4;

    if (tid < 64) sBg[tid] = b_g[tid];
    if (tid >= 64 && tid < 128) sGB[tid - 64] = gamma[tid - 64];
    if (tid >= 128 && tid < 192) sGB[tid - 64] = beta[tid - 128];
    for (int idx = tid; idx < 576; idx += 256)
        reinterpret_cast<ushort8*>(sAdj)[idx] = reinterpret_cast<const ushort8*>(padj)[idx];
    for (int idx = tid; idx < 832; idx += 256)
        reinterpret_cast<ushort8*>(sWg)[idx] = reinterpret_cast<const ushort8*>(pWg)[idx];
    for (int idx = tid; idx < 192; idx += 256) {
        int m = idx / 3, k8 = idx - m * 3;
        ushort8 z = {0,0,0,0,0,0,0,0};
        *reinterpret_cast<ushort8*>(&sA2[m * 104 + 72 + k8 * 8]) = z;
    }

    const int pn = tid >> 2, ph = (tid & 3) * 16;
    const int em = tid >> 2, ec = (tid & 3) * 2;
    ushort8 xr0, xr1;
    float2  er;
    {
        const unsigned short* pg = d1 + (((((size_t)b * T_ + t0) * F_) + f) << 12);
        xr0 = *reinterpret_cast<const ushort8*>(&pg[pn * 64 + ph]);
        xr1 = *reinterpret_cast<const ushort8*>(&pg[pn * 64 + ph + 8]);
        er  = *reinterpret_cast<const float2*>(&embs_g[((((size_t)(b * 64 + em)) * T_ + t0) * F_ + f) * 8 + ec]);
    }

    for (int tt = 0; tt < 4; ++tt) {
        const int t = t0 + tt;

        {
#pragma unroll
            for (int i = 0; i < 8; ++i) sXT[(ph + i) * 104 + pn] = xr0[i];
#pragma unroll
            for (int i = 0; i < 8; ++i) sXT[(ph + 8 + i) * 104 + pn] = xr1[i];
            *reinterpret_cast<unsigned*>(&sA2[em * 104 + 64 + ec]) = pk2(er.x, er.y);
        }
        if (tt < 3) {
            const unsigned short* pg = d1 + (((((size_t)b * T_ + t + 1) * F_) + f) << 12);
            xr0 = *reinterpret_cast<const ushort8*>(&pg[pn * 64 + ph]);
            xr1 = *reinterpret_cast<const ushort8*>(&pg[pn * 64 + ph + 8]);
            er  = *reinterpret_cast<const float2*>(&embs_g[((((size_t)(b * 64 + em)) * T_ + t + 1) * F_ + f) * 8 + ec]);
        }
        __syncthreads();

        f32x4 acc[4];
#pragma unroll
        for (int j = 0; j < 4; j++) acc[j] = {0.f, 0.f, 0.f, 0.f};
#pragma unroll
        for (int ks = 0; ks < 2; ++ks) {
            f16x8 af = *reinterpret_cast<const f16x8*>(&sAdj[(w * 16 + r16) * 72 + ks * 32 + q * 8]);
#pragma unroll
            for (int ht = 0; ht < 4; ++ht) {
                f16x8 xf = *reinterpret_cast<const f16x8*>(&sXT[(ht * 16 + r16) * 104 + ks * 32 + q * 8]);
                acc[ht] = __builtin_amdgcn_mfma_f32_16x16x32_f16(xf, af, acc[ht], 0, 0, 0);
            }
        }

        const int m = w * 16 + r16;
        float s = 0.f, qq = 0.f;
#pragma unroll
        for (int ht = 0; ht < 4; ++ht)
#pragma unroll
            for (int r = 0; r < 4; ++r) { float v = acc[ht][r]; s += v; qq += v * v; }
        s += __shfl_xor(s, 16, 64); qq += __shfl_xor(qq, 16, 64);
        s += __shfl_xor(s, 32, 64); qq += __shfl_xor(qq, 32, 64);
        float mean = s * (1.f / 64.f);
        float var  = qq * (1.f / 64.f) - mean * mean;
        float rstd = rsqrtf(var + 1e-5f);

#pragma unroll
        for (int ht = 0; ht < 4; ++ht) {
            float4 g4  = *reinterpret_cast<const float4*>(&sGB[ht * 16 + q * 4]);
            float4 be4 = *reinterpret_cast<const float4*>(&sGB[64 + ht * 16 + q * 4]);
            st4h(&sA2[m * 104 + ht * 16 + q * 4],
                 (acc[ht][0] - mean) * rstd * ((const float*)&g4)[0] + ((const float*)&be4)[0],
                 (acc[ht][1] - mean) * rstd * ((const float*)&g4)[1] + ((const float*)&be4)[1],
                 (acc[ht][2] - mean) * rstd * ((const float*)&g4)[2] + ((const float*)&be4)[2],
                 (acc[ht][3] - mean) * rstd * ((const float*)&g4)[3] + ((const float*)&be4)[3]);
        }
        __syncthreads();

        f32x4 dacc[4];
#pragma unroll
        for (int j = 0; j < 4; j++) dacc[j] = {0.f, 0.f, 0.f, 0.f};
#pragma unroll
        for (int ks = 0; ks < 3; ++ks) {
            const int ko = ks * 32 + q * 8;
            f16x8 aw = *reinterpret_cast<const f16x8*>(&sWg[(w * 16 + r16) * 104 + ko]);
#pragma unroll
            for (int mt = 0; mt < 4; ++mt) {
                f16x8 bx = *reinterpret_cast<const f16x8*>(&sA2[(mt * 16 + r16) * 104 + ko]);
                dacc[mt] = __builtin_amdgcn_mfma_f32_16x16x32_f16(aw, bx, dacc[mt], 0, 0, 0);
            }
        }

        float4 b4 = *reinterpret_cast<const float4*>(&sBg[w * 16 + q * 4]);
#pragma unroll
        for (int mt = 0; mt < 4; ++mt) {
            const int mm = mt * 16 + r16;
            const size_t row = (((size_t)(b * 64 + mm) * T_ + t) * F_ + f);
            st4h(&d2[row * H_ + w * 16 + q * 4],
                 elu_(dacc[mt][0] + b4.x), elu_(dacc[mt][1] + b4.y),
                 elu_(dacc[mt][2] + b4.z), elu_(dacc[mt][3] + b4.w));
        }
        __syncthreads();
    }
}

// ---------------- feature mix + LN + residual, 8 t per block (verified r14-r18; conflict-free already) ----------------
__global__ __launch_bounds__(256) void featmix_v3(const unsigned short* __restrict__ e,
                                                  const float* __restrict__ adjg,
                                                  const float* __restrict__ gamma,
                                                  const float* __restrict__ beta,
                                                  const float* __restrict__ res,
                                                  float* __restrict__ out)
{
    __shared__ __align__(16) unsigned short se[8 * 16 * 64];

    const int t0 = (blockIdx.x & 15) * 8, bn = blockIdx.x >> 4;
    const int tid = threadIdx.x;

    {
        int f = tid >> 4, c4 = (tid & 15) * 4;
#pragma unroll
        for (int tl = 0; tl < 8; ++tl)
            *reinterpret_cast<ushort4*>(&se[tl * 1024 + f * 64 + c4]) =
                *reinterpret_cast<const ushort4*>(&e[(((size_t)bn * T_ + t0 + tl) * F_ + f) * H_ + c4]);
    }
    __syncthreads();

    const int g = tid >> 4, hq = tid & 15;
    float ag[16];
#pragma unroll
    for (int f = 0; f < 16; ++f) ag[f] = adjg[g * 16 + f];
    float gm0 = gamma[hq * 4 + 0], gm1 = gamma[hq * 4 + 1], gm2 = gamma[hq * 4 + 2], gm3 = gamma[hq * 4 + 3];
    float be0 = beta[hq * 4 + 0],  be1 = beta[hq * 4 + 1],  be2 = beta[hq * 4 + 2],  be3 = beta[hq * 4 + 3];

    for (int tl = 0; tl < 8; ++tl) {
        float a0 = 0.f, a1 = 0.f, a2 = 0.f, a3 = 0.f;
#pragma unroll
        for (int f = 0; f < 16; ++f) {
            ushort4 dv = *reinterpret_cast<const ushort4*>(&se[tl * 1024 + f * 64 + hq * 4]);
            float av = ag[f];
            a0 = fmaf(av, h2f(dv.x), a0);
            a1 = fmaf(av, h2f(dv.y), a1);
            a2 = fmaf(av, h2f(dv.z), a2);
            a3 = fmaf(av, h2f(dv.w), a3);
        }
        float s  = a0 + a1 + a2 + a3;
        float qv = a0*a0 + a1*a1 + a2*a2 + a3*a3;
#pragma unroll
        for (int m = 1; m < 16; m <<= 1) { s += __shfl_xor(s, m, 64); qv += __shfl_xor(qv, m, 64); }
        float mean = s * (1.f / 64.f);
        float var  = qv * (1.f / 64.f) - mean * mean;
        float rstd = rsqrtf(var + 1e-5f);

        const size_t o = (((size_t)bn * T_ + t0 + tl) * F_ + g) * H_ + hq * 4;
        float4 rv = *reinterpret_cast<const float4*>(res + o);
        float4 ov;
        ov.x = (a0 - mean) * rstd * gm0 + be0 + rv.x;
        ov.y = (a1 - mean) * rstd * gm1 + be1 + rv.y;
        ov.z = (a2 - mean) * rstd * gm2 + be2 + rv.z;
        ov.w = (a3 - mean) * rstd * gm3 + be3 + rv.w;
        *reinterpret_cast<float4*>(out + o) = ov;
    }
}

extern "C" void kernel_launch(void* const* d_in, const int* in_sizes, int n_in,
                              void* d_out, int out_size, void* d_ws, size_t ws_size,
                              hipStream_t stream)
{
    const float* h_in    = (const float*)d_in[0];
    const float* embs_G  = (const float*)d_in[2];
    const float* embs_g  = (const float*)d_in[3];
    const float* adj_G   = (const float*)d_in[4];
    const float* adj_g   = (const float*)d_in[5];
    const float* Wt0 = (const float*)d_in[6];  const float* bt0 = (const float*)d_in[7];
    const float* Wt1 = (const float*)d_in[8];  const float* bt1 = (const float*)d_in[9];
    const float* Wt2 = (const float*)d_in[10]; const float* bt2 = (const float*)d_in[11];
    const float* gamma_t = (const float*)d_in[12]; const float* beta_t = (const float*)d_in[13];
    const float* W_G = (const float*)d_in[14]; const float* b_G = (const float*)d_in[15];
    const float* gamma_G = (const float*)d_in[16]; const float* beta_G = (const float*)d_in[17];
    const float* W_g = (const float*)d_in[18]; const float* b_g = (const float*)d_in[19];
    const float* gamma_g = (const float*)d_in[20]; const float* beta_g = (const float*)d_in[21];

    float* out = (float*)d_out;
    char*  ws  = (char*)d_ws;
    unsigned short* d1 = (unsigned short*)ws;                          // 64 MiB (paged layout)
    unsigned short* d2 = (unsigned short*)(ws + ((size_t)64 << 20));   // 64 MiB

    unsigned short* prep = (unsigned short*)(ws + ((size_t)192 << 20));
    unsigned short* pw   = prep;                 // 3*16*64*192
    unsigned short* pWG  = prep + 589824;
    unsigned short* pWg  = pWG + 6656;
    unsigned short* padj = pWg + 6656;

    prep_all<<<49, 256, 0, stream>>>(Wt0, Wt1, Wt2, adj_G, W_G, W_g, pw, padj, pWG, pWg);

    conv_chain<<<4096, 512, 0, stream>>>(h_in, pw, bt0, bt1, bt2, gamma_t, beta_t,
                                         embs_G, pWG, b_G, d1);
    nodemix_dense2<<<2048, 256, 0, stream>>>(d1, padj, gamma_G, beta_G,
                                             embs_g, pWg, b_g, d2);
    featmix_v3<<<4096, 256, 0, stream>>>(d2, adj_g, gamma_g, beta_g, h_in, out);
}